// Round 6
// baseline (869.447 us; speedup 1.0000x reference)
//
#include <hip/hip_runtime.h>
#include <math.h>

#define PI_D 3.14159265358979323846264338327950288

// LDS skew: +1 element per 16 to break power-of-2 butterfly strides
// (round-5 rocprof: 1.05M bank-conflict cycles per 1024-col dispatch from the
// 8-way conflict of the stride-2 radix-2 write pattern).
#define SK(e) ((e) + ((e) >> 4))

enum { LOP_NONE=0, LOP_R2C, LOP_ABSC, LOP_PAD, LOP_POWDC };
enum { SOP_NONE=0, SOP_REAL, SOP_STATS };

// ---------------------------------------------------------------------------
// helpers
// ---------------------------------------------------------------------------
__host__ __device__ constexpr int P4(int a, int b){ return a*4 - a*(a-1)/2 + (b-a); }
__host__ __device__ constexpr int P5(int a, int b){ return a*5 - a*(a-1)/2 + (b-a); }

__device__ __forceinline__ unsigned encf(float f){
  unsigned u = __float_as_uint(f);
  return (u & 0x80000000u) ? ~u : (u | 0x80000000u);
}
__device__ __forceinline__ float decf(unsigned u){
  unsigned b = (u & 0x80000000u) ? (u ^ 0x80000000u) : ~u;
  return __uint_as_float(b);
}

// wave shuffle-reduce -> LDS -> ONE atomicAdd per counter per block.
template<int CNT, int WAVES>
__device__ __forceinline__ void block_reduce_add(float (&acc)[CNT], double* out){
  __shared__ float red[WAVES*CNT];
  int lane = threadIdx.x & 63;
  int wid  = threadIdx.x >> 6;
  #pragma unroll
  for (int k = 0; k < CNT; k++){
    float v = acc[k];
    #pragma unroll
    for (int o = 32; o > 0; o >>= 1) v += __shfl_down(v, o, 64);
    if (lane == 0) red[wid*CNT + k] = v;
  }
  __syncthreads();
  int t = threadIdx.x;
  if (t < CNT){
    double s = 0.0;
    #pragma unroll
    for (int w = 0; w < WAVES; w++) s += (double)red[w*CNT + t];
    atomicAdd(&out[t], s);
  }
}

// polar grid of the ORIGINAL 1024x1024 image (0-indexed center at 512).
__device__ __forceinline__ void polar_at(int iy, int ix, double& lr, double& ang){
  double yn = (double)(iy - 512) / 512.0;
  double xn = (double)(ix - 512) / 512.0;
  ang = atan2(yn, xn);
  double rad = (iy == 512 && ix == 512) ? (1.0/512.0) : sqrt(xn*xn + yn*yn);
  lr = log2(rad);
}
__device__ __forceinline__ double d_hi(double lr, double shift){
  double v = lr - shift;
  v = fmin(fmax(v, -1.0), 0.0);
  return cos(PI_D * 0.5 * v);
}
__device__ __forceinline__ double d_lo(double lr, double shift){
  double h = d_hi(lr, shift);
  double q = 1.0 - h*h;
  q = fmin(fmax(q, 0.0), 1.0);
  return sqrt(q);
}

// ---------------------------------------------------------------------------
// FFT rows pass: one line per block, out-of-place capable, fused load-op.
// ---------------------------------------------------------------------------
template<int N>
__global__ __launch_bounds__((N/2 < 64) ? 64 : N/2)
void ps_fft_rows(float2* __restrict__ dst, const void* __restrict__ vsrc,
                 const double* __restrict__ msum, float invn,
                 int simg, int dimg, int srcH1,
                 float dir, int xin, int xout, int lop)
{
  constexpr int T = (N/2 < 64) ? 64 : N/2;
  constexpr int NS = N + (N >> 4);
  __shared__ float2 smem[2*NS];
  float2* sA = smem; float2* sB = smem + NS;
  const int t = threadIdx.x;
  const int l = blockIdx.x & (N-1);
  const int img = blockIdx.x / N;
  float2* dline = dst + (size_t)img*(size_t)dimg + (size_t)l*N;

  if (lop == LOP_PAD){
    const int q = N/4;
    const int sl = l - q;
    if (sl < 0 || sl >= srcH1){
      for (int j = t; j < N; j += T) dline[j] = make_float2(0.f, 0.f);
      return;
    }
    const float2* s = (const float2*)vsrc + (size_t)img*simg + (size_t)sl*srcH1;
    for (int j = t; j < N; j += T){
      int p = j ^ xin;
      sA[SK(j)] = (p >= q && p < q + srcH1) ? s[p - q] : make_float2(0.f, 0.f);
    }
  } else if (lop == LOP_R2C){
    const float* s = (const float*)vsrc + (size_t)img*simg + (size_t)l*N;
    for (int j = t; j < N; j += T) sA[SK(j)] = make_float2(s[j ^ xin], 0.f);
  } else if (lop == LOP_ABSC){
    const float2* s = (const float2*)vsrc + (size_t)img*simg + (size_t)l*N;
    float m = (float)(msum[img] * (double)invn);
    for (int j = t; j < N; j += T){
      float2 v = s[j ^ xin];
      sA[SK(j)] = make_float2(sqrtf(v.x*v.x + v.y*v.y) - m, 0.f);
    }
  } else {
    const float2* s = (const float2*)vsrc + (size_t)img*simg + (size_t)l*N;
    for (int j = t; j < N; j += T) sA[SK(j)] = s[j ^ xin];
  }
  __syncthreads();
  float2* src = sA; float2* dstp = sB;
  for (int Ns = 1; Ns < N; Ns <<= 1){
    if (t < N/2){
      int k = t & (Ns - 1);
      float2 i0 = src[SK(t)], i1 = src[SK(t + N/2)];
      float2 tv;
      if (Ns == 1){
        tv = i1;                       // w = 1, skip sincos
      } else {
        float ang = dir * (float)PI_D * (float)k / (float)Ns;
        float sw, cw; __sincosf(ang, &sw, &cw);
        tv = make_float2(cw*i1.x - sw*i1.y, cw*i1.y + sw*i1.x);
      }
      int d = ((t - k) << 1) + k;
      dstp[SK(d)]      = make_float2(i0.x + tv.x, i0.y + tv.y);
      dstp[SK(d + Ns)] = make_float2(i0.x - tv.x, i0.y - tv.y);
    }
    __syncthreads();
    float2* tmp = src; src = dstp; dstp = tmp;
  }
  for (int j = t; j < N; j += T) dline[j ^ xout] = src[SK(j)];
}

// ---------------------------------------------------------------------------
// FFT cols pass: CB adjacent columns per block (coalesced). src/dst may alias.
// lop POWDC: |v|^2 on load with DC bin zeroed.  fused: FWD -> |.|^2 -> INV.
// sop: NONE complex store; REAL real store; STATS accumulate 5 moments, no store.
// ---------------------------------------------------------------------------
template<int N, int CB>
__global__ __launch_bounds__(512)
void ps_fft_cols(float2* __restrict__ dst, const float2* __restrict__ src,
                 int simg, int dimg,
                 float dir, int xin, int xout, float scale,
                 int sop, float* __restrict__ rdst, int rimg,
                 double* __restrict__ mout, int lop, int fused)
{
  constexpr int T = 512;
  constexpr int LCB = (CB==2)?1:(CB==4)?2:(CB==8)?3:4;
  constexpr int NB = N / CB;
  constexpr int NE = N*CB;
  constexpr int NES = NE + (NE >> 4);
  __shared__ float2 smem[2*NES];
  float2* sA = smem; float2* sB = smem + NES;
  const int t = threadIdx.x;
  const int img = blockIdx.x / NB;
  const int c0 = (blockIdx.x % NB) * CB;
  const float2* sbase = src + (size_t)img*(size_t)simg + c0;
  float2* dbase = dst + (size_t)img*(size_t)dimg + c0;

  for (int e = t; e < NE; e += T){
    int j = e >> LCB, c = e & (CB - 1);
    float2 v = sbase[(size_t)(j ^ xin)*N + c];
    if (lop == LOP_POWDC){
      float p = v.x*v.x + v.y*v.y;
      if (((j ^ xin) == N/2) && ((c0 + c) == N/2)) p = 0.f;
      v = make_float2(p, 0.f);
    }
    sA[SK(e)] = v;
  }
  __syncthreads();
  float2* cur = sA; float2* oth = sB;
  float d1 = fused ? -1.f : dir;
  for (int Ns = 1; Ns < N; Ns <<= 1){
    for (int q = t; q < (N/2)*CB; q += T){
      int c  = q & (CB - 1);
      int tt = q >> LCB;
      int k  = tt & (Ns - 1);
      float2 i0 = cur[SK(tt*CB + c)], i1 = cur[SK((tt + N/2)*CB + c)];
      float2 tv;
      if (Ns == 1){
        tv = i1;
      } else {
        float ang = d1 * (float)PI_D * (float)k / (float)Ns;
        float sw, cw; __sincosf(ang, &sw, &cw);
        tv = make_float2(cw*i1.x - sw*i1.y, cw*i1.y + sw*i1.x);
      }
      int d = ((tt - k) << 1) + k;
      oth[SK(d*CB + c)]        = make_float2(i0.x + tv.x, i0.y + tv.y);
      oth[SK((d + Ns)*CB + c)] = make_float2(i0.x - tv.x, i0.y - tv.y);
    }
    __syncthreads();
    float2* tmp = cur; cur = oth; oth = tmp;
  }
  if (fused){
    for (int e = t; e < NE; e += T){
      float2 v = cur[SK(e)];
      cur[SK(e)] = make_float2(v.x*v.x + v.y*v.y, 0.f);
    }
    __syncthreads();
    for (int Ns = 1; Ns < N; Ns <<= 1){
      for (int q = t; q < (N/2)*CB; q += T){
        int c  = q & (CB - 1);
        int tt = q >> LCB;
        int k  = tt & (Ns - 1);
        float2 i0 = cur[SK(tt*CB + c)], i1 = cur[SK((tt + N/2)*CB + c)];
        float2 tv;
        if (Ns == 1){
          tv = i1;
        } else {
          float ang = (float)PI_D * (float)k / (float)Ns;   // inverse
          float sw, cw; __sincosf(ang, &sw, &cw);
          tv = make_float2(cw*i1.x - sw*i1.y, cw*i1.y + sw*i1.x);
        }
        int d = ((tt - k) << 1) + k;
        oth[SK(d*CB + c)]        = make_float2(i0.x + tv.x, i0.y + tv.y);
        oth[SK((d + Ns)*CB + c)] = make_float2(i0.x - tv.x, i0.y - tv.y);
      }
      __syncthreads();
      float2* tmp = cur; cur = oth; oth = tmp;
    }
  }
  if (sop == SOP_REAL){
    for (int e = t; e < NE; e += T){
      int j = e >> LCB, c = e & (CB - 1);
      rdst[(size_t)img*(size_t)rimg + (size_t)(j ^ xout)*N + c0 + c] = cur[SK(j*CB + c)].x * scale;
    }
  } else if (sop == SOP_NONE){
    for (int e = t; e < NE; e += T){
      int j = e >> LCB, c = e & (CB - 1);
      float2 v = cur[SK(j*CB + c)];
      dbase[(size_t)(j ^ xout)*N + c] = make_float2(v.x*scale, v.y*scale);
    }
  }
  if (mout){
    float acc[5] = {0.f,0.f,0.f,0.f,0.f};
    for (int e = t; e < NE; e += T){
      float r = cur[SK(e)].x * scale, r2 = r*r;
      acc[0] += r; acc[1] += r2; acc[2] += r2*r; acc[3] += r2*r2; acc[4] += fabsf(r);
    }
    block_reduce_add<5, 8>(acc, mout);
  }
}

// ---------------------------------------------------------------------------
// autocorr tail: inverse-FFT ONLY the 9 needed rows, write 81 normalized outs.
// ---------------------------------------------------------------------------
template<int N>
__global__ __launch_bounds__((N/2 < 64) ? 64 : N/2)
void ps_ac_rows(float* __restrict__ out, const float2* __restrict__ buf, int n_per_img,
                const double* __restrict__ s1, const double* __restrict__ s2, int sstride,
                double nrecip, float invn2, int base0, int img_mul, int stride, int xin)
{
  constexpr int T = (N/2 < 64) ? 64 : N/2;
  constexpr int NS = N + (N >> 4);
  __shared__ float2 smem[2*NS];
  float2* sA = smem; float2* sB = smem + NS;
  const int t = threadIdx.x;
  const int img = blockIdx.x / 9;
  const int dy  = blockIdx.x % 9;
  const int row = (dy - 4) & (N - 1);
  const float2* line = buf + (size_t)img*(size_t)n_per_img + (size_t)row*N;
  for (int j = t; j < N; j += T) sA[SK(j)] = line[j ^ xin];
  __syncthreads();
  float2* src = sA; float2* dstp = sB;
  for (int Ns = 1; Ns < N; Ns <<= 1){
    if (t < N/2){
      int k = t & (Ns - 1);
      float2 i0 = src[SK(t)], i1 = src[SK(t + N/2)];
      float2 tv;
      if (Ns == 1){
        tv = i1;
      } else {
        float ang = (float)PI_D * (float)k / (float)Ns;   // inverse
        float sw, cw; __sincosf(ang, &sw, &cw);
        tv = make_float2(cw*i1.x - sw*i1.y, cw*i1.y + sw*i1.x);
      }
      int d = ((t - k) << 1) + k;
      dstp[SK(d)]      = make_float2(i0.x + tv.x, i0.y + tv.y);
      dstp[SK(d + Ns)] = make_float2(i0.x - tv.x, i0.y - tv.y);
    }
    __syncthreads();
    float2* tmp = src; src = dstp; dstp = tmp;
  }
  if (t < 9){
    int col = (t - 4) & (N - 1);
    double m = s1[img*sstride] * nrecip;
    double ctr = s2[img*sstride] * nrecip - m*m;
    float v = src[SK(col)].x * invn2;
    out[base0 + img*img_mul + (dy*9 + t)*stride] = v / ((float)ctr + 1e-12f);
  }
}

// ---------------------------------------------------------------------------
// elementwise kernels
// ---------------------------------------------------------------------------
__global__ __launch_bounds__(256)
void ps_mask_hl(float2* __restrict__ lo_dst, float2* __restrict__ hi_dst,
                const float2* __restrict__ src){
  int i = blockIdx.x*blockDim.x + threadIdx.x;
  if (i >= 1024*1024) return;
  int y = i >> 10, x = i & 1023;
  double lr, ang; polar_at(y, x, lr, ang);
  float2 v = src[i];
  float lo = (float)d_lo(lr, 0.0), hi = (float)d_hi(lr, 0.0);
  lo_dst[i] = make_float2(v.x*lo, v.y*lo);
  hi_dst[i] = make_float2(v.x*hi, v.y*hi);
}
__global__ __launch_bounds__(256)
void ps_band_mask4(float2* __restrict__ dst, const float2* __restrict__ src,
                   int H, int off, double shift){
  int i = blockIdx.x*blockDim.x + threadIdx.x;
  int n = H*H;
  if (i >= n) return;
  int y = i / H, x = i - y*H;
  double lr, ang; polar_at(off + y, off + x, lr, ang);
  double hm = d_hi(lr, shift);
  float2 v = src[i];
  #pragma unroll
  for (int b = 0; b < 4; b++){
    double a0 = ang - PI_D*(double)b/4.0 + PI_D;
    double a = fmod(a0, 2.0*PI_D);
    if (a < 0.0) a += 2.0*PI_D;
    a -= PI_D;
    double mk = 0.0;
    if (fabs(a) < PI_D*0.5){ double c = cos(a); mk = 2.0*sqrt(0.8)*c*c*c; }
    float mf = (float)(hm*mk);
    dst[(size_t)b*n + i] = make_float2(-mf*v.y, mf*v.x);
  }
}
__global__ __launch_bounds__(256)
void ps_crop_lo(float2* dst, const float2* src, int Hs, int offNew, double shift){
  int Hd = Hs/2;
  int i = blockIdx.x*blockDim.x + threadIdx.x;
  if (i >= Hd*Hd) return;
  int y = i / Hd, x = i - y*Hd;
  double lr, ang; polar_at(offNew + y, offNew + x, lr, ang);
  float mk = (float)d_lo(lr, shift);
  float2 v = src[(y + Hs/4)*Hs + (x + Hs/4)];
  dst[i] = make_float2(v.x*mk, v.y*mk);
}

// ---------------------------------------------------------------------------
// reductions
// ---------------------------------------------------------------------------
__global__ void ps_init_mm(unsigned* mm){ mm[0] = 0xFFFFFFFFu; mm[1] = 0u; }

__global__ __launch_bounds__(256, 1)
void ps_im_stats(const float4* __restrict__ x4, int n4, double* out, unsigned* mm){
  float acc[4] = {0.f,0.f,0.f,0.f};
  float mn = INFINITY, mx = -INFINITY;
  for (int i = blockIdx.x*blockDim.x + threadIdx.x; i < n4; i += gridDim.x*blockDim.x){
    float4 v = x4[i];
    float a0 = v.x, a1 = v.y, a2 = v.z, a3 = v.w;
    acc[0] += a0 + a1 + a2 + a3;
    acc[1] += a0*a0 + a1*a1 + a2*a2 + a3*a3;
    acc[2] += a0*a0*a0 + a1*a1*a1 + a2*a2*a2 + a3*a3*a3;
    acc[3] += a0*a0*a0*a0 + a1*a1*a1*a1 + a2*a2*a2*a2 + a3*a3*a3*a3;
    mn = fminf(mn, fminf(fminf(a0,a1), fminf(a2,a3)));
    mx = fmaxf(mx, fmaxf(fmaxf(a0,a1), fmaxf(a2,a3)));
  }
  block_reduce_add<4, 4>(acc, out);
  #pragma unroll
  for (int o = 32; o > 0; o >>= 1){
    mn = fminf(mn, __shfl_down(mn, o, 64));
    mx = fmaxf(mx, __shfl_down(mx, o, 64));
  }
  if ((threadIdx.x & 63) == 0){
    atomicMin(&mm[0], encf(mn));
    atomicMax(&mm[1], encf(mx));
  }
}
__global__ __launch_bounds__(256, 1)
void ps_scaleA(const float2* __restrict__ b0, const float2* __restrict__ b1,
               const float2* __restrict__ b2, const float2* __restrict__ b3,
               int n, double* out){
  float acc[32];
  #pragma unroll
  for (int k = 0; k < 32; k++) acc[k] = 0.f;
  for (int i = blockIdx.x*blockDim.x + threadIdx.x; i < n; i += gridDim.x*blockDim.x){
    float2 v0 = b0[i], v1 = b1[i], v2 = b2[i], v3 = b3[i];
    float ab[4] = { sqrtf(v0.x*v0.x+v0.y*v0.y), sqrtf(v1.x*v1.x+v1.y*v1.y),
                    sqrtf(v2.x*v2.x+v2.y*v2.y), sqrtf(v3.x*v3.x+v3.y*v3.y) };
    float re[4] = { v0.x, v1.x, v2.x, v3.x };
    #pragma unroll
    for (int a = 0; a < 4; a++){
      #pragma unroll
      for (int c = a; c < 4; c++){
        acc[P4(a,c)]      += ab[a]*ab[c];
        acc[10 + P4(a,c)] += re[a]*re[c];
      }
      acc[20 + a] += ab[a];
      acc[24 + a] += re[a];
      acc[28 + a] += ab[a]*ab[a];
    }
  }
  block_reduce_add<32, 4>(acc, out);
}
__global__ __launch_bounds__(256, 1)
void ps_scaleB(const float2* __restrict__ u0, const float2* __restrict__ u1,
               const float2* __restrict__ u2, const float2* __restrict__ u3,
               const float2* __restrict__ s0, const float2* __restrict__ s1,
               const float2* __restrict__ s2, const float2* __restrict__ s3,
               int n, double* out){
  float acc[72];
  #pragma unroll
  for (int k = 0; k < 72; k++) acc[k] = 0.f;
  for (int i = blockIdx.x*blockDim.x + threadIdx.x; i < n; i += gridDim.x*blockDim.x){
    float2 u[4] = { u0[i], u1[i], u2[i], u3[i] };
    float2 bb[4] = { s0[i], s1[i], s2[i], s3[i] };
    float au[4], dre[4], dim[4], M[4], R[4];
    #pragma unroll
    for (int c = 0; c < 4; c++){
      float xx = u[c].x, yy = u[c].y;
      float mag = sqrtf(xx*xx + yy*yy);
      float den = mag + 1e-12f;
      au[c] = mag;
      dre[c] = (xx*xx - yy*yy)/den;
      dim[c] = (2.f*xx*yy)/den;
      M[c] = sqrtf(bb[c].x*bb[c].x + bb[c].y*bb[c].y);
      R[c] = bb[c].x;
    }
    #pragma unroll
    for (int c = 0; c < 4; c++){
      acc[c]      += au[c];
      acc[4 + c]  += au[c]*au[c];
      acc[24 + c] += dre[c];
      acc[28 + c] += dim[c];
      acc[32 + c] += dre[c]*dre[c];
      acc[36 + c] += dim[c]*dim[c];
    }
    #pragma unroll
    for (int a = 0; a < 4; a++)
      #pragma unroll
      for (int c = 0; c < 4; c++){
        acc[8 + a*4 + c]  += M[a]*au[c];
        acc[40 + a*4 + c] += R[a]*dre[c];
        acc[56 + a*4 + c] += R[a]*dim[c];
      }
  }
  block_reduce_add<72, 4>(acc, out);
}
__global__ __launch_bounds__(256, 1)
void ps_scaleC(const float2* __restrict__ s0, const float2* __restrict__ s1,
               const float2* __restrict__ s2, const float2* __restrict__ s3,
               const float* __restrict__ lp, int n, double* out){
  float acc[36];
  #pragma unroll
  for (int k = 0; k < 36; k++) acc[k] = 0.f;
  for (int i = blockIdx.x*blockDim.x + threadIdx.x; i < n; i += gridDim.x*blockDim.x){
    int y = i >> 7, x = i & 127;
    float L[5];
    L[0] = lp[i];
    L[1] = lp[(y << 7) | ((x + 126) & 127)];
    L[2] = lp[(y << 7) | ((x + 2) & 127)];
    L[3] = lp[(((y + 126) & 127) << 7) | x];
    L[4] = lp[(((y + 2) & 127) << 7) | x];
    float R[4] = { s0[i].x, s1[i].x, s2[i].x, s3[i].x };
    acc[0] += L[0];
    #pragma unroll
    for (int a = 0; a < 5; a++)
      #pragma unroll
      for (int c = a; c < 5; c++)
        acc[1 + P5(a,c)] += L[a]*L[c];
    #pragma unroll
    for (int a = 0; a < 4; a++)
      #pragma unroll
      for (int j = 0; j < 5; j++)
        acc[16 + a*5 + j] += R[a]*L[j];
  }
  block_reduce_add<36, 4>(acc, out);
}

// ---------------------------------------------------------------------------
// finalize (single thread, doubles). ST layout:
//  [0..3] image moments; [4..8] hipass s1,s2,s3,s4,sabs
//  [10+r*6 .. 14+r*6] recon r: s1,s2,s3,s4,sabs (r=0..4)
//  [64+s*32] scaleA(32); [192+s*80] scaleB(72); [432..467] scaleC(36)
// ---------------------------------------------------------------------------
__global__ void ps_finalize(const double* __restrict__ ST, const unsigned* __restrict__ MM,
                            float* __restrict__ out){
  if (threadIdx.x != 0 || blockIdx.x != 0) return;
  const double n0 = 1048576.0;
  {
    double m = ST[0]/n0, e2 = ST[1]/n0, e3 = ST[2]/n0, e4 = ST[3]/n0;
    double v = e2 - m*m;
    double c3 = e3 - 3.0*m*e2 + 2.0*m*m*m;
    double c4 = e4 - 4.0*m*e3 + 6.0*m*m*e2 - 3.0*m*m*m*m;
    out[0] = (float)m; out[1] = (float)v;
    out[2] = (float)(c3/pow(v,1.5)); out[3] = (float)(c4/(v*v));
    out[4] = decf(MM[0]); out[5] = decf(MM[1]);
    out[6] = (float)(ST[8]/n0);
    out[23] = (float)(ST[10 + 4*6 + 4]/4096.0);
    out[2460] = (float)(ST[5]/n0 - (ST[4]/n0)*(ST[4]/n0));
  }
  for (int s = 0; s < 4; s++){
    double ns = (double)(1024 >> s) * (double)(1024 >> s);
    for (int b = 0; b < 4; b++)
      out[7 + s*4 + b] = (float)(ST[64 + s*32 + 20 + b]/ns);
  }
  for (int r = 0; r < 5; r++){
    double nr = (double)(1024 >> r) * (double)(1024 >> r);
    if (r == 4) nr = 4096.0;
    const double* Mo = ST + 10 + r*6;
    double m = Mo[0]/nr, e2 = Mo[1]/nr, e3 = Mo[2]/nr, e4 = Mo[3]/nr;
    double v = e2 - m*m;
    double c3 = e3 - 3.0*m*e2 + 2.0*m*m*m;
    double c4 = e4 - 4.0*m*e3 + 6.0*m*m*e2 - 3.0*m*m*m*m;
    out[1320 + r] = (float)(c3/pow(v,1.5));
    out[1325 + r] = (float)(c4/(v*v));
    out[1735 + r] = (float)sqrt(v);
  }
  for (int s = 0; s < 4; s++){
    double ns = (double)(1024 >> s) * (double)(1024 >> s);
    const double* A = ST + 64 + s*32;
    double mM[4], mR[4], sdM[4], sdR[4], cM[4][4], cR[4][4];
    for (int a = 0; a < 4; a++){ mM[a] = A[20+a]/ns; mR[a] = A[24+a]/ns; }
    for (int a = 0; a < 4; a++)
      for (int b = a; b < 4; b++){
        double vM = A[P4(a,b)]/ns - mM[a]*mM[b];
        double vR = A[10 + P4(a,b)]/ns - mR[a]*mR[b];
        cM[a][b] = cM[b][a] = vM;
        cR[a][b] = cR[b][a] = vR;
      }
    for (int a = 0; a < 4; a++){ sdM[a] = sqrt(cM[a][a]); sdR[a] = sqrt(cR[a][a]); }
    for (int a = 0; a < 4; a++)
      for (int b = 0; b < 4; b++){
        out[1740 + (a*4 + b)*5 + s] = (float)(cM[a][b]/(sdM[a]*sdM[b] + 1e-12));
        out[1884 + (a*8 + b)*5 + s] = (float)(cR[a][b]/(sdR[a]*sdR[b] + 1e-12));
      }
    if (s < 3){
      const double* B = ST + 192 + s*80;
      double mU[4], sdU[4], mdr[4], mdi[4], sdr[4], sdi[4];
      for (int c = 0; c < 4; c++){
        mU[c] = B[c]/ns;       sdU[c] = sqrt(B[4+c]/ns - mU[c]*mU[c]);
        mdr[c] = B[24+c]/ns;   mdi[c] = B[28+c]/ns;
        sdr[c] = sqrt(B[32+c]/ns - mdr[c]*mdr[c]);
        sdi[c] = sqrt(B[36+c]/ns - mdi[c]*mdi[c]);
      }
      for (int a = 0; a < 4; a++)
        for (int c = 0; c < 4; c++){
          out[1820 + (a*4 + c)*4 + s] =
            (float)((B[8 + a*4 + c]/ns - mM[a]*mU[c])/(sdM[a]*sdU[c] + 1e-12));
          out[2204 + (a*8 + c)*4 + s] =
            (float)((B[40 + a*4 + c]/ns - mR[a]*mdr[c])/(sdR[a]*sdr[c] + 1e-12));
          out[2204 + (a*8 + 4 + c)*4 + s] =
            (float)((B[56 + a*4 + c]/ns - mR[a]*mdi[c])/(sdR[a]*sdi[c] + 1e-12));
        }
    } else {
      const double* C = ST + 432;
      const double n3 = 16384.0;
      double lb = C[0]/n3;
      double cL[5][5], sdL[5];
      for (int i = 0; i < 5; i++)
        for (int j = i; j < 5; j++){
          double v = C[1 + P5(i,j)]/n3 - lb*lb;
          cL[i][j] = cL[j][i] = v;
        }
      for (int i = 0; i < 5; i++) sdL[i] = sqrt(cL[i][i]);
      for (int a = 0; a < 4; a++)
        for (int j = 0; j < 5; j++)
          out[2204 + (a*8 + j)*4 + 3] =
            (float)((C[16 + a*5 + j]/n3 - mR[a]*lb)/(sdR[a]*sdL[j] + 1e-12));
      for (int i = 0; i < 5; i++)
        for (int j = 0; j < 5; j++)
          out[1884 + (i*8 + j)*5 + 4] = (float)(cL[i][j]/(sdL[i]*sdL[j] + 1e-12));
    }
  }
}

// ---------------------------------------------------------------------------
// host orchestration
// ---------------------------------------------------------------------------
static void rows_pass(int H, float2* dst, const void* src,
                      const double* msum, float invn,
                      int nimg, int simg, int dimg, int srcH1,
                      float dir, int xin, int xout, int lop, hipStream_t st){
  dim3 g(nimg * H);
  switch (H){
    case 64:   ps_fft_rows<64>  <<<g, 64,  0, st>>>(dst, src, msum, invn, simg, dimg, srcH1, dir, xin, xout, lop); break;
    case 128:  ps_fft_rows<128> <<<g, 64,  0, st>>>(dst, src, msum, invn, simg, dimg, srcH1, dir, xin, xout, lop); break;
    case 256:  ps_fft_rows<256> <<<g, 128, 0, st>>>(dst, src, msum, invn, simg, dimg, srcH1, dir, xin, xout, lop); break;
    case 512:  ps_fft_rows<512> <<<g, 256, 0, st>>>(dst, src, msum, invn, simg, dimg, srcH1, dir, xin, xout, lop); break;
    case 1024: ps_fft_rows<1024><<<g, 512, 0, st>>>(dst, src, msum, invn, simg, dimg, srcH1, dir, xin, xout, lop); break;
    default: break;
  }
}
static void cols_pass(int H, float2* dst, const float2* src, int nimg, int simg, int dimg,
                      float dir, int xin, int xout, float scale,
                      int sop, float* rdst, int rimg, double* mout,
                      int lop, int fused, hipStream_t st){
  switch (H){
    case 64:   ps_fft_cols<64,16>  <<<dim3(nimg*(64/16)),  512, 0, st>>>(dst, src, simg, dimg, dir, xin, xout, scale, sop, rdst, rimg, mout, lop, fused); break;
    case 128:  ps_fft_cols<128,16> <<<dim3(nimg*(128/16)), 512, 0, st>>>(dst, src, simg, dimg, dir, xin, xout, scale, sop, rdst, rimg, mout, lop, fused); break;
    case 256:  ps_fft_cols<256,8>  <<<dim3(nimg*(256/8)),  512, 0, st>>>(dst, src, simg, dimg, dir, xin, xout, scale, sop, rdst, rimg, mout, lop, fused); break;
    case 512:  ps_fft_cols<512,8>  <<<dim3(nimg*(512/8)),  512, 0, st>>>(dst, src, simg, dimg, dir, xin, xout, scale, sop, rdst, rimg, mout, lop, fused); break;
    case 1024: ps_fft_cols<1024,4> <<<dim3(nimg*(1024/4)), 512, 0, st>>>(dst, src, simg, dimg, dir, xin, xout, scale, sop, rdst, rimg, mout, lop, fused); break;
    default: break;
  }
}
static void ac_rows_pass(int H, float* out, const float2* buf, int n_per_img, int nimg,
                         const double* s1, const double* s2, int sstride,
                         double nrecip, float invn2, int base0, int img_mul, int stride,
                         int xin, hipStream_t st){
  dim3 g(nimg * 9);
  switch (H){
    case 64:   ps_ac_rows<64>  <<<g, 64,  0, st>>>(out, buf, n_per_img, s1, s2, sstride, nrecip, invn2, base0, img_mul, stride, xin); break;
    case 128:  ps_ac_rows<128> <<<g, 64,  0, st>>>(out, buf, n_per_img, s1, s2, sstride, nrecip, invn2, base0, img_mul, stride, xin); break;
    case 256:  ps_ac_rows<256> <<<g, 128, 0, st>>>(out, buf, n_per_img, s1, s2, sstride, nrecip, invn2, base0, img_mul, stride, xin); break;
    case 512:  ps_ac_rows<512> <<<g, 256, 0, st>>>(out, buf, n_per_img, s1, s2, sstride, nrecip, invn2, base0, img_mul, stride, xin); break;
    case 1024: ps_ac_rows<1024><<<g, 512, 0, st>>>(out, buf, n_per_img, s1, s2, sstride, nrecip, invn2, base0, img_mul, stride, xin); break;
    default: break;
  }
}

static inline dim3 gr(int n){ return dim3((n + 255)/256); }
static inline int  rblocks(int n){ int b = (n + 255)/256; return b > 512 ? 512 : b; }

#define FWD (-1.0f)
#define INV (+1.0f)

extern "C" void kernel_launch(void* const* d_in, const int* in_sizes, int n_in,
                              void* d_out, int out_size, void* d_ws, size_t ws_size,
                              hipStream_t stream){
  (void)in_sizes; (void)n_in;
  const float* im = (const float*)d_in[0];
  float* out = (float*)d_out;

  const int Hs[5]   = {1024, 512, 256, 128, 64};
  const int offs[5] = {0, 256, 384, 448, 480};

  // ---- carve workspace ----
  char* base = (char*)d_ws;
  size_t off = 0;
  auto carve = [&](size_t bytes)->void*{
    void* r = base + off;
    off = (off + bytes + 255) & ~(size_t)255;
    return r;
  };
  float2* lod[5];
  for (int s = 0; s < 5; s++) lod[s] = (float2*)carve((size_t)Hs[s]*Hs[s]*sizeof(float2));
  float2* band[4];
  for (int s = 0; s < 4; s++) band[s] = (float2*)carve((size_t)4*Hs[s]*Hs[s]*sizeof(float2));
  float2* bdft[4];
  bdft[0] = nullptr;
  for (int s = 1; s < 4; s++) bdft[s] = (float2*)carve((size_t)4*Hs[s]*Hs[s]*sizeof(float2));
  float* lp = (float*)carve(128*128*sizeof(float));
  float2* scr  = (float2*)carve((size_t)1024*1024*sizeof(float2));
  float2* scr4 = (float2*)carve((size_t)4*1024*1024*sizeof(float2));
  double* ST = (double*)carve(512*sizeof(double));
  unsigned* MM = (unsigned*)carve(64*sizeof(unsigned));
  if (off > ws_size) return;

  // ---- init ----
  hipMemsetAsync(out, 0, (size_t)out_size*sizeof(float), stream);
  hipMemsetAsync(ST, 0, 512*sizeof(double), stream);
  ps_init_mm<<<1, 1, 0, stream>>>(MM);

  const int n0 = 1024*1024;
  ps_im_stats<<<256, 256, 0, stream>>>((const float4*)im, n0/4, ST + 0, MM);

  // ---- imdft (shifted) ----
  rows_pass(1024, scr, im, nullptr, 0.f, 1, 0, 0, 0, FWD, 0, 512, LOP_R2C, stream);
  cols_pass(1024, scr, scr, 1, 0, 0, FWD, 0, 512, 1.0f, SOP_NONE, nullptr, 0, nullptr, LOP_NONE, 0, stream);
  ps_mask_hl<<<gr(n0), 256, 0, stream>>>(lod[0], scr, scr);
  rows_pass(1024, scr, scr, nullptr, 0.f, 1, 0, 0, 0, INV, 512, 0, LOP_NONE, stream);
  cols_pass(1024, scr, scr, 1, 0, 0, INV, 512, 0, 1.0f/(float)n0, SOP_STATS, nullptr, 0, ST + 4, LOP_NONE, 0, stream);

  // ---- pyramid scales ----
  for (int s = 0; s < 4; s++){
    int H = Hs[s], n = H*H;
    float invn = 1.0f/((float)H*(float)H);
    rows_pass(H, scr, lod[s], nullptr, 0.f, 1, 0, 0, 0, INV, H/2, 0, LOP_NONE, stream);
    cols_pass(H, scr, scr, 1, 0, 0, INV, H/2, 0, invn, SOP_STATS, nullptr, 0, ST + 10 + s*6, LOP_NONE, 0, stream);
    float2* bq = (s == 0) ? scr4 : bdft[s];
    ps_band_mask4<<<gr(n), 256, 0, stream>>>(bq, lod[s], H, offs[s], -(double)(s+1));
    rows_pass(H, band[s], bq, nullptr, 0.f, 4, n, n, 0, INV, H/2, 0, LOP_NONE, stream);
    cols_pass(H, band[s], band[s], 4, n, n, INV, H/2, 0, invn, SOP_NONE, nullptr, 0, nullptr, LOP_NONE, 0, stream);
    ps_crop_lo<<<gr((H/2)*(H/2)), 256, 0, stream>>>(lod[s+1], lod[s], H, offs[s+1], -(double)(s+1));
  }
  rows_pass(64, scr, lod[4], nullptr, 0.f, 1, 0, 0, 0, INV, 32, 0, LOP_NONE, stream);
  cols_pass(64, scr, scr, 1, 0, 0, INV, 32, 0, 1.0f/4096.f, SOP_STATS, nullptr, 0, ST + 10 + 4*6, LOP_NONE, 0, stream);

  // ---- recon autocorrs straight from lod (power spectrum, DC zeroed) ----
  for (int r = 0; r < 5; r++){
    int H = Hs[r], n = H*H;
    float invn = 1.0f/(float)n;
    cols_pass(H, scr, lod[r], 1, n, n, INV, H/2, 0, invn, SOP_NONE, nullptr, 0, nullptr, LOP_POWDC, 0, stream);
    ac_rows_pass(H, out, scr, 0, 1, ST + 10 + r*6, ST + 10 + r*6 + 1, 0,
                 1.0/(double)n, invn, 1330 + r, 0, 5, H/2, stream);
  }

  // ---- per-scale band Grams ----
  for (int s = 0; s < 4; s++){
    int n = Hs[s]*Hs[s];
    ps_scaleA<<<rblocks(n), 256, 0, stream>>>(band[s], band[s]+n, band[s]+2*n, band[s]+3*n,
                                              n, ST + 64 + s*32);
  }

  // ---- cross-scale: pad kept band DFTs directly ----
  for (int s = 0; s < 3; s++){
    int H1 = Hs[s+1], H2 = Hs[s];
    int n1 = H1*H1, n2 = H2*H2;
    rows_pass(H2, scr4, bdft[s+1], nullptr, 0.f, 4, n1, n2, H1, INV, H2/2, 0, LOP_PAD, stream);
    cols_pass(H2, scr4, scr4, 4, n2, n2, INV, H2/2, 0, 1.0f/(float)n1, SOP_NONE, nullptr, 0, nullptr, LOP_NONE, 0, stream);
    ps_scaleB<<<rblocks(n2), 256, 0, stream>>>(scr4, scr4+n2, scr4+2*n2, scr4+3*n2,
                                               band[s], band[s]+n2, band[s]+2*n2, band[s]+3*n2,
                                               n2, ST + 192 + s*80);
  }
  // s=3: expand2(lowpass) = pad lod[4] directly
  rows_pass(128, scr4, lod[4], nullptr, 0.f, 1, 4096, 16384, 64, INV, 64, 0, LOP_PAD, stream);
  cols_pass(128, scr4, scr4, 1, 16384, 16384, INV, 64, 0, 1.0f/4096.f, SOP_REAL, lp, 0, nullptr, LOP_NONE, 0, stream);
  ps_scaleC<<<rblocks(16384), 256, 0, stream>>>(band[3], band[3]+16384, band[3]+2*16384, band[3]+3*16384,
                                                lp, 16384, ST + 432);

  // ---- band-magnitude autocorrs (fused FWD->|.|^2->INV col pass) ----
  for (int s = 0; s < 4; s++){
    int H = Hs[s], n = H*H;
    float invn = 1.0f/(float)n;
    rows_pass(H, scr4, band[s], ST + 64 + s*32 + 20, invn, 4, n, n, 0, FWD, 0, 0, LOP_ABSC, stream);
    cols_pass(H, scr4, scr4, 4, n, n, FWD, 0, 0, invn, SOP_NONE, nullptr, 0, nullptr, LOP_NONE, 1, stream);
    ac_rows_pass(H, out, scr4, n, 4, ST + 64 + s*32 + 20, ST + 64 + s*32 + 28, 1,
                 1.0/(double)n, invn, 24 + s*4, 1, 16, 0, stream);
  }

  // ---- finalize ----
  ps_finalize<<<1, 1, 0, stream>>>(ST, MM, out);
}

// Round 7
// 849.818 us; speedup vs baseline: 1.0231x; 1.0231x over previous
//
#include <hip/hip_runtime.h>
#include <math.h>

#define PI_D 3.14159265358979323846264338327950288

enum { LOP_NONE=0, LOP_R2C, LOP_PAD };
enum { SOP_NONE=0, SOP_REAL, SOP_STATS };

// ---------------------------------------------------------------------------
// helpers
// ---------------------------------------------------------------------------
__host__ __device__ constexpr int P4(int a, int b){ return a*4 - a*(a-1)/2 + (b-a); }
__host__ __device__ constexpr int P5(int a, int b){ return a*5 - a*(a-1)/2 + (b-a); }

__device__ __forceinline__ unsigned encf(float f){
  unsigned u = __float_as_uint(f);
  return (u & 0x80000000u) ? ~u : (u | 0x80000000u);
}
__device__ __forceinline__ float decf(unsigned u){
  unsigned b = (u & 0x80000000u) ? (u ^ 0x80000000u) : ~u;
  return __uint_as_float(b);
}

// wave shuffle-reduce -> LDS -> ONE atomicAdd per counter per block.
template<int CNT, int WAVES>
__device__ __forceinline__ void block_reduce_add(float (&acc)[CNT], double* out){
  __shared__ float red[WAVES*CNT];
  int lane = threadIdx.x & 63;
  int wid  = threadIdx.x >> 6;
  #pragma unroll
  for (int k = 0; k < CNT; k++){
    float v = acc[k];
    #pragma unroll
    for (int o = 32; o > 0; o >>= 1) v += __shfl_down(v, o, 64);
    if (lane == 0) red[wid*CNT + k] = v;
  }
  __syncthreads();
  int t = threadIdx.x;
  if (t < CNT){
    double s = 0.0;
    #pragma unroll
    for (int w = 0; w < WAVES; w++) s += (double)red[w*CNT + t];
    atomicAdd(&out[t], s);
  }
  __syncthreads();
}

// polar grid of the ORIGINAL 1024x1024 image (0-indexed center at 512).
__device__ __forceinline__ void polar_at(int iy, int ix, double& lr, double& ang){
  double yn = (double)(iy - 512) / 512.0;
  double xn = (double)(ix - 512) / 512.0;
  ang = atan2(yn, xn);
  double rad = (iy == 512 && ix == 512) ? (1.0/512.0) : sqrt(xn*xn + yn*yn);
  lr = log2(rad);
}
__device__ __forceinline__ double d_hi(double lr, double shift){
  double v = lr - shift;
  v = fmin(fmax(v, -1.0), 0.0);
  return cos(PI_D * 0.5 * v);
}
__device__ __forceinline__ double d_lo(double lr, double shift){
  double h = d_hi(lr, shift);
  double q = 1.0 - h*h;
  q = fmin(fmax(q, 0.0), 1.0);
  return sqrt(q);
}

// ---------------------------------------------------------------------------
// FFT rows pass: one line per block, out-of-place capable, fused load-op.
// (round-6 lesson: LDS skew REGRESSED conflicts 1.05M->3.93M; plain layout.)
// ---------------------------------------------------------------------------
template<int N>
__global__ __launch_bounds__((N/2 < 64) ? 64 : N/2)
void ps_fft_rows(float2* __restrict__ dst, const void* __restrict__ vsrc,
                 int simg, int dimg, int srcH1,
                 float dir, int xin, int xout, int lop)
{
  constexpr int T = (N/2 < 64) ? 64 : N/2;
  __shared__ float2 smem[2*N];
  float2* sA = smem; float2* sB = smem + N;
  const int t = threadIdx.x;
  const int l = blockIdx.x & (N-1);
  const int img = blockIdx.x / N;
  float2* dline = dst + (size_t)img*(size_t)dimg + (size_t)l*N;

  if (lop == LOP_PAD){
    const int q = N/4;
    const int sl = l - q;
    if (sl < 0 || sl >= srcH1){
      for (int j = t; j < N; j += T) dline[j] = make_float2(0.f, 0.f);
      return;
    }
    const float2* s = (const float2*)vsrc + (size_t)img*simg + (size_t)sl*srcH1;
    for (int j = t; j < N; j += T){
      int p = j ^ xin;
      sA[j] = (p >= q && p < q + srcH1) ? s[p - q] : make_float2(0.f, 0.f);
    }
  } else if (lop == LOP_R2C){
    const float* s = (const float*)vsrc + (size_t)img*simg + (size_t)l*N;
    for (int j = t; j < N; j += T) sA[j] = make_float2(s[j ^ xin], 0.f);
  } else {
    const float2* s = (const float2*)vsrc + (size_t)img*simg + (size_t)l*N;
    for (int j = t; j < N; j += T) sA[j] = s[j ^ xin];
  }
  __syncthreads();
  float2* src = sA; float2* dstp = sB;
  for (int Ns = 1; Ns < N; Ns <<= 1){
    if (t < N/2){
      int k = t & (Ns - 1);
      float2 i0 = src[t], i1 = src[t + N/2];
      float2 tv;
      if (Ns == 1){
        tv = i1;
      } else {
        float ang = dir * (float)PI_D * (float)k / (float)Ns;
        float sw, cw; __sincosf(ang, &sw, &cw);
        tv = make_float2(cw*i1.x - sw*i1.y, cw*i1.y + sw*i1.x);
      }
      int d = ((t - k) << 1) + k;
      dstp[d]      = make_float2(i0.x + tv.x, i0.y + tv.y);
      dstp[d + Ns] = make_float2(i0.x - tv.x, i0.y - tv.y);
    }
    __syncthreads();
    float2* tmp = src; src = dstp; dstp = tmp;
  }
  for (int j = t; j < N; j += T) dline[j ^ xout] = src[j];
}

// ---------------------------------------------------------------------------
// FFT cols pass: CB adjacent columns per block (coalesced). src/dst may alias.
// sop: NONE complex store; REAL real store; STATS no store.
// mout != null: accumulate 5 moments of (re*scale).
// ---------------------------------------------------------------------------
template<int N, int CB>
__global__ __launch_bounds__(512)
void ps_fft_cols(float2* __restrict__ dst, const float2* __restrict__ src,
                 int simg, int dimg,
                 float dir, int xin, int xout, float scale,
                 int sop, float* __restrict__ rdst, int rimg,
                 double* __restrict__ mout)
{
  constexpr int T = 512;
  constexpr int LCB = (CB==2)?1:(CB==4)?2:(CB==8)?3:4;
  constexpr int NB = N / CB;
  constexpr int NE = N*CB;
  __shared__ float2 smem[2*NE];
  float2* sA = smem; float2* sB = smem + NE;
  const int t = threadIdx.x;
  const int img = blockIdx.x / NB;
  const int c0 = (blockIdx.x % NB) * CB;
  const float2* sbase = src + (size_t)img*(size_t)simg + c0;
  float2* dbase = dst + (size_t)img*(size_t)dimg + c0;

  for (int e = t; e < NE; e += T){
    int j = e >> LCB, c = e & (CB - 1);
    sA[e] = sbase[(size_t)(j ^ xin)*N + c];
  }
  __syncthreads();
  float2* cur = sA; float2* oth = sB;
  for (int Ns = 1; Ns < N; Ns <<= 1){
    for (int q = t; q < (N/2)*CB; q += T){
      int c  = q & (CB - 1);
      int tt = q >> LCB;
      int k  = tt & (Ns - 1);
      float2 i0 = cur[tt*CB + c], i1 = cur[(tt + N/2)*CB + c];
      float2 tv;
      if (Ns == 1){
        tv = i1;
      } else {
        float ang = dir * (float)PI_D * (float)k / (float)Ns;
        float sw, cw; __sincosf(ang, &sw, &cw);
        tv = make_float2(cw*i1.x - sw*i1.y, cw*i1.y + sw*i1.x);
      }
      int d = ((tt - k) << 1) + k;
      oth[d*CB + c]        = make_float2(i0.x + tv.x, i0.y + tv.y);
      oth[(d + Ns)*CB + c] = make_float2(i0.x - tv.x, i0.y - tv.y);
    }
    __syncthreads();
    float2* tmp = cur; cur = oth; oth = tmp;
  }
  if (sop == SOP_REAL){
    for (int e = t; e < NE; e += T){
      int j = e >> LCB, c = e & (CB - 1);
      rdst[(size_t)img*(size_t)rimg + (size_t)(j ^ xout)*N + c0 + c] = cur[j*CB + c].x * scale;
    }
  } else if (sop == SOP_NONE){
    for (int e = t; e < NE; e += T){
      int j = e >> LCB, c = e & (CB - 1);
      float2 v = cur[j*CB + c];
      dbase[(size_t)(j ^ xout)*N + c] = make_float2(v.x*scale, v.y*scale);
    }
  }
  if (mout){
    float acc[5] = {0.f,0.f,0.f,0.f,0.f};
    for (int e = t; e < NE; e += T){
      float r = cur[e].x * scale, r2 = r*r;
      acc[0] += r; acc[1] += r2; acc[2] += r2*r; acc[3] += r2*r2; acc[4] += fabsf(r);
    }
    block_reduce_add<5, 8>(acc, mout);
  }
}

// ---------------------------------------------------------------------------
// spatial circular autocorrelation, 9x9 lag window, direct products.
// R[d] = sum_p x(p) x(p+d); symmetric R[-d]=R[d] -> 41 accumulators:
//   o in [0..4]   : dy=0, dx=o
//   o in [5..40]  : dy=1..4, dx=-4..4, o = 5 + (dy-1)*9 + (dx+4)
// mean subtraction handled algebraically in finalize (ac = R/n - mu^2).
// grid: (min(tiles,128), nimg). ST dst = st_base + img*st_stride.
// ---------------------------------------------------------------------------
__global__ __launch_bounds__(256, 1)
void ps_spat_ac(const void* __restrict__ vsrc, int isMag, int H, int n_per_img,
                double* __restrict__ st_base, int st_stride)
{
  __shared__ float tile[40*40];
  const int t = threadIdx.x;
  const int img = blockIdx.y;
  const int tilesX = H >> 5;
  const int tiles = tilesX * tilesX;
  float acc[41];
  #pragma unroll
  for (int k = 0; k < 41; k++) acc[k] = 0.f;

  for (int tl = blockIdx.x; tl < tiles; tl += gridDim.x){
    int by = tl / tilesX, bx = tl - by*tilesX;
    int y0 = by << 5, x0 = bx << 5;
    __syncthreads();
    for (int e = t; e < 40*40; e += 256){
      int ly = e / 40, lx = e - ly*40;
      int gy = (y0 + ly - 4) & (H - 1);
      int gx = (x0 + lx - 4) & (H - 1);
      float v;
      if (isMag){
        float2 c = ((const float2*)vsrc)[(size_t)img*n_per_img + (size_t)gy*H + gx];
        v = sqrtf(c.x*c.x + c.y*c.y);
      } else {
        v = ((const float*)vsrc)[(size_t)img*n_per_img + (size_t)gy*H + gx];
      }
      tile[e] = v;
    }
    __syncthreads();
    for (int p = t; p < 32*32; p += 256){
      int py = p >> 5, px = p & 31;
      const float* row0 = tile + (py+4)*40 + (px+4);
      float c = row0[0];
      #pragma unroll
      for (int dx = 0; dx <= 4; dx++)
        acc[dx] += c * row0[dx];
      #pragma unroll
      for (int dy = 1; dy <= 4; dy++){
        const float* rw = row0 + dy*40;
        #pragma unroll
        for (int dx = -4; dx <= 4; dx++)
          acc[5 + (dy-1)*9 + (dx+4)] += c * rw[dx];
      }
    }
  }
  block_reduce_add<41, 4>(acc, st_base + (size_t)img*st_stride);
}

// ---------------------------------------------------------------------------
// elementwise kernels
// ---------------------------------------------------------------------------
__global__ __launch_bounds__(256)
void ps_mask_hl(float2* __restrict__ lo_dst, float2* __restrict__ hi_dst,
                const float2* __restrict__ src){
  int i = blockIdx.x*blockDim.x + threadIdx.x;
  if (i >= 1024*1024) return;
  int y = i >> 10, x = i & 1023;
  double lr, ang; polar_at(y, x, lr, ang);
  float2 v = src[i];
  float lo = (float)d_lo(lr, 0.0), hi = (float)d_hi(lr, 0.0);
  lo_dst[i] = make_float2(v.x*lo, v.y*lo);
  hi_dst[i] = make_float2(v.x*hi, v.y*hi);
}
__global__ __launch_bounds__(256)
void ps_band_mask4(float2* __restrict__ dst, const float2* __restrict__ src,
                   int H, int off, double shift){
  int i = blockIdx.x*blockDim.x + threadIdx.x;
  int n = H*H;
  if (i >= n) return;
  int y = i / H, x = i - y*H;
  double lr, ang; polar_at(off + y, off + x, lr, ang);
  double hm = d_hi(lr, shift);
  float2 v = src[i];
  #pragma unroll
  for (int b = 0; b < 4; b++){
    double a0 = ang - PI_D*(double)b/4.0 + PI_D;
    double a = fmod(a0, 2.0*PI_D);
    if (a < 0.0) a += 2.0*PI_D;
    a -= PI_D;
    double mk = 0.0;
    if (fabs(a) < PI_D*0.5){ double c = cos(a); mk = 2.0*sqrt(0.8)*c*c*c; }
    float mf = (float)(hm*mk);
    dst[(size_t)b*n + i] = make_float2(-mf*v.y, mf*v.x);
  }
}
__global__ __launch_bounds__(256)
void ps_crop_lo(float2* dst, const float2* src, int Hs, int offNew, double shift){
  int Hd = Hs/2;
  int i = blockIdx.x*blockDim.x + threadIdx.x;
  if (i >= Hd*Hd) return;
  int y = i / Hd, x = i - y*Hd;
  double lr, ang; polar_at(offNew + y, offNew + x, lr, ang);
  float mk = (float)d_lo(lr, shift);
  float2 v = src[(y + Hs/4)*Hs + (x + Hs/4)];
  dst[i] = make_float2(v.x*mk, v.y*mk);
}

// ---------------------------------------------------------------------------
// reductions
// ---------------------------------------------------------------------------
__global__ void ps_init_mm(unsigned* mm){ mm[0] = 0xFFFFFFFFu; mm[1] = 0u; }

__global__ __launch_bounds__(256, 1)
void ps_im_stats(const float4* __restrict__ x4, int n4, double* out, unsigned* mm){
  float acc[4] = {0.f,0.f,0.f,0.f};
  float mn = INFINITY, mx = -INFINITY;
  for (int i = blockIdx.x*blockDim.x + threadIdx.x; i < n4; i += gridDim.x*blockDim.x){
    float4 v = x4[i];
    float a0 = v.x, a1 = v.y, a2 = v.z, a3 = v.w;
    acc[0] += a0 + a1 + a2 + a3;
    acc[1] += a0*a0 + a1*a1 + a2*a2 + a3*a3;
    acc[2] += a0*a0*a0 + a1*a1*a1 + a2*a2*a2 + a3*a3*a3;
    acc[3] += a0*a0*a0*a0 + a1*a1*a1*a1 + a2*a2*a2*a2 + a3*a3*a3*a3;
    mn = fminf(mn, fminf(fminf(a0,a1), fminf(a2,a3)));
    mx = fmaxf(mx, fmaxf(fmaxf(a0,a1), fmaxf(a2,a3)));
  }
  block_reduce_add<4, 4>(acc, out);
  #pragma unroll
  for (int o = 32; o > 0; o >>= 1){
    mn = fminf(mn, __shfl_down(mn, o, 64));
    mx = fmaxf(mx, __shfl_down(mx, o, 64));
  }
  if ((threadIdx.x & 63) == 0){
    atomicMin(&mm[0], encf(mn));
    atomicMax(&mm[1], encf(mx));
  }
}
__global__ __launch_bounds__(256, 1)
void ps_scaleA(const float2* __restrict__ b0, const float2* __restrict__ b1,
               const float2* __restrict__ b2, const float2* __restrict__ b3,
               int n, double* out){
  float acc[28];
  #pragma unroll
  for (int k = 0; k < 28; k++) acc[k] = 0.f;
  for (int i = blockIdx.x*blockDim.x + threadIdx.x; i < n; i += gridDim.x*blockDim.x){
    float2 v0 = b0[i], v1 = b1[i], v2 = b2[i], v3 = b3[i];
    float ab[4] = { sqrtf(v0.x*v0.x+v0.y*v0.y), sqrtf(v1.x*v1.x+v1.y*v1.y),
                    sqrtf(v2.x*v2.x+v2.y*v2.y), sqrtf(v3.x*v3.x+v3.y*v3.y) };
    float re[4] = { v0.x, v1.x, v2.x, v3.x };
    #pragma unroll
    for (int a = 0; a < 4; a++){
      #pragma unroll
      for (int c = a; c < 4; c++){
        acc[P4(a,c)]      += ab[a]*ab[c];
        acc[10 + P4(a,c)] += re[a]*re[c];
      }
      acc[20 + a] += ab[a];
      acc[24 + a] += re[a];
    }
  }
  block_reduce_add<28, 4>(acc, out);
}
__global__ __launch_bounds__(256, 1)
void ps_scaleB(const float2* __restrict__ u0, const float2* __restrict__ u1,
               const float2* __restrict__ u2, const float2* __restrict__ u3,
               const float2* __restrict__ s0, const float2* __restrict__ s1,
               const float2* __restrict__ s2, const float2* __restrict__ s3,
               int n, double* out){
  float acc[72];
  #pragma unroll
  for (int k = 0; k < 72; k++) acc[k] = 0.f;
  for (int i = blockIdx.x*blockDim.x + threadIdx.x; i < n; i += gridDim.x*blockDim.x){
    float2 u[4] = { u0[i], u1[i], u2[i], u3[i] };
    float2 bb[4] = { s0[i], s1[i], s2[i], s3[i] };
    float au[4], dre[4], dim[4], M[4], R[4];
    #pragma unroll
    for (int c = 0; c < 4; c++){
      float xx = u[c].x, yy = u[c].y;
      float mag = sqrtf(xx*xx + yy*yy);
      float den = mag + 1e-12f;
      au[c] = mag;
      dre[c] = (xx*xx - yy*yy)/den;
      dim[c] = (2.f*xx*yy)/den;
      M[c] = sqrtf(bb[c].x*bb[c].x + bb[c].y*bb[c].y);
      R[c] = bb[c].x;
    }
    #pragma unroll
    for (int c = 0; c < 4; c++){
      acc[c]      += au[c];
      acc[4 + c]  += au[c]*au[c];
      acc[24 + c] += dre[c];
      acc[28 + c] += dim[c];
      acc[32 + c] += dre[c]*dre[c];
      acc[36 + c] += dim[c]*dim[c];
    }
    #pragma unroll
    for (int a = 0; a < 4; a++)
      #pragma unroll
      for (int c = 0; c < 4; c++){
        acc[8 + a*4 + c]  += M[a]*au[c];
        acc[40 + a*4 + c] += R[a]*dre[c];
        acc[56 + a*4 + c] += R[a]*dim[c];
      }
  }
  block_reduce_add<72, 4>(acc, out);
}
__global__ __launch_bounds__(256, 1)
void ps_scaleC(const float2* __restrict__ s0, const float2* __restrict__ s1,
               const float2* __restrict__ s2, const float2* __restrict__ s3,
               const float* __restrict__ lp, int n, double* out){
  float acc[36];
  #pragma unroll
  for (int k = 0; k < 36; k++) acc[k] = 0.f;
  for (int i = blockIdx.x*blockDim.x + threadIdx.x; i < n; i += gridDim.x*blockDim.x){
    int y = i >> 7, x = i & 127;
    float L[5];
    L[0] = lp[i];
    L[1] = lp[(y << 7) | ((x + 126) & 127)];
    L[2] = lp[(y << 7) | ((x + 2) & 127)];
    L[3] = lp[(((y + 126) & 127) << 7) | x];
    L[4] = lp[(((y + 2) & 127) << 7) | x];
    float R[4] = { s0[i].x, s1[i].x, s2[i].x, s3[i].x };
    acc[0] += L[0];
    #pragma unroll
    for (int a = 0; a < 5; a++)
      #pragma unroll
      for (int c = a; c < 5; c++)
        acc[1 + P5(a,c)] += L[a]*L[c];
    #pragma unroll
    for (int a = 0; a < 4; a++)
      #pragma unroll
      for (int j = 0; j < 5; j++)
        acc[16 + a*5 + j] += R[a]*L[j];
  }
  block_reduce_add<36, 4>(acc, out);
}

// ---------------------------------------------------------------------------
// finalize, 256 threads. ST layout:
//  [0..3] image moments; [4..8] hipass s1,s2,s3,s4,sabs
//  [10+r*6 ..] recon r: s1,s2,s3,s4,sabs; [64+s*32] scaleA(28)
//  [192+s*80] scaleB(72); [432..467] scaleC(36)
//  [512+r*48] recon AC R[41]; [752+(s*4+b)*48] band-mag AC R[41]
// ---------------------------------------------------------------------------
__global__ __launch_bounds__(256)
void ps_finalize(const double* __restrict__ ST, const unsigned* __restrict__ MM,
                 float* __restrict__ out){
  // --- parallel: 21 autocorrelations x 81 outputs ---
  for (int idx = threadIdx.x; idx < 21*81; idx += blockDim.x){
    int a = idx / 81, w = idx - a*81;
    int dy = w/9 - 4, dx = w - (w/9)*9 - 4;
    const double* R; double mu, n; int pos, stride;
    if (a < 5){
      int r = a;
      n = (r == 4) ? 4096.0 : (double)(1024 >> r)*(double)(1024 >> r);
      R = ST + 512 + r*48;
      mu = ST[10 + r*6] / n;
      pos = 1330 + r; stride = 5;
    } else {
      int j = a - 5, s = j >> 2, b = j & 3;
      n = (double)(1024 >> s)*(double)(1024 >> s);
      R = ST + 752 + j*48;
      mu = ST[64 + s*32 + 20 + b] / n;
      pos = 24 + j; stride = 16;
    }
    int ady = dy, adx = dx;
    if (dy < 0 || (dy == 0 && dx < 0)){ ady = -dy; adx = -dx; }
    int o = (ady == 0) ? adx : (5 + (ady-1)*9 + (adx+4));
    double mu2 = mu*mu;
    double ctr = R[0]/n - mu2;
    out[pos + w*stride] = (float)((R[o]/n - mu2) / (ctr + 1e-12));
  }
  if (threadIdx.x != 0 || blockIdx.x != 0) return;
  const double n0 = 1048576.0;
  {
    double m = ST[0]/n0, e2 = ST[1]/n0, e3 = ST[2]/n0, e4 = ST[3]/n0;
    double v = e2 - m*m;
    double c3 = e3 - 3.0*m*e2 + 2.0*m*m*m;
    double c4 = e4 - 4.0*m*e3 + 6.0*m*m*e2 - 3.0*m*m*m*m;
    out[0] = (float)m; out[1] = (float)v;
    out[2] = (float)(c3/pow(v,1.5)); out[3] = (float)(c4/(v*v));
    out[4] = decf(MM[0]); out[5] = decf(MM[1]);
    out[6] = (float)(ST[8]/n0);
    out[23] = (float)(ST[10 + 4*6 + 4]/4096.0);
    out[2460] = (float)(ST[5]/n0 - (ST[4]/n0)*(ST[4]/n0));
  }
  for (int s = 0; s < 4; s++){
    double ns = (double)(1024 >> s) * (double)(1024 >> s);
    for (int b = 0; b < 4; b++)
      out[7 + s*4 + b] = (float)(ST[64 + s*32 + 20 + b]/ns);
  }
  for (int r = 0; r < 5; r++){
    double nr = (double)(1024 >> r) * (double)(1024 >> r);
    if (r == 4) nr = 4096.0;
    const double* Mo = ST + 10 + r*6;
    double m = Mo[0]/nr, e2 = Mo[1]/nr, e3 = Mo[2]/nr, e4 = Mo[3]/nr;
    double v = e2 - m*m;
    double c3 = e3 - 3.0*m*e2 + 2.0*m*m*m;
    double c4 = e4 - 4.0*m*e3 + 6.0*m*m*e2 - 3.0*m*m*m*m;
    out[1320 + r] = (float)(c3/pow(v,1.5));
    out[1325 + r] = (float)(c4/(v*v));
    out[1735 + r] = (float)sqrt(v);
  }
  for (int s = 0; s < 4; s++){
    double ns = (double)(1024 >> s) * (double)(1024 >> s);
    const double* A = ST + 64 + s*32;
    double mM[4], mR[4], sdM[4], sdR[4], cM[4][4], cR[4][4];
    for (int a = 0; a < 4; a++){ mM[a] = A[20+a]/ns; mR[a] = A[24+a]/ns; }
    for (int a = 0; a < 4; a++)
      for (int b = a; b < 4; b++){
        double vM = A[P4(a,b)]/ns - mM[a]*mM[b];
        double vR = A[10 + P4(a,b)]/ns - mR[a]*mR[b];
        cM[a][b] = cM[b][a] = vM;
        cR[a][b] = cR[b][a] = vR;
      }
    for (int a = 0; a < 4; a++){ sdM[a] = sqrt(cM[a][a]); sdR[a] = sqrt(cR[a][a]); }
    for (int a = 0; a < 4; a++)
      for (int b = 0; b < 4; b++){
        out[1740 + (a*4 + b)*5 + s] = (float)(cM[a][b]/(sdM[a]*sdM[b] + 1e-12));
        out[1884 + (a*8 + b)*5 + s] = (float)(cR[a][b]/(sdR[a]*sdR[b] + 1e-12));
      }
    if (s < 3){
      const double* B = ST + 192 + s*80;
      double mU[4], sdU[4], mdr[4], mdi[4], sdr[4], sdi[4];
      for (int c = 0; c < 4; c++){
        mU[c] = B[c]/ns;       sdU[c] = sqrt(B[4+c]/ns - mU[c]*mU[c]);
        mdr[c] = B[24+c]/ns;   mdi[c] = B[28+c]/ns;
        sdr[c] = sqrt(B[32+c]/ns - mdr[c]*mdr[c]);
        sdi[c] = sqrt(B[36+c]/ns - mdi[c]*mdi[c]);
      }
      for (int a = 0; a < 4; a++)
        for (int c = 0; c < 4; c++){
          out[1820 + (a*4 + c)*4 + s] =
            (float)((B[8 + a*4 + c]/ns - mM[a]*mU[c])/(sdM[a]*sdU[c] + 1e-12));
          out[2204 + (a*8 + c)*4 + s] =
            (float)((B[40 + a*4 + c]/ns - mR[a]*mdr[c])/(sdR[a]*sdr[c] + 1e-12));
          out[2204 + (a*8 + 4 + c)*4 + s] =
            (float)((B[56 + a*4 + c]/ns - mR[a]*mdi[c])/(sdR[a]*sdi[c] + 1e-12));
        }
    } else {
      const double* C = ST + 432;
      const double n3 = 16384.0;
      double lb = C[0]/n3;
      double cL[5][5], sdL[5];
      for (int i = 0; i < 5; i++)
        for (int j = i; j < 5; j++){
          double v = C[1 + P5(i,j)]/n3 - lb*lb;
          cL[i][j] = cL[j][i] = v;
        }
      for (int i = 0; i < 5; i++) sdL[i] = sqrt(cL[i][i]);
      for (int a = 0; a < 4; a++)
        for (int j = 0; j < 5; j++)
          out[2204 + (a*8 + j)*4 + 3] =
            (float)((C[16 + a*5 + j]/n3 - mR[a]*lb)/(sdR[a]*sdL[j] + 1e-12));
      for (int i = 0; i < 5; i++)
        for (int j = 0; j < 5; j++)
          out[1884 + (i*8 + j)*5 + 4] = (float)(cL[i][j]/(sdL[i]*sdL[j] + 1e-12));
    }
  }
}

// ---------------------------------------------------------------------------
// host orchestration
// ---------------------------------------------------------------------------
static void rows_pass(int H, float2* dst, const void* src,
                      int nimg, int simg, int dimg, int srcH1,
                      float dir, int xin, int xout, int lop, hipStream_t st){
  dim3 g(nimg * H);
  switch (H){
    case 64:   ps_fft_rows<64>  <<<g, 64,  0, st>>>(dst, src, simg, dimg, srcH1, dir, xin, xout, lop); break;
    case 128:  ps_fft_rows<128> <<<g, 64,  0, st>>>(dst, src, simg, dimg, srcH1, dir, xin, xout, lop); break;
    case 256:  ps_fft_rows<256> <<<g, 128, 0, st>>>(dst, src, simg, dimg, srcH1, dir, xin, xout, lop); break;
    case 512:  ps_fft_rows<512> <<<g, 256, 0, st>>>(dst, src, simg, dimg, srcH1, dir, xin, xout, lop); break;
    case 1024: ps_fft_rows<1024><<<g, 512, 0, st>>>(dst, src, simg, dimg, srcH1, dir, xin, xout, lop); break;
    default: break;
  }
}
static void cols_pass(int H, float2* dst, const float2* src, int nimg, int simg, int dimg,
                      float dir, int xin, int xout, float scale,
                      int sop, float* rdst, int rimg, double* mout, hipStream_t st){
  switch (H){
    case 64:   ps_fft_cols<64,16>  <<<dim3(nimg*(64/16)),  512, 0, st>>>(dst, src, simg, dimg, dir, xin, xout, scale, sop, rdst, rimg, mout); break;
    case 128:  ps_fft_cols<128,16> <<<dim3(nimg*(128/16)), 512, 0, st>>>(dst, src, simg, dimg, dir, xin, xout, scale, sop, rdst, rimg, mout); break;
    case 256:  ps_fft_cols<256,8>  <<<dim3(nimg*(256/8)),  512, 0, st>>>(dst, src, simg, dimg, dir, xin, xout, scale, sop, rdst, rimg, mout); break;
    case 512:  ps_fft_cols<512,8>  <<<dim3(nimg*(512/8)),  512, 0, st>>>(dst, src, simg, dimg, dir, xin, xout, scale, sop, rdst, rimg, mout); break;
    case 1024: ps_fft_cols<1024,4> <<<dim3(nimg*(1024/4)), 512, 0, st>>>(dst, src, simg, dimg, dir, xin, xout, scale, sop, rdst, rimg, mout); break;
    default: break;
  }
}
static void spat_ac(const void* src, int isMag, int H, int n_per_img, int nimg,
                    double* st_base, int st_stride, hipStream_t st){
  int tiles = (H >> 5) * (H >> 5);
  int nb = tiles < 128 ? tiles : 128;
  ps_spat_ac<<<dim3(nb, nimg), 256, 0, st>>>(src, isMag, H, n_per_img, st_base, st_stride);
}

static inline dim3 gr(int n){ return dim3((n + 255)/256); }
static inline int  rblocks(int n){ int b = (n + 255)/256; return b > 512 ? 512 : b; }

#define FWD (-1.0f)
#define INV (+1.0f)

extern "C" void kernel_launch(void* const* d_in, const int* in_sizes, int n_in,
                              void* d_out, int out_size, void* d_ws, size_t ws_size,
                              hipStream_t stream){
  (void)in_sizes; (void)n_in;
  const float* im = (const float*)d_in[0];
  float* out = (float*)d_out;

  const int Hs[5]   = {1024, 512, 256, 128, 64};
  const int offs[5] = {0, 256, 384, 448, 480};

  // ---- carve workspace ----
  char* base = (char*)d_ws;
  size_t off = 0;
  auto carve = [&](size_t bytes)->void*{
    void* r = base + off;
    off = (off + bytes + 255) & ~(size_t)255;
    return r;
  };
  float2* lod[5];
  for (int s = 0; s < 5; s++) lod[s] = (float2*)carve((size_t)Hs[s]*Hs[s]*sizeof(float2));
  float2* band[4];
  for (int s = 0; s < 4; s++) band[s] = (float2*)carve((size_t)4*Hs[s]*Hs[s]*sizeof(float2));
  float2* bdft[4];
  bdft[0] = nullptr;
  for (int s = 1; s < 4; s++) bdft[s] = (float2*)carve((size_t)4*Hs[s]*Hs[s]*sizeof(float2));
  float* recon[5];
  for (int s = 0; s < 5; s++) recon[s] = (float*)carve((size_t)Hs[s]*Hs[s]*sizeof(float));
  float* lp = (float*)carve(128*128*sizeof(float));
  float2* scr  = (float2*)carve((size_t)1024*1024*sizeof(float2));
  float2* scr4 = (float2*)carve((size_t)4*1024*1024*sizeof(float2));
  double* ST = (double*)carve(2048*sizeof(double));
  unsigned* MM = (unsigned*)carve(64*sizeof(unsigned));
  if (off > ws_size) return;

  // ---- init ----
  hipMemsetAsync(out, 0, (size_t)out_size*sizeof(float), stream);
  hipMemsetAsync(ST, 0, 2048*sizeof(double), stream);
  ps_init_mm<<<1, 1, 0, stream>>>(MM);

  const int n0 = 1024*1024;
  ps_im_stats<<<256, 256, 0, stream>>>((const float4*)im, n0/4, ST + 0, MM);

  // ---- imdft (shifted) ----
  rows_pass(1024, scr, im, 1, 0, 0, 0, FWD, 0, 512, LOP_R2C, stream);
  cols_pass(1024, scr, scr, 1, 0, 0, FWD, 0, 512, 1.0f, SOP_NONE, nullptr, 0, nullptr, stream);
  ps_mask_hl<<<gr(n0), 256, 0, stream>>>(lod[0], scr, scr);
  rows_pass(1024, scr, scr, 1, 0, 0, 0, INV, 512, 0, LOP_NONE, stream);
  cols_pass(1024, scr, scr, 1, 0, 0, INV, 512, 0, 1.0f/(float)n0, SOP_STATS, nullptr, 0, ST + 4, stream);

  // ---- pyramid scales: recon (stored + stats), bands, next lowpass ----
  for (int s = 0; s < 4; s++){
    int H = Hs[s], n = H*H;
    float invn = 1.0f/((float)H*(float)H);
    rows_pass(H, scr, lod[s], 1, 0, 0, 0, INV, H/2, 0, LOP_NONE, stream);
    cols_pass(H, scr, scr, 1, 0, 0, INV, H/2, 0, invn, SOP_REAL, recon[s], 0, ST + 10 + s*6, stream);
    float2* bq = (s == 0) ? scr4 : bdft[s];
    ps_band_mask4<<<gr(n), 256, 0, stream>>>(bq, lod[s], H, offs[s], -(double)(s+1));
    rows_pass(H, band[s], bq, 4, n, n, 0, INV, H/2, 0, LOP_NONE, stream);
    cols_pass(H, band[s], band[s], 4, n, n, INV, H/2, 0, invn, SOP_NONE, nullptr, 0, nullptr, stream);
    ps_crop_lo<<<gr((H/2)*(H/2)), 256, 0, stream>>>(lod[s+1], lod[s], H, offs[s+1], -(double)(s+1));
  }
  rows_pass(64, scr, lod[4], 1, 0, 0, 0, INV, 32, 0, LOP_NONE, stream);
  cols_pass(64, scr, scr, 1, 0, 0, INV, 32, 0, 1.0f/4096.f, SOP_REAL, recon[4], 0, ST + 10 + 4*6, stream);

  // ---- autocorrs: direct spatial circular correlation (9x9 lags) ----
  for (int r = 0; r < 5; r++)
    spat_ac(recon[r], 0, Hs[r], Hs[r]*Hs[r], 1, ST + 512 + r*48, 48, stream);
  for (int s = 0; s < 4; s++)
    spat_ac(band[s], 1, Hs[s], Hs[s]*Hs[s], 4, ST + 752 + s*4*48, 48, stream);

  // ---- per-scale band Grams ----
  for (int s = 0; s < 4; s++){
    int n = Hs[s]*Hs[s];
    ps_scaleA<<<rblocks(n), 256, 0, stream>>>(band[s], band[s]+n, band[s]+2*n, band[s]+3*n,
                                              n, ST + 64 + s*32);
  }

  // ---- cross-scale: pad kept band DFTs directly ----
  for (int s = 0; s < 3; s++){
    int H1 = Hs[s+1], H2 = Hs[s];
    int n1 = H1*H1, n2 = H2*H2;
    rows_pass(H2, scr4, bdft[s+1], 4, n1, n2, H1, INV, H2/2, 0, LOP_PAD, stream);
    cols_pass(H2, scr4, scr4, 4, n2, n2, INV, H2/2, 0, 1.0f/(float)n1, SOP_NONE, nullptr, 0, nullptr, stream);
    ps_scaleB<<<rblocks(n2), 256, 0, stream>>>(scr4, scr4+n2, scr4+2*n2, scr4+3*n2,
                                               band[s], band[s]+n2, band[s]+2*n2, band[s]+3*n2,
                                               n2, ST + 192 + s*80);
  }
  // s=3: expand2(lowpass) = pad lod[4] directly
  rows_pass(128, scr4, lod[4], 1, 4096, 16384, 64, INV, 64, 0, LOP_PAD, stream);
  cols_pass(128, scr4, scr4, 1, 16384, 16384, INV, 64, 0, 1.0f/4096.f, SOP_REAL, lp, 0, nullptr, stream);
  ps_scaleC<<<rblocks(16384), 256, 0, stream>>>(band[3], band[3]+16384, band[3]+2*16384, band[3]+3*16384,
                                                lp, 16384, ST + 432);

  // ---- finalize ----
  ps_finalize<<<1, 256, 0, stream>>>(ST, MM, out);
}

// Round 8
// 572.249 us; speedup vs baseline: 1.5194x; 1.4850x over previous
//
#include <hip/hip_runtime.h>
#include <math.h>

#define PI_D 3.14159265358979323846264338327950288
#define PI_F 3.14159265358979323846f

enum { LOP_NONE=0, LOP_R2C, LOP_PAD };
enum { SOP_NONE=0, SOP_REAL, SOP_STATS };

// ---------------------------------------------------------------------------
// helpers
// ---------------------------------------------------------------------------
__host__ __device__ constexpr int P4(int a, int b){ return a*4 - a*(a-1)/2 + (b-a); }
__host__ __device__ constexpr int P5(int a, int b){ return a*5 - a*(a-1)/2 + (b-a); }

__device__ __forceinline__ unsigned encf(float f){
  unsigned u = __float_as_uint(f);
  return (u & 0x80000000u) ? ~u : (u | 0x80000000u);
}
__device__ __forceinline__ float decf(unsigned u){
  unsigned b = (u & 0x80000000u) ? (u ^ 0x80000000u) : ~u;
  return __uint_as_float(b);
}

// wave shuffle-reduce -> LDS -> ONE atomicAdd per counter per block.
template<int CNT, int WAVES>
__device__ __forceinline__ void block_reduce_add(float (&acc)[CNT], double* out){
  __shared__ float red[WAVES*CNT];
  int lane = threadIdx.x & 63;
  int wid  = threadIdx.x >> 6;
  #pragma unroll
  for (int k = 0; k < CNT; k++){
    float v = acc[k];
    #pragma unroll
    for (int o = 32; o > 0; o >>= 1) v += __shfl_down(v, o, 64);
    if (lane == 0) red[wid*CNT + k] = v;
  }
  __syncthreads();
  int t = threadIdx.x;
  if (t < CNT){
    double s = 0.0;
    #pragma unroll
    for (int w = 0; w < WAVES; w++) s += (double)red[w*CNT + t];
    atomicAdd(&out[t], s);
  }
  __syncthreads();
}

// float polar grid (ref computes masks in f64 then CASTS to f32; float mask
// error ~1e-7 rel vs 0.199 abs threshold — safe, and 3-4x less VALU).
__device__ __forceinline__ void polar_f(int iy, int ix, float& lr, float& ang){
  float yn = (float)(iy - 512) * (1.f/512.f);
  float xn = (float)(ix - 512) * (1.f/512.f);
  ang = atan2f(yn, xn);
  float rad = (iy == 512 && ix == 512) ? (1.f/512.f) : sqrtf(xn*xn + yn*yn);
  lr = log2f(rad);
}
__device__ __forceinline__ float f_hi(float lr, float shift){
  float v = fminf(fmaxf(lr - shift, -1.f), 0.f);
  return cosf((PI_F*0.5f) * v);
}
__device__ __forceinline__ float f_lo(float lr, float shift){
  float h = f_hi(lr, shift);
  float q = fminf(fmaxf(1.f - h*h, 0.f), 1.f);
  return sqrtf(q);
}

// ---------------------------------------------------------------------------
// FFT rows pass: one line per block, out-of-place capable, fused load-op.
// ---------------------------------------------------------------------------
template<int N>
__global__ __launch_bounds__((N/2 < 64) ? 64 : N/2)
void ps_fft_rows(float2* __restrict__ dst, const void* __restrict__ vsrc,
                 int simg, int dimg, int srcH1,
                 float dir, int xin, int xout, int lop)
{
  constexpr int T = (N/2 < 64) ? 64 : N/2;
  __shared__ float2 smem[2*N];
  float2* sA = smem; float2* sB = smem + N;
  const int t = threadIdx.x;
  const int l = blockIdx.x & (N-1);
  const int img = blockIdx.x / N;
  float2* dline = dst + (size_t)img*(size_t)dimg + (size_t)l*N;

  if (lop == LOP_PAD){
    const int q = N/4;
    const int sl = l - q;
    if (sl < 0 || sl >= srcH1){
      for (int j = t; j < N; j += T) dline[j] = make_float2(0.f, 0.f);
      return;
    }
    const float2* s = (const float2*)vsrc + (size_t)img*simg + (size_t)sl*srcH1;
    for (int j = t; j < N; j += T){
      int p = j ^ xin;
      sA[j] = (p >= q && p < q + srcH1) ? s[p - q] : make_float2(0.f, 0.f);
    }
  } else if (lop == LOP_R2C){
    const float* s = (const float*)vsrc + (size_t)img*simg + (size_t)l*N;
    for (int j = t; j < N; j += T) sA[j] = make_float2(s[j ^ xin], 0.f);
  } else {
    const float2* s = (const float2*)vsrc + (size_t)img*simg + (size_t)l*N;
    for (int j = t; j < N; j += T) sA[j] = s[j ^ xin];
  }
  __syncthreads();
  float2* src = sA; float2* dstp = sB;
  for (int Ns = 1; Ns < N; Ns <<= 1){
    if (t < N/2){
      int k = t & (Ns - 1);
      float2 i0 = src[t], i1 = src[t + N/2];
      float2 tv;
      if (Ns == 1){
        tv = i1;
      } else {
        float ang = dir * (float)PI_D * (float)k / (float)Ns;
        float sw, cw; __sincosf(ang, &sw, &cw);
        tv = make_float2(cw*i1.x - sw*i1.y, cw*i1.y + sw*i1.x);
      }
      int d = ((t - k) << 1) + k;
      dstp[d]      = make_float2(i0.x + tv.x, i0.y + tv.y);
      dstp[d + Ns] = make_float2(i0.x - tv.x, i0.y - tv.y);
    }
    __syncthreads();
    float2* tmp = src; src = dstp; dstp = tmp;
  }
  for (int j = t; j < N; j += T) dline[j ^ xout] = src[j];
}

// ---------------------------------------------------------------------------
// FFT cols pass: CB adjacent columns per block (coalesced). src/dst may alias.
// ---------------------------------------------------------------------------
template<int N, int CB>
__global__ __launch_bounds__(512)
void ps_fft_cols(float2* __restrict__ dst, const float2* __restrict__ src,
                 int simg, int dimg,
                 float dir, int xin, int xout, float scale,
                 int sop, float* __restrict__ rdst, int rimg,
                 double* __restrict__ mout)
{
  constexpr int T = 512;
  constexpr int LCB = (CB==2)?1:(CB==4)?2:(CB==8)?3:4;
  constexpr int NB = N / CB;
  constexpr int NE = N*CB;
  __shared__ float2 smem[2*NE];
  float2* sA = smem; float2* sB = smem + NE;
  const int t = threadIdx.x;
  const int img = blockIdx.x / NB;
  const int c0 = (blockIdx.x % NB) * CB;
  const float2* sbase = src + (size_t)img*(size_t)simg + c0;
  float2* dbase = dst + (size_t)img*(size_t)dimg + c0;

  for (int e = t; e < NE; e += T){
    int j = e >> LCB, c = e & (CB - 1);
    sA[e] = sbase[(size_t)(j ^ xin)*N + c];
  }
  __syncthreads();
  float2* cur = sA; float2* oth = sB;
  for (int Ns = 1; Ns < N; Ns <<= 1){
    for (int q = t; q < (N/2)*CB; q += T){
      int c  = q & (CB - 1);
      int tt = q >> LCB;
      int k  = tt & (Ns - 1);
      float2 i0 = cur[tt*CB + c], i1 = cur[(tt + N/2)*CB + c];
      float2 tv;
      if (Ns == 1){
        tv = i1;
      } else {
        float ang = dir * (float)PI_D * (float)k / (float)Ns;
        float sw, cw; __sincosf(ang, &sw, &cw);
        tv = make_float2(cw*i1.x - sw*i1.y, cw*i1.y + sw*i1.x);
      }
      int d = ((tt - k) << 1) + k;
      oth[d*CB + c]        = make_float2(i0.x + tv.x, i0.y + tv.y);
      oth[(d + Ns)*CB + c] = make_float2(i0.x - tv.x, i0.y - tv.y);
    }
    __syncthreads();
    float2* tmp = cur; cur = oth; oth = tmp;
  }
  if (sop == SOP_REAL){
    for (int e = t; e < NE; e += T){
      int j = e >> LCB, c = e & (CB - 1);
      rdst[(size_t)img*(size_t)rimg + (size_t)(j ^ xout)*N + c0 + c] = cur[j*CB + c].x * scale;
    }
  } else if (sop == SOP_NONE){
    for (int e = t; e < NE; e += T){
      int j = e >> LCB, c = e & (CB - 1);
      float2 v = cur[j*CB + c];
      dbase[(size_t)(j ^ xout)*N + c] = make_float2(v.x*scale, v.y*scale);
    }
  }
  if (mout){
    float acc[5] = {0.f,0.f,0.f,0.f,0.f};
    for (int e = t; e < NE; e += T){
      float r = cur[e].x * scale, r2 = r*r;
      acc[0] += r; acc[1] += r2; acc[2] += r2*r; acc[3] += r2*r2; acc[4] += fabsf(r);
    }
    block_reduce_add<5, 8>(acc, mout);
  }
}

// ---------------------------------------------------------------------------
// spatial circular autocorrelation, 9x9 lags, ALL 21 arrays in ONE launch.
// R[d] = sum_p x(p) x(p+d); 41 accumulators exploiting R[-d]=R[d].
// ---------------------------------------------------------------------------
#define MAX_AC_TASKS 9
struct AcTaskTab {
  const void* src[MAX_AC_TASKS];
  int isMag[MAX_AC_TASKS];
  int H[MAX_AC_TASKS];
  int npi[MAX_AC_TASKS];
  int nb[MAX_AC_TASKS];
  int stOff[MAX_AC_TASKS];
  int stStride[MAX_AC_TASKS];
  int blkStart[MAX_AC_TASKS+1];
  int nTasks;
};

__global__ __launch_bounds__(256, 1)
void ps_spat_ac_multi(AcTaskTab tt, double* __restrict__ ST)
{
  __shared__ float tile[40*40];
  const int gb = blockIdx.x;
  int tk = 0;
  while (tk + 1 < tt.nTasks && gb >= tt.blkStart[tk+1]) tk++;
  const int lb  = gb - tt.blkStart[tk];
  const int nb  = tt.nb[tk];
  const int img = lb / nb;
  const int b0  = lb - img*nb;
  const int H = tt.H[tk];
  const int n_per_img = tt.npi[tk];
  const int isMag = tt.isMag[tk];
  const void* vsrc = tt.src[tk];
  const int t = threadIdx.x;
  const int tilesX = H >> 5;
  const int tiles = tilesX * tilesX;
  float acc[41];
  #pragma unroll
  for (int k = 0; k < 41; k++) acc[k] = 0.f;

  for (int tl = b0; tl < tiles; tl += nb){
    int by = tl / tilesX, bx = tl - by*tilesX;
    int y0 = by << 5, x0 = bx << 5;
    __syncthreads();
    for (int e = t; e < 40*40; e += 256){
      int ly = e / 40, lx = e - ly*40;
      int gy = (y0 + ly - 4) & (H - 1);
      int gx = (x0 + lx - 4) & (H - 1);
      float v;
      if (isMag){
        float2 c = ((const float2*)vsrc)[(size_t)img*n_per_img + (size_t)gy*H + gx];
        v = sqrtf(c.x*c.x + c.y*c.y);
      } else {
        v = ((const float*)vsrc)[(size_t)img*n_per_img + (size_t)gy*H + gx];
      }
      tile[e] = v;
    }
    __syncthreads();
    for (int p = t; p < 32*32; p += 256){
      int py = p >> 5, px = p & 31;
      const float* row0 = tile + (py+4)*40 + (px+4);
      float c = row0[0];
      #pragma unroll
      for (int dx = 0; dx <= 4; dx++)
        acc[dx] += c * row0[dx];
      #pragma unroll
      for (int dy = 1; dy <= 4; dy++){
        const float* rw = row0 + dy*40;
        #pragma unroll
        for (int dx = -4; dx <= 4; dx++)
          acc[5 + (dy-1)*9 + (dx+4)] += c * rw[dx];
      }
    }
  }
  block_reduce_add<41, 4>(acc, ST + tt.stOff[tk] + (size_t)img*tt.stStride[tk]);
}

// ---------------------------------------------------------------------------
// elementwise kernels (float masks)
// ---------------------------------------------------------------------------
__global__ __launch_bounds__(256)
void ps_mask_hl(float2* __restrict__ lo_dst, float2* __restrict__ hi_dst,
                const float2* __restrict__ src){
  int i = blockIdx.x*blockDim.x + threadIdx.x;
  if (i >= 1024*1024) return;
  int y = i >> 10, x = i & 1023;
  float lr, ang; polar_f(y, x, lr, ang);
  float2 v = src[i];
  float lo = f_lo(lr, 0.f), hi = f_hi(lr, 0.f);
  lo_dst[i] = make_float2(v.x*lo, v.y*lo);
  hi_dst[i] = make_float2(v.x*hi, v.y*hi);
}
__global__ __launch_bounds__(256)
void ps_band_mask4(float2* __restrict__ dst, const float2* __restrict__ src,
                   int H, int off, float shift){
  int i = blockIdx.x*blockDim.x + threadIdx.x;
  int n = H*H;
  if (i >= n) return;
  int y = i / H, x = i - y*H;
  float lr, ang; polar_f(off + y, off + x, lr, ang);
  float hm = f_hi(lr, shift);
  float2 v = src[i];
  #pragma unroll
  for (int b = 0; b < 4; b++){
    float a0 = ang - (PI_F*0.25f)*(float)b + PI_F;
    float a = fmodf(a0, 2.f*PI_F);
    if (a < 0.f) a += 2.f*PI_F;
    a -= PI_F;
    float mk = 0.f;
    if (fabsf(a) < PI_F*0.5f){ float c = cosf(a); mk = 1.78885438199983f*c*c*c; }
    float mf = hm*mk;
    dst[(size_t)b*n + i] = make_float2(-mf*v.y, mf*v.x);
  }
}
__global__ __launch_bounds__(256)
void ps_crop_lo(float2* dst, const float2* src, int Hs, int offNew, float shift){
  int Hd = Hs/2;
  int i = blockIdx.x*blockDim.x + threadIdx.x;
  if (i >= Hd*Hd) return;
  int y = i / Hd, x = i - y*Hd;
  float lr, ang; polar_f(offNew + y, offNew + x, lr, ang);
  float mk = f_lo(lr, shift);
  float2 v = src[(y + Hs/4)*Hs + (x + Hs/4)];
  dst[i] = make_float2(v.x*mk, v.y*mk);
}

// ---------------------------------------------------------------------------
// reductions
// ---------------------------------------------------------------------------
__global__ void ps_init_mm(unsigned* mm){ mm[0] = 0xFFFFFFFFu; mm[1] = 0u; }

__global__ __launch_bounds__(256, 1)
void ps_im_stats(const float4* __restrict__ x4, int n4, double* out, unsigned* mm){
  float acc[4] = {0.f,0.f,0.f,0.f};
  float mn = INFINITY, mx = -INFINITY;
  for (int i = blockIdx.x*blockDim.x + threadIdx.x; i < n4; i += gridDim.x*blockDim.x){
    float4 v = x4[i];
    float a0 = v.x, a1 = v.y, a2 = v.z, a3 = v.w;
    acc[0] += a0 + a1 + a2 + a3;
    acc[1] += a0*a0 + a1*a1 + a2*a2 + a3*a3;
    acc[2] += a0*a0*a0 + a1*a1*a1 + a2*a2*a2 + a3*a3*a3;
    acc[3] += a0*a0*a0*a0 + a1*a1*a1*a1 + a2*a2*a2*a2 + a3*a3*a3*a3;
    mn = fminf(mn, fminf(fminf(a0,a1), fminf(a2,a3)));
    mx = fmaxf(mx, fmaxf(fmaxf(a0,a1), fmaxf(a2,a3)));
  }
  block_reduce_add<4, 4>(acc, out);
  #pragma unroll
  for (int o = 32; o > 0; o >>= 1){
    mn = fminf(mn, __shfl_down(mn, o, 64));
    mx = fmaxf(mx, __shfl_down(mx, o, 64));
  }
  if ((threadIdx.x & 63) == 0){
    atomicMin(&mm[0], encf(mn));
    atomicMax(&mm[1], encf(mx));
  }
}

// all 4 scales in one launch; blockIdx.y = s; idle blocks exit early.
struct ScaleATab { const float2* b[4]; int n[4]; };
__global__ __launch_bounds__(256, 1)
void ps_scaleA_multi(ScaleATab tt, double* __restrict__ ST){
  int s = blockIdx.y;
  int n = tt.n[s];
  if ((size_t)blockIdx.x*blockDim.x >= (size_t)n) return;
  const float2* bb = tt.b[s];
  double* outp = ST + 64 + s*32;
  float acc[28];
  #pragma unroll
  for (int k = 0; k < 28; k++) acc[k] = 0.f;
  for (int i = blockIdx.x*blockDim.x + threadIdx.x; i < n; i += gridDim.x*blockDim.x){
    float2 v0 = bb[i], v1 = bb[(size_t)n + i], v2 = bb[2*(size_t)n + i], v3 = bb[3*(size_t)n + i];
    float ab[4] = { sqrtf(v0.x*v0.x+v0.y*v0.y), sqrtf(v1.x*v1.x+v1.y*v1.y),
                    sqrtf(v2.x*v2.x+v2.y*v2.y), sqrtf(v3.x*v3.x+v3.y*v3.y) };
    float re[4] = { v0.x, v1.x, v2.x, v3.x };
    #pragma unroll
    for (int a = 0; a < 4; a++){
      #pragma unroll
      for (int c = a; c < 4; c++){
        acc[P4(a,c)]      += ab[a]*ab[c];
        acc[10 + P4(a,c)] += re[a]*re[c];
      }
      acc[20 + a] += ab[a];
      acc[24 + a] += re[a];
    }
  }
  block_reduce_add<28, 4>(acc, outp);
}
__global__ __launch_bounds__(256, 1)
void ps_scaleB(const float2* __restrict__ u0, const float2* __restrict__ u1,
               const float2* __restrict__ u2, const float2* __restrict__ u3,
               const float2* __restrict__ s0, const float2* __restrict__ s1,
               const float2* __restrict__ s2, const float2* __restrict__ s3,
               int n, double* out){
  float acc[72];
  #pragma unroll
  for (int k = 0; k < 72; k++) acc[k] = 0.f;
  for (int i = blockIdx.x*blockDim.x + threadIdx.x; i < n; i += gridDim.x*blockDim.x){
    float2 u[4] = { u0[i], u1[i], u2[i], u3[i] };
    float2 bb[4] = { s0[i], s1[i], s2[i], s3[i] };
    float au[4], dre[4], dim[4], M[4], R[4];
    #pragma unroll
    for (int c = 0; c < 4; c++){
      float xx = u[c].x, yy = u[c].y;
      float mag = sqrtf(xx*xx + yy*yy);
      float den = mag + 1e-12f;
      au[c] = mag;
      dre[c] = (xx*xx - yy*yy)/den;
      dim[c] = (2.f*xx*yy)/den;
      M[c] = sqrtf(bb[c].x*bb[c].x + bb[c].y*bb[c].y);
      R[c] = bb[c].x;
    }
    #pragma unroll
    for (int c = 0; c < 4; c++){
      acc[c]      += au[c];
      acc[4 + c]  += au[c]*au[c];
      acc[24 + c] += dre[c];
      acc[28 + c] += dim[c];
      acc[32 + c] += dre[c]*dre[c];
      acc[36 + c] += dim[c]*dim[c];
    }
    #pragma unroll
    for (int a = 0; a < 4; a++)
      #pragma unroll
      for (int c = 0; c < 4; c++){
        acc[8 + a*4 + c]  += M[a]*au[c];
        acc[40 + a*4 + c] += R[a]*dre[c];
        acc[56 + a*4 + c] += R[a]*dim[c];
      }
  }
  block_reduce_add<72, 4>(acc, out);
}
__global__ __launch_bounds__(256, 1)
void ps_scaleC(const float2* __restrict__ s0, const float2* __restrict__ s1,
               const float2* __restrict__ s2, const float2* __restrict__ s3,
               const float* __restrict__ lp, int n, double* out){
  float acc[36];
  #pragma unroll
  for (int k = 0; k < 36; k++) acc[k] = 0.f;
  for (int i = blockIdx.x*blockDim.x + threadIdx.x; i < n; i += gridDim.x*blockDim.x){
    int y = i >> 7, x = i & 127;
    float L[5];
    L[0] = lp[i];
    L[1] = lp[(y << 7) | ((x + 126) & 127)];
    L[2] = lp[(y << 7) | ((x + 2) & 127)];
    L[3] = lp[(((y + 126) & 127) << 7) | x];
    L[4] = lp[(((y + 2) & 127) << 7) | x];
    float R[4] = { s0[i].x, s1[i].x, s2[i].x, s3[i].x };
    acc[0] += L[0];
    #pragma unroll
    for (int a = 0; a < 5; a++)
      #pragma unroll
      for (int c = a; c < 5; c++)
        acc[1 + P5(a,c)] += L[a]*L[c];
    #pragma unroll
    for (int a = 0; a < 4; a++)
      #pragma unroll
      for (int j = 0; j < 5; j++)
        acc[16 + a*5 + j] += R[a]*L[j];
  }
  block_reduce_add<36, 4>(acc, out);
}

// ---------------------------------------------------------------------------
// finalize — ONE THREAD PER OUTPUT ELEMENT (round-7 lesson: serial finalize
// thread = 57us latency chain; every output is independent given ST).
// ST layout: [0..3] image moments; [4..8] hipass s1,s2,s3,s4,sabs
//  [10+r*6 ..] recon r: s1..s4,sabs; [64+s*32] scaleA(28)
//  [192+s*80] scaleB(72); [432..467] scaleC(36)
//  [512+r*48] recon AC R[41]; [752+(s*4+b)*48] band-mag AC R[41]
// ---------------------------------------------------------------------------
__device__ __forceinline__ double d_ns(int s){ double h = (double)(1024 >> s); return h*h; }
__device__ __forceinline__ void d_moments(const double* Mo, double n,
                                          double& sk, double& ku, double& var){
  double m = Mo[0]/n, e2 = Mo[1]/n, e3 = Mo[2]/n, e4 = Mo[3]/n;
  var = e2 - m*m;
  double c3 = e3 - 3.0*m*e2 + 2.0*m*m*m;
  double c4 = e4 - 4.0*m*e3 + 6.0*m*m*e2 - 3.0*m*m*m*m;
  sk = c3/pow(var,1.5); ku = c4/(var*var);
}
__device__ __forceinline__ int ac_o(int w, int& dy, int& dx){
  dy = w/9 - 4; dx = w - (w/9)*9 - 4;
  int ady = dy, adx = dx;
  if (dy < 0 || (dy == 0 && dx < 0)){ ady = -dy; adx = -dx; }
  return (ady == 0) ? adx : (5 + (ady-1)*9 + (adx+4));
}

__global__ __launch_bounds__(256)
void ps_finalize(const double* __restrict__ ST, const unsigned* __restrict__ MM,
                 float* __restrict__ out, int out_size){
  int idx = blockIdx.x*blockDim.x + threadIdx.x;
  if (idx >= out_size) return;
  const double n0 = 1048576.0;
  double val = 0.0;

  if (idx <= 5){
    if (idx == 4){ out[4] = decf(MM[0]); return; }
    if (idx == 5){ out[5] = decf(MM[1]); return; }
    double sk, ku, v; d_moments(ST, n0, sk, ku, v);
    val = (idx == 0) ? ST[0]/n0 : (idx == 1) ? v : (idx == 2) ? sk : ku;
  } else if (idx == 6){
    val = ST[8]/n0;
  } else if (idx <= 22){
    int i = idx - 7; int s = i >> 2, b = i & 3;
    val = ST[64 + s*32 + 20 + b] / d_ns(s);
  } else if (idx == 23){
    val = ST[10 + 4*6 + 4] / 4096.0;
  } else if (idx <= 1319){                      // band-mag ACs
    int i = idx - 24; int w = i >> 4; int j = i & 15;
    int s = j >> 2, b = j & 3;
    double n = d_ns(s);
    const double* R = ST + 752 + j*48;
    double mu = ST[64 + s*32 + 20 + b]/n, mu2 = mu*mu;
    int dy, dx; int o = ac_o(w, dy, dx);
    val = (R[o]/n - mu2) / (R[0]/n - mu2 + 1e-12);
  } else if (idx <= 1329){                      // skew_r / kurt_r
    int i = idx - 1320; bool kq = (i >= 5); int r = kq ? i - 5 : i;
    double n = (r == 4) ? 4096.0 : d_ns(r);
    double sk, ku, v; d_moments(ST + 10 + r*6, n, sk, ku, v);
    val = kq ? ku : sk;
  } else if (idx <= 1734){                      // recon ACs
    int i = idx - 1330; int w = i / 5; int r = i - w*5;
    double n = (r == 4) ? 4096.0 : d_ns(r);
    const double* R = ST + 512 + r*48;
    double mu = ST[10 + r*6]/n, mu2 = mu*mu;
    int dy, dx; int o = ac_o(w, dy, dx);
    val = (R[o]/n - mu2) / (R[0]/n - mu2 + 1e-12);
  } else if (idx <= 1739){                      // std_r
    int r = idx - 1735;
    double n = (r == 4) ? 4096.0 : d_ns(r);
    double sk, ku, v; d_moments(ST + 10 + r*6, n, sk, ku, v);
    val = sqrt(v);
  } else if (idx <= 1819){                      // com (|b| gram)
    int i = idx - 1740; int s = i % 5; int q = i / 5; int a = q >> 2, b = q & 3;
    if (s < 4){
      double n = d_ns(s); const double* A = ST + 64 + s*32;
      double ma = A[20+a]/n, mb = A[20+b]/n;
      double caa = A[P4(a,a)]/n - ma*ma, cbb = A[P4(b,b)]/n - mb*mb;
      int lo = a < b ? a : b, hi = a < b ? b : a;
      double cab = A[P4(lo,hi)]/n - ma*mb;
      val = cab / (sqrt(caa)*sqrt(cbb) + 1e-12);
    }
  } else if (idx <= 1883){                      // csm
    int i = idx - 1820; int s = i & 3; int q = i >> 2; int a = q >> 2, c = q & 3;
    if (s < 3){
      double n = d_ns(s); const double* A = ST + 64 + s*32; const double* B = ST + 192 + s*80;
      double mM = A[20+a]/n; double sdM = sqrt(A[P4(a,a)]/n - mM*mM);
      double mU = B[c]/n;    double sdU = sqrt(B[4+c]/n - mU*mU);
      val = (B[8 + a*4 + c]/n - mM*mU) / (sdM*sdU + 1e-12);
    }
  } else if (idx <= 2203){                      // cor
    int i = idx - 1884; int s = i % 5; int q = i / 5; int a = q >> 3, b = q & 7;
    if (s < 4){
      if (a < 4 && b < 4){
        double n = d_ns(s); const double* A = ST + 64 + s*32;
        double ma = A[24+a]/n, mb = A[24+b]/n;
        double caa = A[10+P4(a,a)]/n - ma*ma, cbb = A[10+P4(b,b)]/n - mb*mb;
        int lo = a < b ? a : b, hi = a < b ? b : a;
        double cab = A[10+P4(lo,hi)]/n - ma*mb;
        val = cab / (sqrt(caa)*sqrt(cbb) + 1e-12);
      }
    } else {
      if (a < 5 && b < 5){
        const double* C = ST + 432; const double n3 = 16384.0;
        double lb = C[0]/n3;
        double caa = C[1+P5(a,a)]/n3 - lb*lb, cbb = C[1+P5(b,b)]/n3 - lb*lb;
        int lo = a < b ? a : b, hi = a < b ? b : a;
        double cab = C[1+P5(lo,hi)]/n3 - lb*lb;
        val = cab / (sqrt(caa)*sqrt(cbb) + 1e-12);
      }
    }
  } else if (idx <= 2459){                      // csr
    int i = idx - 2204; int s = i & 3; int q = i >> 2; int a = q >> 3, c = q & 7;
    if (a < 4){
      double n = d_ns(s); const double* A = ST + 64 + s*32;
      double mR = A[24+a]/n; double sdR = sqrt(A[10+P4(a,a)]/n - mR*mR);
      if (s < 3 && c < 8){
        const double* B = ST + 192 + s*80;
        if (c < 4){
          double md = B[24+c]/n; double sd = sqrt(B[32+c]/n - md*md);
          val = (B[40 + a*4 + c]/n - mR*md) / (sdR*sd + 1e-12);
        } else {
          int cc = c - 4;
          double md = B[28+cc]/n; double sd = sqrt(B[36+cc]/n - md*md);
          val = (B[56 + a*4 + cc]/n - mR*md) / (sdR*sd + 1e-12);
        }
      } else if (s == 3 && c < 5){
        const double* C = ST + 432; const double n3 = 16384.0;
        double lb = C[0]/n3;
        double sdL = sqrt(C[1+P5(c,c)]/n3 - lb*lb);
        val = (C[16 + a*5 + c]/n3 - mR*lb) / (sdR*sdL + 1e-12);
      }
    }
  } else {                                      // 2460: var_hp
    val = ST[5]/n0 - (ST[4]/n0)*(ST[4]/n0);
  }
  out[idx] = (float)val;
}

// ---------------------------------------------------------------------------
// host orchestration
// ---------------------------------------------------------------------------
static void rows_pass(int H, float2* dst, const void* src,
                      int nimg, int simg, int dimg, int srcH1,
                      float dir, int xin, int xout, int lop, hipStream_t st){
  dim3 g(nimg * H);
  switch (H){
    case 64:   ps_fft_rows<64>  <<<g, 64,  0, st>>>(dst, src, simg, dimg, srcH1, dir, xin, xout, lop); break;
    case 128:  ps_fft_rows<128> <<<g, 64,  0, st>>>(dst, src, simg, dimg, srcH1, dir, xin, xout, lop); break;
    case 256:  ps_fft_rows<256> <<<g, 128, 0, st>>>(dst, src, simg, dimg, srcH1, dir, xin, xout, lop); break;
    case 512:  ps_fft_rows<512> <<<g, 256, 0, st>>>(dst, src, simg, dimg, srcH1, dir, xin, xout, lop); break;
    case 1024: ps_fft_rows<1024><<<g, 512, 0, st>>>(dst, src, simg, dimg, srcH1, dir, xin, xout, lop); break;
    default: break;
  }
}
static void cols_pass(int H, float2* dst, const float2* src, int nimg, int simg, int dimg,
                      float dir, int xin, int xout, float scale,
                      int sop, float* rdst, int rimg, double* mout, hipStream_t st){
  switch (H){
    case 64:   ps_fft_cols<64,16>  <<<dim3(nimg*(64/16)),  512, 0, st>>>(dst, src, simg, dimg, dir, xin, xout, scale, sop, rdst, rimg, mout); break;
    case 128:  ps_fft_cols<128,16> <<<dim3(nimg*(128/16)), 512, 0, st>>>(dst, src, simg, dimg, dir, xin, xout, scale, sop, rdst, rimg, mout); break;
    case 256:  ps_fft_cols<256,8>  <<<dim3(nimg*(256/8)),  512, 0, st>>>(dst, src, simg, dimg, dir, xin, xout, scale, sop, rdst, rimg, mout); break;
    case 512:  ps_fft_cols<512,8>  <<<dim3(nimg*(512/8)),  512, 0, st>>>(dst, src, simg, dimg, dir, xin, xout, scale, sop, rdst, rimg, mout); break;
    case 1024: ps_fft_cols<1024,4> <<<dim3(nimg*(1024/4)), 512, 0, st>>>(dst, src, simg, dimg, dir, xin, xout, scale, sop, rdst, rimg, mout); break;
    default: break;
  }
}

static inline dim3 gr(int n){ return dim3((n + 255)/256); }
static inline int  rblocks(int n){ int b = (n + 255)/256; return b > 512 ? 512 : b; }

#define FWD (-1.0f)
#define INV (+1.0f)

extern "C" void kernel_launch(void* const* d_in, const int* in_sizes, int n_in,
                              void* d_out, int out_size, void* d_ws, size_t ws_size,
                              hipStream_t stream){
  (void)in_sizes; (void)n_in;
  const float* im = (const float*)d_in[0];
  float* out = (float*)d_out;

  const int Hs[5]   = {1024, 512, 256, 128, 64};
  const int offs[5] = {0, 256, 384, 448, 480};

  // ---- carve workspace ----
  char* base = (char*)d_ws;
  size_t off = 0;
  auto carve = [&](size_t bytes)->void*{
    void* r = base + off;
    off = (off + bytes + 255) & ~(size_t)255;
    return r;
  };
  float2* lod[5];
  for (int s = 0; s < 5; s++) lod[s] = (float2*)carve((size_t)Hs[s]*Hs[s]*sizeof(float2));
  float2* band[4];
  for (int s = 0; s < 4; s++) band[s] = (float2*)carve((size_t)4*Hs[s]*Hs[s]*sizeof(float2));
  float2* bdft[4];
  bdft[0] = nullptr;
  for (int s = 1; s < 4; s++) bdft[s] = (float2*)carve((size_t)4*Hs[s]*Hs[s]*sizeof(float2));
  float* recon[5];
  for (int s = 0; s < 5; s++) recon[s] = (float*)carve((size_t)Hs[s]*Hs[s]*sizeof(float));
  float* lp = (float*)carve(128*128*sizeof(float));
  float2* scr  = (float2*)carve((size_t)1024*1024*sizeof(float2));
  float2* scr4 = (float2*)carve((size_t)4*1024*1024*sizeof(float2));
  double* ST = (double*)carve(2048*sizeof(double));
  unsigned* MM = (unsigned*)carve(64*sizeof(unsigned));
  if (off > ws_size) return;

  // ---- init ----
  hipMemsetAsync(ST, 0, 2048*sizeof(double), stream);
  ps_init_mm<<<1, 1, 0, stream>>>(MM);

  const int n0 = 1024*1024;
  ps_im_stats<<<256, 256, 0, stream>>>((const float4*)im, n0/4, ST + 0, MM);

  // ---- imdft (shifted) ----
  rows_pass(1024, scr, im, 1, 0, 0, 0, FWD, 0, 512, LOP_R2C, stream);
  cols_pass(1024, scr, scr, 1, 0, 0, FWD, 0, 512, 1.0f, SOP_NONE, nullptr, 0, nullptr, stream);
  ps_mask_hl<<<gr(n0), 256, 0, stream>>>(lod[0], scr, scr);
  rows_pass(1024, scr, scr, 1, 0, 0, 0, INV, 512, 0, LOP_NONE, stream);
  cols_pass(1024, scr, scr, 1, 0, 0, INV, 512, 0, 1.0f/(float)n0, SOP_STATS, nullptr, 0, ST + 4, stream);

  // ---- pyramid scales: recon (stored + stats), bands, next lowpass ----
  for (int s = 0; s < 4; s++){
    int H = Hs[s], n = H*H;
    float invn = 1.0f/((float)H*(float)H);
    rows_pass(H, scr, lod[s], 1, 0, 0, 0, INV, H/2, 0, LOP_NONE, stream);
    cols_pass(H, scr, scr, 1, 0, 0, INV, H/2, 0, invn, SOP_REAL, recon[s], 0, ST + 10 + s*6, stream);
    float2* bq = (s == 0) ? scr4 : bdft[s];
    ps_band_mask4<<<gr(n), 256, 0, stream>>>(bq, lod[s], H, offs[s], -(float)(s+1));
    rows_pass(H, band[s], bq, 4, n, n, 0, INV, H/2, 0, LOP_NONE, stream);
    cols_pass(H, band[s], band[s], 4, n, n, INV, H/2, 0, invn, SOP_NONE, nullptr, 0, nullptr, stream);
    ps_crop_lo<<<gr((H/2)*(H/2)), 256, 0, stream>>>(lod[s+1], lod[s], H, offs[s+1], -(float)(s+1));
  }
  rows_pass(64, scr, lod[4], 1, 0, 0, 0, INV, 32, 0, LOP_NONE, stream);
  cols_pass(64, scr, scr, 1, 0, 0, INV, 32, 0, 1.0f/4096.f, SOP_REAL, recon[4], 0, ST + 10 + 4*6, stream);

  // ---- all 21 autocorrelations in one launch ----
  {
    AcTaskTab tt{};
    int nt = 0, blk = 0;
    for (int r = 0; r < 5; r++){
      int H = Hs[r]; int tiles = (H>>5)*(H>>5); int nb = tiles < 128 ? tiles : 128;
      tt.src[nt] = recon[r]; tt.isMag[nt] = 0; tt.H[nt] = H; tt.npi[nt] = H*H;
      tt.nb[nt] = nb; tt.stOff[nt] = 512 + r*48; tt.stStride[nt] = 48;
      tt.blkStart[nt] = blk; blk += nb; nt++;
    }
    for (int s = 0; s < 4; s++){
      int H = Hs[s]; int tiles = (H>>5)*(H>>5); int nb = tiles < 128 ? tiles : 128;
      tt.src[nt] = band[s]; tt.isMag[nt] = 1; tt.H[nt] = H; tt.npi[nt] = H*H;
      tt.nb[nt] = nb; tt.stOff[nt] = 752 + s*4*48; tt.stStride[nt] = 48;
      tt.blkStart[nt] = blk; blk += nb*4; nt++;
    }
    tt.blkStart[nt] = blk; tt.nTasks = nt;
    ps_spat_ac_multi<<<dim3(blk), 256, 0, stream>>>(tt, ST);
  }

  // ---- per-scale band Grams (one launch) ----
  {
    ScaleATab ta{};
    for (int s = 0; s < 4; s++){ ta.b[s] = band[s]; ta.n[s] = Hs[s]*Hs[s]; }
    ps_scaleA_multi<<<dim3(512, 4), 256, 0, stream>>>(ta, ST);
  }

  // ---- cross-scale: pad kept band DFTs directly ----
  for (int s = 0; s < 3; s++){
    int H1 = Hs[s+1], H2 = Hs[s];
    int n1 = H1*H1, n2 = H2*H2;
    rows_pass(H2, scr4, bdft[s+1], 4, n1, n2, H1, INV, H2/2, 0, LOP_PAD, stream);
    cols_pass(H2, scr4, scr4, 4, n2, n2, INV, H2/2, 0, 1.0f/(float)n1, SOP_NONE, nullptr, 0, nullptr, stream);
    ps_scaleB<<<rblocks(n2), 256, 0, stream>>>(scr4, scr4+n2, scr4+2*n2, scr4+3*n2,
                                               band[s], band[s]+n2, band[s]+2*n2, band[s]+3*n2,
                                               n2, ST + 192 + s*80);
  }
  // s=3: expand2(lowpass) = pad lod[4] directly
  rows_pass(128, scr4, lod[4], 1, 4096, 16384, 64, INV, 64, 0, LOP_PAD, stream);
  cols_pass(128, scr4, scr4, 1, 16384, 16384, INV, 64, 0, 1.0f/4096.f, SOP_REAL, lp, 0, nullptr, stream);
  ps_scaleC<<<rblocks(16384), 256, 0, stream>>>(band[3], band[3]+16384, band[3]+2*16384, band[3]+3*16384,
                                                lp, 16384, ST + 432);

  // ---- finalize: one thread per output element ----
  ps_finalize<<<gr(out_size), 256, 0, stream>>>(ST, MM, out, out_size);
}

// Round 9
// 503.988 us; speedup vs baseline: 1.7251x; 1.1354x over previous
//
#include <hip/hip_runtime.h>
#include <math.h>

#define PI_F 3.14159265358979323846f

enum { LOP_NONE=0, LOP_R2C, LOP_PAD };
enum { SOP_NONE=0, SOP_REAL };

// ---------------------------------------------------------------------------
// helpers
// ---------------------------------------------------------------------------
__host__ __device__ constexpr int P4(int a, int b){ return a*4 - a*(a-1)/2 + (b-a); }
__host__ __device__ constexpr int P5(int a, int b){ return a*5 - a*(a-1)/2 + (b-a); }

__device__ __forceinline__ unsigned encf(float f){
  unsigned u = __float_as_uint(f);
  return (u & 0x80000000u) ? ~u : (u | 0x80000000u);
}
__device__ __forceinline__ float decf(unsigned u){
  unsigned b = (u & 0x80000000u) ? (u ^ 0x80000000u) : ~u;
  return __uint_as_float(b);
}
__device__ __forceinline__ float2 cxmul(float2 a, float c, float s){
  return make_float2(c*a.x - s*a.y, c*a.y + s*a.x);
}
__device__ __forceinline__ float2 f2add(float2 a, float2 b){ return make_float2(a.x+b.x, a.y+b.y); }
__device__ __forceinline__ float2 f2sub(float2 a, float2 b){ return make_float2(a.x-b.x, a.y-b.y); }

// wave shuffle-reduce -> LDS -> ONE atomicAdd per counter per block.
template<int CNT, int WAVES>
__device__ __forceinline__ void block_reduce_add(float (&acc)[CNT], double* out){
  __shared__ float red[WAVES*CNT];
  int lane = threadIdx.x & 63;
  int wid  = threadIdx.x >> 6;
  #pragma unroll
  for (int k = 0; k < CNT; k++){
    float v = acc[k];
    #pragma unroll
    for (int o = 32; o > 0; o >>= 1) v += __shfl_down(v, o, 64);
    if (lane == 0) red[wid*CNT + k] = v;
  }
  __syncthreads();
  int t = threadIdx.x;
  if (t < CNT){
    double s = 0.0;
    #pragma unroll
    for (int w = 0; w < WAVES; w++) s += (double)red[w*CNT + t];
    atomicAdd(&out[t], s);
  }
  __syncthreads();
}

// float polar grid (ref computes masks in f64 then casts to f32; float error
// ~1e-7 rel vs 0.199 abs threshold)
__device__ __forceinline__ void polar_f(int iy, int ix, float& lr, float& ang){
  float yn = (float)(iy - 512) * (1.f/512.f);
  float xn = (float)(ix - 512) * (1.f/512.f);
  ang = atan2f(yn, xn);
  float rad = (iy == 512 && ix == 512) ? (1.f/512.f) : sqrtf(xn*xn + yn*yn);
  lr = log2f(rad);
}
__device__ __forceinline__ float f_hi(float lr, float shift){
  float v = fminf(fmaxf(lr - shift, -1.f), 0.f);
  return cosf((PI_F*0.5f) * v);
}
__device__ __forceinline__ float f_lo(float lr, float shift){
  float h = f_hi(lr, shift);
  float q = fminf(fmaxf(1.f - h*h, 0.f), 1.f);
  return sqrtf(q);
}

// ---------------------------------------------------------------------------
// In-place mixed radix-4/radix-2 Stockham over LDS (single buffer,
// read-all -> sync -> write-all). Generalizes the verified radix-2 form:
// stage: v_r = src[q + r*N/R] * e^{i r dir 2pi k/(R Ns)}, k = q mod Ns,
// butterfly DFT_R, dst[(q-k)*R + k + m*Ns] = y_m.
// ---------------------------------------------------------------------------

// radix-4 butterfly on v[4]; fwd: omega=-i
__device__ __forceinline__ void bfly4(float2* v, bool fwd){
  float2 A = f2add(v[0], v[2]), B = f2sub(v[0], v[2]);
  float2 C = f2add(v[1], v[3]), D = f2sub(v[1], v[3]);
  float2 dj = fwd ? make_float2(D.y, -D.x) : make_float2(-D.y, D.x);
  v[0] = f2add(A, C);
  v[1] = f2add(B, dj);
  v[2] = f2sub(A, C);
  v[3] = f2sub(B, dj);
}

// ---------------------------------------------------------------------------
// FFT rows pass: one line per block, out-of-place capable, fused load-op.
// ---------------------------------------------------------------------------
template<int N>
__global__ __launch_bounds__((N/4 < 64) ? 64 : N/4)
void ps_fft_rows(float2* __restrict__ dst, const void* __restrict__ vsrc,
                 int simg, int dimg, int srcH1,
                 float dir, int xin, int xout, int lop)
{
  constexpr int T = (N/4 < 64) ? 64 : N/4;
  __shared__ float2 sm[N];
  const int t = threadIdx.x;
  const int l = blockIdx.x & (N-1);
  const int img = blockIdx.x / N;
  float2* dline = dst + (size_t)img*(size_t)dimg + (size_t)l*N;

  if (lop == LOP_PAD){
    const int q = N/4;
    const int sl = l - q;
    if (sl < 0 || sl >= srcH1){
      for (int j = t; j < N; j += T) dline[j] = make_float2(0.f, 0.f);
      return;
    }
    const float2* s = (const float2*)vsrc + (size_t)img*simg + (size_t)sl*srcH1;
    for (int j = t; j < N; j += T){
      int p = j ^ xin;
      sm[j] = (p >= q && p < q + srcH1) ? s[p - q] : make_float2(0.f, 0.f);
    }
  } else if (lop == LOP_R2C){
    const float* s = (const float*)vsrc + (size_t)img*simg + (size_t)l*N;
    for (int j = t; j < N; j += T) sm[j] = make_float2(s[j ^ xin], 0.f);
  } else {
    const float2* s = (const float2*)vsrc + (size_t)img*simg + (size_t)l*N;
    for (int j = t; j < N; j += T) sm[j] = s[j ^ xin];
  }
  __syncthreads();

  const bool fwd = (dir < 0.f);
  int Ns = 1;
  if constexpr ((N & 0xAAAAAAAAu) != 0){           // odd log2: radix-2 first
    constexpr int NB2 = N/2;
    constexpr int P2 = (NB2 + T - 1)/T;
    float2 a[P2], b[P2];
    #pragma unroll
    for (int p = 0; p < P2; p++){
      int q = t + p*T;
      if (q < NB2){ a[p] = sm[q]; b[p] = sm[q + N/2]; }
    }
    __syncthreads();
    #pragma unroll
    for (int p = 0; p < P2; p++){
      int q = t + p*T;
      if (q < NB2){
        sm[2*q]   = f2add(a[p], b[p]);
        sm[2*q+1] = f2sub(a[p], b[p]);
      }
    }
    __syncthreads();
    Ns = 2;
  }
  constexpr int NB4 = N/4;
  for (; Ns < N; Ns <<= 2){
    float2 v[4];
    int q = t;
    int k = 0;
    if (q < NB4){
      k = q & (Ns - 1);
      #pragma unroll
      for (int r = 0; r < 4; r++) v[r] = sm[q + r*NB4];
      if (k){
        float ang = dir * (PI_F*0.5f) * (float)k / (float)Ns;
        float s1, c1; __sincosf(ang, &s1, &c1);
        float c2 = c1*c1 - s1*s1, s2 = 2.f*c1*s1;
        float c3 = c1*c2 - s1*s2, s3 = c1*s2 + s1*c2;
        v[1] = cxmul(v[1], c1, s1);
        v[2] = cxmul(v[2], c2, s2);
        v[3] = cxmul(v[3], c3, s3);
      }
      bfly4(v, fwd);
    }
    __syncthreads();
    if (q < NB4){
      int dd = ((q - k) << 2) + k;
      sm[dd]        = v[0];
      sm[dd + Ns]   = v[1];
      sm[dd + 2*Ns] = v[2];
      sm[dd + 3*Ns] = v[3];
    }
    __syncthreads();
  }
  for (int j = t; j < N; j += T) dline[j ^ xout] = sm[j];
}

// ---------------------------------------------------------------------------
// FFT cols pass: CB adjacent columns per block (coalesced). src/dst may alias.
// mout != null: accumulate 5 moments of (re*scale) into mout + img*mstride.
// ---------------------------------------------------------------------------
template<int N, int CB>
__global__ __launch_bounds__(512)
void ps_fft_cols(float2* __restrict__ dst, const float2* __restrict__ src,
                 int simg, int dimg,
                 float dir, int xin, int xout, float scale,
                 int sop, float* __restrict__ rdst, int rimg,
                 double* __restrict__ mout, int mstride)
{
  constexpr int T = 512;
  constexpr int LCB = (CB==2)?1:(CB==4)?2:(CB==8)?3:4;
  constexpr int NBK = N / CB;
  constexpr int NE = N*CB;
  __shared__ float2 sm[NE];
  const int t = threadIdx.x;
  const int img = blockIdx.x / NBK;
  const int c0 = (blockIdx.x % NBK) * CB;
  const float2* sbase = src + (size_t)img*(size_t)simg + c0;
  float2* dbase = dst + (size_t)img*(size_t)dimg + c0;

  for (int e = t; e < NE; e += T){
    int j = e >> LCB, c = e & (CB - 1);
    sm[e] = sbase[(size_t)(j ^ xin)*N + c];
  }
  __syncthreads();

  const bool fwd = (dir < 0.f);
  int Ns = 1;
  if constexpr ((N & 0xAAAAAAAAu) != 0){
    constexpr int NB2 = (N/2)*CB;
    constexpr int P2 = (NB2 + T - 1)/T;
    float2 a[P2], b[P2];
    #pragma unroll
    for (int p = 0; p < P2; p++){
      int q = t + p*T;
      if (q < NB2){
        int c = q & (CB-1), tt = q >> LCB;
        a[p] = sm[tt*CB + c];
        b[p] = sm[(tt + N/2)*CB + c];
      }
    }
    __syncthreads();
    #pragma unroll
    for (int p = 0; p < P2; p++){
      int q = t + p*T;
      if (q < NB2){
        int c = q & (CB-1), tt = q >> LCB;
        sm[(2*tt)*CB + c]   = f2add(a[p], b[p]);
        sm[(2*tt+1)*CB + c] = f2sub(a[p], b[p]);
      }
    }
    __syncthreads();
    Ns = 2;
  }
  constexpr int NB4 = (N/4)*CB;
  constexpr int PB = (NB4 + T - 1)/T;
  for (; Ns < N; Ns <<= 2){
    float2 v[PB][4];
    int kk[PB];
    #pragma unroll
    for (int p = 0; p < PB; p++){
      int q = t + p*T;
      if (q < NB4){
        int c = q & (CB-1), tt = q >> LCB;
        int k = tt & (Ns - 1);
        kk[p] = k;
        #pragma unroll
        for (int r = 0; r < 4; r++) v[p][r] = sm[(tt + r*(N/4))*CB + c];
        if (k){
          float ang = dir * (PI_F*0.5f) * (float)k / (float)Ns;
          float s1, c1; __sincosf(ang, &s1, &c1);
          float c2 = c1*c1 - s1*s1, s2 = 2.f*c1*s1;
          float c3 = c1*c2 - s1*s2, s3 = c1*s2 + s1*c2;
          v[p][1] = cxmul(v[p][1], c1, s1);
          v[p][2] = cxmul(v[p][2], c2, s2);
          v[p][3] = cxmul(v[p][3], c3, s3);
        }
        bfly4(v[p], fwd);
      }
    }
    __syncthreads();
    #pragma unroll
    for (int p = 0; p < PB; p++){
      int q = t + p*T;
      if (q < NB4){
        int c = q & (CB-1), tt = q >> LCB;
        int k = kk[p];
        int dd = ((tt - k) << 2) + k;
        sm[(dd)*CB + c]        = v[p][0];
        sm[(dd + Ns)*CB + c]   = v[p][1];
        sm[(dd + 2*Ns)*CB + c] = v[p][2];
        sm[(dd + 3*Ns)*CB + c] = v[p][3];
      }
    }
    __syncthreads();
  }

  if (sop == SOP_REAL){
    for (int e = t; e < NE; e += T){
      int j = e >> LCB, c = e & (CB - 1);
      rdst[(size_t)img*(size_t)rimg + (size_t)(j ^ xout)*N + c0 + c] = sm[j*CB + c].x * scale;
    }
  } else {
    for (int e = t; e < NE; e += T){
      int j = e >> LCB, c = e & (CB - 1);
      float2 v = sm[j*CB + c];
      dbase[(size_t)(j ^ xout)*N + c] = make_float2(v.x*scale, v.y*scale);
    }
  }
  if (mout){
    float acc[5] = {0.f,0.f,0.f,0.f,0.f};
    for (int e = t; e < NE; e += T){
      float r = sm[e].x * scale, r2 = r*r;
      acc[0] += r; acc[1] += r2; acc[2] += r2*r; acc[3] += r2*r2; acc[4] += fabsf(r);
    }
    block_reduce_add<5, 8>(acc, mout + (size_t)img*mstride);
  }
}

// ---------------------------------------------------------------------------
// spatial circular autocorrelation, 9x9 lags, ALL 21 arrays in ONE launch.
// register-blocked: 4 px per thread along x (round-8: 45 LDS reads/41 FMA
// was latency-bound; now 15 reads/41 FMA).
// ---------------------------------------------------------------------------
#define MAX_AC_TASKS 9
struct AcTaskTab {
  const void* src[MAX_AC_TASKS];
  int isMag[MAX_AC_TASKS];
  int H[MAX_AC_TASKS];
  int npi[MAX_AC_TASKS];
  int nb[MAX_AC_TASKS];
  int stOff[MAX_AC_TASKS];
  int stStride[MAX_AC_TASKS];
  int blkStart[MAX_AC_TASKS+1];
  int nTasks;
};

__global__ __launch_bounds__(256, 1)
void ps_spat_ac_multi(AcTaskTab tt, double* __restrict__ ST)
{
  __shared__ float tile[40*40];
  const int gb = blockIdx.x;
  int tk = 0;
  while (tk + 1 < tt.nTasks && gb >= tt.blkStart[tk+1]) tk++;
  const int lb  = gb - tt.blkStart[tk];
  const int nb  = tt.nb[tk];
  const int img = lb / nb;
  const int b0  = lb - img*nb;
  const int H = tt.H[tk];
  const int n_per_img = tt.npi[tk];
  const int isMag = tt.isMag[tk];
  const void* vsrc = tt.src[tk];
  const int t = threadIdx.x;
  const int tilesX = H >> 5;
  const int tiles = tilesX * tilesX;
  const int py  = t >> 3;          // 0..31
  const int px0 = (t & 7) << 2;    // 0,4,..,28
  float acc[41];
  #pragma unroll
  for (int k = 0; k < 41; k++) acc[k] = 0.f;

  for (int tl = b0; tl < tiles; tl += nb){
    int by = tl / tilesX, bx = tl - by*tilesX;
    int y0 = by << 5, x0 = bx << 5;
    __syncthreads();
    for (int e = t; e < 40*40; e += 256){
      int ly = e / 40, lx = e - ly*40;
      int gy = (y0 + ly - 4) & (H - 1);
      int gx = (x0 + lx - 4) & (H - 1);
      float v;
      if (isMag){
        float2 c = ((const float2*)vsrc)[(size_t)img*n_per_img + (size_t)gy*H + gx];
        v = sqrtf(c.x*c.x + c.y*c.y);
      } else {
        v = ((const float*)vsrc)[(size_t)img*n_per_img + (size_t)gy*H + gx];
      }
      tile[e] = v;
    }
    __syncthreads();
    {
      const float* row0 = tile + (py+4)*40 + (px0+4);
      float c0 = row0[0], c1 = row0[1], c2 = row0[2], c3 = row0[3];
      {
        float r[8];
        #pragma unroll
        for (int i = 0; i < 8; i++) r[i] = row0[i];
        #pragma unroll
        for (int dx = 0; dx <= 4; dx++)
          acc[dx] += c0*r[dx] + c1*r[dx+1] + c2*r[dx+2] + c3*r[dx+3];
      }
      #pragma unroll
      for (int dy = 1; dy <= 4; dy++){
        const float* rw = tile + (py+4+dy)*40 + px0;
        float r[12];
        #pragma unroll
        for (int i = 0; i < 12; i++) r[i] = rw[i];
        #pragma unroll
        for (int dx = -4; dx <= 4; dx++)
          acc[5 + (dy-1)*9 + (dx+4)] += c0*r[4+dx] + c1*r[5+dx] + c2*r[6+dx] + c3*r[7+dx];
      }
    }
  }
  block_reduce_add<41, 4>(acc, ST + tt.stOff[tk] + (size_t)img*tt.stStride[tk]);
}

// ---------------------------------------------------------------------------
// elementwise kernels (float masks)
// ---------------------------------------------------------------------------
// hi -> hi_dst (img0), lo -> lo1 AND lo2 (lo2 = img1 slot of the batched buf)
__global__ __launch_bounds__(256)
void ps_mask_hl(float2* __restrict__ lo1, float2* __restrict__ lo2,
                float2* __restrict__ hi_dst, const float2* __restrict__ src){
  int i = blockIdx.x*blockDim.x + threadIdx.x;
  if (i >= 1024*1024) return;
  int y = i >> 10, x = i & 1023;
  float lr, ang; polar_f(y, x, lr, ang);
  float2 v = src[i];
  float lo = f_lo(lr, 0.f), hi = f_hi(lr, 0.f);
  float2 lv = make_float2(v.x*lo, v.y*lo);
  lo1[i] = lv;
  lo2[i] = lv;
  hi_dst[i] = make_float2(v.x*hi, v.y*hi);
}
__global__ __launch_bounds__(256)
void ps_band_mask4(float2* __restrict__ dst, const float2* __restrict__ src,
                   int H, int off, float shift){
  int i = blockIdx.x*blockDim.x + threadIdx.x;
  int n = H*H;
  if (i >= n) return;
  int y = i / H, x = i - y*H;
  float lr, ang; polar_f(off + y, off + x, lr, ang);
  float hm = f_hi(lr, shift);
  float2 v = src[i];
  #pragma unroll
  for (int b = 0; b < 4; b++){
    float a0 = ang - (PI_F*0.25f)*(float)b + PI_F;
    float a = fmodf(a0, 2.f*PI_F);
    if (a < 0.f) a += 2.f*PI_F;
    a -= PI_F;
    float mk = 0.f;
    if (fabsf(a) < PI_F*0.5f){ float c = cosf(a); mk = 1.78885438199983f*c*c*c; }
    float mf = hm*mk;
    dst[(size_t)b*n + i] = make_float2(-mf*v.y, mf*v.x);
  }
}
__global__ __launch_bounds__(256)
void ps_crop_lo(float2* dst, const float2* src, int Hs, int offNew, float shift){
  int Hd = Hs/2;
  int i = blockIdx.x*blockDim.x + threadIdx.x;
  if (i >= Hd*Hd) return;
  int y = i / Hd, x = i - y*Hd;
  float lr, ang; polar_f(offNew + y, offNew + x, lr, ang);
  float mk = f_lo(lr, shift);
  float2 v = src[(y + Hs/4)*Hs + (x + Hs/4)];
  dst[i] = make_float2(v.x*mk, v.y*mk);
}

// ---------------------------------------------------------------------------
// reductions
// ---------------------------------------------------------------------------
__global__ void ps_init_mm(unsigned* mm){ mm[0] = 0xFFFFFFFFu; mm[1] = 0u; }

__global__ __launch_bounds__(256, 1)
void ps_im_stats(const float4* __restrict__ x4, int n4, double* out, unsigned* mm){
  float acc[4] = {0.f,0.f,0.f,0.f};
  float mn = INFINITY, mx = -INFINITY;
  for (int i = blockIdx.x*blockDim.x + threadIdx.x; i < n4; i += gridDim.x*blockDim.x){
    float4 v = x4[i];
    float a0 = v.x, a1 = v.y, a2 = v.z, a3 = v.w;
    acc[0] += a0 + a1 + a2 + a3;
    acc[1] += a0*a0 + a1*a1 + a2*a2 + a3*a3;
    acc[2] += a0*a0*a0 + a1*a1*a1 + a2*a2*a2 + a3*a3*a3;
    acc[3] += a0*a0*a0*a0 + a1*a1*a1*a1 + a2*a2*a2*a2 + a3*a3*a3*a3;
    mn = fminf(mn, fminf(fminf(a0,a1), fminf(a2,a3)));
    mx = fmaxf(mx, fmaxf(fmaxf(a0,a1), fmaxf(a2,a3)));
  }
  block_reduce_add<4, 4>(acc, out);
  #pragma unroll
  for (int o = 32; o > 0; o >>= 1){
    mn = fminf(mn, __shfl_down(mn, o, 64));
    mx = fmaxf(mx, __shfl_down(mx, o, 64));
  }
  if ((threadIdx.x & 63) == 0){
    atomicMin(&mm[0], encf(mn));
    atomicMax(&mm[1], encf(mx));
  }
}

struct ScaleATab { const float2* b[4]; int n[4]; };
__global__ __launch_bounds__(256, 1)
void ps_scaleA_multi(ScaleATab tt, double* __restrict__ ST){
  int s = blockIdx.y;
  int n = tt.n[s];
  if ((size_t)blockIdx.x*blockDim.x >= (size_t)n) return;
  const float2* bb = tt.b[s];
  double* outp = ST + 64 + s*32;
  float acc[28];
  #pragma unroll
  for (int k = 0; k < 28; k++) acc[k] = 0.f;
  for (int i = blockIdx.x*blockDim.x + threadIdx.x; i < n; i += gridDim.x*blockDim.x){
    float2 v0 = bb[i], v1 = bb[(size_t)n + i], v2 = bb[2*(size_t)n + i], v3 = bb[3*(size_t)n + i];
    float ab[4] = { sqrtf(v0.x*v0.x+v0.y*v0.y), sqrtf(v1.x*v1.x+v1.y*v1.y),
                    sqrtf(v2.x*v2.x+v2.y*v2.y), sqrtf(v3.x*v3.x+v3.y*v3.y) };
    float re[4] = { v0.x, v1.x, v2.x, v3.x };
    #pragma unroll
    for (int a = 0; a < 4; a++){
      #pragma unroll
      for (int c = a; c < 4; c++){
        acc[P4(a,c)]      += ab[a]*ab[c];
        acc[10 + P4(a,c)] += re[a]*re[c];
      }
      acc[20 + a] += ab[a];
      acc[24 + a] += re[a];
    }
  }
  block_reduce_add<28, 4>(acc, outp);
}
__global__ __launch_bounds__(256, 1)
void ps_scaleB(const float2* __restrict__ u0, const float2* __restrict__ u1,
               const float2* __restrict__ u2, const float2* __restrict__ u3,
               const float2* __restrict__ s0, const float2* __restrict__ s1,
               const float2* __restrict__ s2, const float2* __restrict__ s3,
               int n, double* out){
  float acc[72];
  #pragma unroll
  for (int k = 0; k < 72; k++) acc[k] = 0.f;
  for (int i = blockIdx.x*blockDim.x + threadIdx.x; i < n; i += gridDim.x*blockDim.x){
    float2 u[4] = { u0[i], u1[i], u2[i], u3[i] };
    float2 bb[4] = { s0[i], s1[i], s2[i], s3[i] };
    float au[4], dre[4], dim[4], M[4], R[4];
    #pragma unroll
    for (int c = 0; c < 4; c++){
      float xx = u[c].x, yy = u[c].y;
      float mag = sqrtf(xx*xx + yy*yy);
      float den = mag + 1e-12f;
      au[c] = mag;
      dre[c] = (xx*xx - yy*yy)/den;
      dim[c] = (2.f*xx*yy)/den;
      M[c] = sqrtf(bb[c].x*bb[c].x + bb[c].y*bb[c].y);
      R[c] = bb[c].x;
    }
    #pragma unroll
    for (int c = 0; c < 4; c++){
      acc[c]      += au[c];
      acc[4 + c]  += au[c]*au[c];
      acc[24 + c] += dre[c];
      acc[28 + c] += dim[c];
      acc[32 + c] += dre[c]*dre[c];
      acc[36 + c] += dim[c]*dim[c];
    }
    #pragma unroll
    for (int a = 0; a < 4; a++)
      #pragma unroll
      for (int c = 0; c < 4; c++){
        acc[8 + a*4 + c]  += M[a]*au[c];
        acc[40 + a*4 + c] += R[a]*dre[c];
        acc[56 + a*4 + c] += R[a]*dim[c];
      }
  }
  block_reduce_add<72, 4>(acc, out);
}
__global__ __launch_bounds__(256, 1)
void ps_scaleC(const float2* __restrict__ s0, const float2* __restrict__ s1,
               const float2* __restrict__ s2, const float2* __restrict__ s3,
               const float* __restrict__ lp, int n, double* out){
  float acc[36];
  #pragma unroll
  for (int k = 0; k < 36; k++) acc[k] = 0.f;
  for (int i = blockIdx.x*blockDim.x + threadIdx.x; i < n; i += gridDim.x*blockDim.x){
    int y = i >> 7, x = i & 127;
    float L[5];
    L[0] = lp[i];
    L[1] = lp[(y << 7) | ((x + 126) & 127)];
    L[2] = lp[(y << 7) | ((x + 2) & 127)];
    L[3] = lp[(((y + 126) & 127) << 7) | x];
    L[4] = lp[(((y + 2) & 127) << 7) | x];
    float R[4] = { s0[i].x, s1[i].x, s2[i].x, s3[i].x };
    acc[0] += L[0];
    #pragma unroll
    for (int a = 0; a < 5; a++)
      #pragma unroll
      for (int c = a; c < 5; c++)
        acc[1 + P5(a,c)] += L[a]*L[c];
    #pragma unroll
    for (int a = 0; a < 4; a++)
      #pragma unroll
      for (int j = 0; j < 5; j++)
        acc[16 + a*5 + j] += R[a]*L[j];
  }
  block_reduce_add<36, 4>(acc, out);
}

// ---------------------------------------------------------------------------
// finalize — one thread per output element.
// ST layout: [0..3] image moments; [4..8] hipass s1,s2,s3,s4,sabs
//  [10+r*6 ..] recon r: s1..s4,sabs; [64+s*32] scaleA(28)
//  [192+s*80] scaleB(72); [432..467] scaleC(36)
//  [512+r*48] recon AC R[41]; [752+(s*4+b)*48] band-mag AC R[41]
// ---------------------------------------------------------------------------
__device__ __forceinline__ double d_ns(int s){ double h = (double)(1024 >> s); return h*h; }
__device__ __forceinline__ void d_moments(const double* Mo, double n,
                                          double& sk, double& ku, double& var){
  double m = Mo[0]/n, e2 = Mo[1]/n, e3 = Mo[2]/n, e4 = Mo[3]/n;
  var = e2 - m*m;
  double c3 = e3 - 3.0*m*e2 + 2.0*m*m*m;
  double c4 = e4 - 4.0*m*e3 + 6.0*m*m*e2 - 3.0*m*m*m*m;
  sk = c3/pow(var,1.5); ku = c4/(var*var);
}
__device__ __forceinline__ int ac_o(int w, int& dy, int& dx){
  dy = w/9 - 4; dx = w - (w/9)*9 - 4;
  int ady = dy, adx = dx;
  if (dy < 0 || (dy == 0 && dx < 0)){ ady = -dy; adx = -dx; }
  return (ady == 0) ? adx : (5 + (ady-1)*9 + (adx+4));
}

__global__ __launch_bounds__(256)
void ps_finalize(const double* __restrict__ ST, const unsigned* __restrict__ MM,
                 float* __restrict__ out, int out_size){
  int idx = blockIdx.x*blockDim.x + threadIdx.x;
  if (idx >= out_size) return;
  const double n0 = 1048576.0;
  double val = 0.0;

  if (idx <= 5){
    if (idx == 4){ out[4] = decf(MM[0]); return; }
    if (idx == 5){ out[5] = decf(MM[1]); return; }
    double sk, ku, v; d_moments(ST, n0, sk, ku, v);
    val = (idx == 0) ? ST[0]/n0 : (idx == 1) ? v : (idx == 2) ? sk : ku;
  } else if (idx == 6){
    val = ST[8]/n0;
  } else if (idx <= 22){
    int i = idx - 7; int s = i >> 2, b = i & 3;
    val = ST[64 + s*32 + 20 + b] / d_ns(s);
  } else if (idx == 23){
    val = ST[10 + 4*6 + 4] / 4096.0;
  } else if (idx <= 1319){                      // band-mag ACs
    int i = idx - 24; int w = i >> 4; int j = i & 15;
    int s = j >> 2, b = j & 3;
    double n = d_ns(s);
    const double* R = ST + 752 + j*48;
    double mu = ST[64 + s*32 + 20 + b]/n, mu2 = mu*mu;
    int dy, dx; int o = ac_o(w, dy, dx);
    val = (R[o]/n - mu2) / (R[0]/n - mu2 + 1e-12);
  } else if (idx <= 1329){                      // skew_r / kurt_r
    int i = idx - 1320; bool kq = (i >= 5); int r = kq ? i - 5 : i;
    double n = (r == 4) ? 4096.0 : d_ns(r);
    double sk, ku, v; d_moments(ST + 10 + r*6, n, sk, ku, v);
    val = kq ? ku : sk;
  } else if (idx <= 1734){                      // recon ACs
    int i = idx - 1330; int w = i / 5; int r = i - w*5;
    double n = (r == 4) ? 4096.0 : d_ns(r);
    const double* R = ST + 512 + r*48;
    double mu = ST[10 + r*6]/n, mu2 = mu*mu;
    int dy, dx; int o = ac_o(w, dy, dx);
    val = (R[o]/n - mu2) / (R[0]/n - mu2 + 1e-12);
  } else if (idx <= 1739){                      // std_r
    int r = idx - 1735;
    double n = (r == 4) ? 4096.0 : d_ns(r);
    double sk, ku, v; d_moments(ST + 10 + r*6, n, sk, ku, v);
    val = sqrt(v);
  } else if (idx <= 1819){                      // com
    int i = idx - 1740; int s = i % 5; int q = i / 5; int a = q >> 2, b = q & 3;
    if (s < 4){
      double n = d_ns(s); const double* A = ST + 64 + s*32;
      double ma = A[20+a]/n, mb = A[20+b]/n;
      double caa = A[P4(a,a)]/n - ma*ma, cbb = A[P4(b,b)]/n - mb*mb;
      int lo = a < b ? a : b, hi = a < b ? b : a;
      double cab = A[P4(lo,hi)]/n - ma*mb;
      val = cab / (sqrt(caa)*sqrt(cbb) + 1e-12);
    }
  } else if (idx <= 1883){                      // csm
    int i = idx - 1820; int s = i & 3; int q = i >> 2; int a = q >> 2, c = q & 3;
    if (s < 3){
      double n = d_ns(s); const double* A = ST + 64 + s*32; const double* B = ST + 192 + s*80;
      double mM = A[20+a]/n; double sdM = sqrt(A[P4(a,a)]/n - mM*mM);
      double mU = B[c]/n;    double sdU = sqrt(B[4+c]/n - mU*mU);
      val = (B[8 + a*4 + c]/n - mM*mU) / (sdM*sdU + 1e-12);
    }
  } else if (idx <= 2203){                      // cor
    int i = idx - 1884; int s = i % 5; int q = i / 5; int a = q >> 3, b = q & 7;
    if (s < 4){
      if (a < 4 && b < 4){
        double n = d_ns(s); const double* A = ST + 64 + s*32;
        double ma = A[24+a]/n, mb = A[24+b]/n;
        double caa = A[10+P4(a,a)]/n - ma*ma, cbb = A[10+P4(b,b)]/n - mb*mb;
        int lo = a < b ? a : b, hi = a < b ? b : a;
        double cab = A[10+P4(lo,hi)]/n - ma*mb;
        val = cab / (sqrt(caa)*sqrt(cbb) + 1e-12);
      }
    } else {
      if (a < 5 && b < 5){
        const double* C = ST + 432; const double n3 = 16384.0;
        double lb = C[0]/n3;
        double caa = C[1+P5(a,a)]/n3 - lb*lb, cbb = C[1+P5(b,b)]/n3 - lb*lb;
        int lo = a < b ? a : b, hi = a < b ? b : a;
        double cab = C[1+P5(lo,hi)]/n3 - lb*lb;
        val = cab / (sqrt(caa)*sqrt(cbb) + 1e-12);
      }
    }
  } else if (idx <= 2459){                      // csr
    int i = idx - 2204; int s = i & 3; int q = i >> 2; int a = q >> 3, c = q & 7;
    if (a < 4){
      double n = d_ns(s); const double* A = ST + 64 + s*32;
      double mR = A[24+a]/n; double sdR = sqrt(A[10+P4(a,a)]/n - mR*mR);
      if (s < 3 && c < 8){
        const double* B = ST + 192 + s*80;
        if (c < 4){
          double md = B[24+c]/n; double sd = sqrt(B[32+c]/n - md*md);
          val = (B[40 + a*4 + c]/n - mR*md) / (sdR*sd + 1e-12);
        } else {
          int cc = c - 4;
          double md = B[28+cc]/n; double sd = sqrt(B[36+cc]/n - md*md);
          val = (B[56 + a*4 + cc]/n - mR*md) / (sdR*sd + 1e-12);
        }
      } else if (s == 3 && c < 5){
        const double* C = ST + 432; const double n3 = 16384.0;
        double lb = C[0]/n3;
        double sdL = sqrt(C[1+P5(c,c)]/n3 - lb*lb);
        val = (C[16 + a*5 + c]/n3 - mR*lb) / (sdR*sdL + 1e-12);
      }
    }
  } else {
    val = ST[5]/n0 - (ST[4]/n0)*(ST[4]/n0);
  }
  out[idx] = (float)val;
}

// ---------------------------------------------------------------------------
// host orchestration
// ---------------------------------------------------------------------------
static void rows_pass(int H, float2* dst, const void* src,
                      int nimg, int simg, int dimg, int srcH1,
                      float dir, int xin, int xout, int lop, hipStream_t st){
  dim3 g(nimg * H);
  switch (H){
    case 64:   ps_fft_rows<64>  <<<g, 64,  0, st>>>(dst, src, simg, dimg, srcH1, dir, xin, xout, lop); break;
    case 128:  ps_fft_rows<128> <<<g, 64,  0, st>>>(dst, src, simg, dimg, srcH1, dir, xin, xout, lop); break;
    case 256:  ps_fft_rows<256> <<<g, 64,  0, st>>>(dst, src, simg, dimg, srcH1, dir, xin, xout, lop); break;
    case 512:  ps_fft_rows<512> <<<g, 128, 0, st>>>(dst, src, simg, dimg, srcH1, dir, xin, xout, lop); break;
    case 1024: ps_fft_rows<1024><<<g, 256, 0, st>>>(dst, src, simg, dimg, srcH1, dir, xin, xout, lop); break;
    default: break;
  }
}
static void cols_pass(int H, float2* dst, const float2* src, int nimg, int simg, int dimg,
                      float dir, int xin, int xout, float scale,
                      int sop, float* rdst, int rimg, double* mout, int mstride,
                      hipStream_t st){
  switch (H){
    case 64:   ps_fft_cols<64,16>  <<<dim3(nimg*(64/16)),  512, 0, st>>>(dst, src, simg, dimg, dir, xin, xout, scale, sop, rdst, rimg, mout, mstride); break;
    case 128:  ps_fft_cols<128,16> <<<dim3(nimg*(128/16)), 512, 0, st>>>(dst, src, simg, dimg, dir, xin, xout, scale, sop, rdst, rimg, mout, mstride); break;
    case 256:  ps_fft_cols<256,8>  <<<dim3(nimg*(256/8)),  512, 0, st>>>(dst, src, simg, dimg, dir, xin, xout, scale, sop, rdst, rimg, mout, mstride); break;
    case 512:  ps_fft_cols<512,8>  <<<dim3(nimg*(512/8)),  512, 0, st>>>(dst, src, simg, dimg, dir, xin, xout, scale, sop, rdst, rimg, mout, mstride); break;
    case 1024: ps_fft_cols<1024,4> <<<dim3(nimg*(1024/4)), 512, 0, st>>>(dst, src, simg, dimg, dir, xin, xout, scale, sop, rdst, rimg, mout, mstride); break;
    default: break;
  }
}

static inline dim3 gr(int n){ return dim3((n + 255)/256); }
static inline int  rblocks(int n){ int b = (n + 255)/256; return b > 512 ? 512 : b; }

#define FWD (-1.0f)
#define INV (+1.0f)

extern "C" void kernel_launch(void* const* d_in, const int* in_sizes, int n_in,
                              void* d_out, int out_size, void* d_ws, size_t ws_size,
                              hipStream_t stream){
  (void)in_sizes; (void)n_in;
  const float* im = (const float*)d_in[0];
  float* out = (float*)d_out;

  const int Hs[5]   = {1024, 512, 256, 128, 64};
  const int offs[5] = {0, 256, 384, 448, 480};

  // ---- carve workspace ----
  char* base = (char*)d_ws;
  size_t off = 0;
  auto carve = [&](size_t bytes)->void*{
    void* r = base + off;
    off = (off + bytes + 255) & ~(size_t)255;
    return r;
  };
  const int n0 = 1024*1024;
  float2* lod[5];
  for (int s = 0; s < 5; s++) lod[s] = (float2*)carve((size_t)Hs[s]*Hs[s]*sizeof(float2));
  float2* band[4];
  for (int s = 0; s < 4; s++) band[s] = (float2*)carve((size_t)4*Hs[s]*Hs[s]*sizeof(float2));
  float2* bdft[4];
  bdft[0] = nullptr;
  for (int s = 1; s < 4; s++) bdft[s] = (float2*)carve((size_t)4*Hs[s]*Hs[s]*sizeof(float2));
  float* reals0 = (float*)carve((size_t)2*n0*sizeof(float));  // [hp_real | recon0]
  float* recon[5];
  recon[0] = reals0 + n0;
  for (int s = 1; s < 5; s++) recon[s] = (float*)carve((size_t)Hs[s]*Hs[s]*sizeof(float));
  float* lp = (float*)carve(128*128*sizeof(float));
  float2* scr  = (float2*)carve((size_t)n0*sizeof(float2));
  float2* scr4 = (float2*)carve((size_t)4*n0*sizeof(float2));
  double* ST = (double*)carve(2048*sizeof(double));
  unsigned* MM = (unsigned*)carve(64*sizeof(unsigned));
  if (off > ws_size) return;

  // ---- init ----
  hipMemsetAsync(ST, 0, 2048*sizeof(double), stream);
  ps_init_mm<<<1, 1, 0, stream>>>(MM);
  ps_im_stats<<<256, 256, 0, stream>>>((const float4*)im, n0/4, ST + 0, MM);

  // ---- imdft (shifted) ----
  rows_pass(1024, scr, im, 1, 0, 0, 0, FWD, 0, 512, LOP_R2C, stream);
  cols_pass(1024, scr, scr, 1, 0, 0, FWD, 0, 512, 1.0f, SOP_NONE, nullptr, 0, nullptr, 0, stream);
  // hi -> scr4[img0], lo -> lod[0] and scr4[img1]
  ps_mask_hl<<<gr(n0), 256, 0, stream>>>(lod[0], scr4 + n0, scr4, scr);
  // batched 2-img inverse: img0 = hipass (stats->ST+4), img1 = recon0 (stats->ST+10)
  rows_pass(1024, scr4, scr4, 2, n0, n0, 0, INV, 512, 0, LOP_NONE, stream);
  cols_pass(1024, scr4, scr4, 2, n0, n0, INV, 512, 0, 1.0f/(float)n0,
            SOP_REAL, reals0, n0, ST + 4, 6, stream);

  // ---- pyramid scales ----
  for (int s = 0; s < 4; s++){
    int H = Hs[s], n = H*H;
    float invn = 1.0f/((float)H*(float)H);
    if (s > 0){
      rows_pass(H, scr, lod[s], 1, 0, 0, 0, INV, H/2, 0, LOP_NONE, stream);
      cols_pass(H, scr, scr, 1, 0, 0, INV, H/2, 0, invn, SOP_REAL, recon[s], 0,
                ST + 10 + s*6, 0, stream);
    }
    float2* bq = (s == 0) ? scr4 : bdft[s];
    ps_band_mask4<<<gr(n), 256, 0, stream>>>(bq, lod[s], H, offs[s], -(float)(s+1));
    rows_pass(H, band[s], bq, 4, n, n, 0, INV, H/2, 0, LOP_NONE, stream);
    cols_pass(H, band[s], band[s], 4, n, n, INV, H/2, 0, invn, SOP_NONE, nullptr, 0, nullptr, 0, stream);
    ps_crop_lo<<<gr((H/2)*(H/2)), 256, 0, stream>>>(lod[s+1], lod[s], H, offs[s+1], -(float)(s+1));
  }
  rows_pass(64, scr, lod[4], 1, 0, 0, 0, INV, 32, 0, LOP_NONE, stream);
  cols_pass(64, scr, scr, 1, 0, 0, INV, 32, 0, 1.0f/4096.f, SOP_REAL, recon[4], 0,
            ST + 10 + 4*6, 0, stream);

  // ---- all 21 autocorrelations in one launch ----
  {
    AcTaskTab tt{};
    int nt = 0, blk = 0;
    for (int r = 0; r < 5; r++){
      int H = Hs[r]; int tiles = (H>>5)*(H>>5); int nb = tiles < 128 ? tiles : 128;
      tt.src[nt] = recon[r]; tt.isMag[nt] = 0; tt.H[nt] = H; tt.npi[nt] = H*H;
      tt.nb[nt] = nb; tt.stOff[nt] = 512 + r*48; tt.stStride[nt] = 48;
      tt.blkStart[nt] = blk; blk += nb; nt++;
    }
    for (int s = 0; s < 4; s++){
      int H = Hs[s]; int tiles = (H>>5)*(H>>5); int nb = tiles < 128 ? tiles : 128;
      tt.src[nt] = band[s]; tt.isMag[nt] = 1; tt.H[nt] = H; tt.npi[nt] = H*H;
      tt.nb[nt] = nb; tt.stOff[nt] = 752 + s*4*48; tt.stStride[nt] = 48;
      tt.blkStart[nt] = blk; blk += nb*4; nt++;
    }
    tt.blkStart[nt] = blk; tt.nTasks = nt;
    ps_spat_ac_multi<<<dim3(blk), 256, 0, stream>>>(tt, ST);
  }

  // ---- per-scale band Grams (one launch) ----
  {
    ScaleATab ta{};
    for (int s = 0; s < 4; s++){ ta.b[s] = band[s]; ta.n[s] = Hs[s]*Hs[s]; }
    ps_scaleA_multi<<<dim3(512, 4), 256, 0, stream>>>(ta, ST);
  }

  // ---- cross-scale: pad kept band DFTs directly ----
  for (int s = 0; s < 3; s++){
    int H1 = Hs[s+1], H2 = Hs[s];
    int n1 = H1*H1, n2 = H2*H2;
    rows_pass(H2, scr4, bdft[s+1], 4, n1, n2, H1, INV, H2/2, 0, LOP_PAD, stream);
    cols_pass(H2, scr4, scr4, 4, n2, n2, INV, H2/2, 0, 1.0f/(float)n1, SOP_NONE, nullptr, 0, nullptr, 0, stream);
    ps_scaleB<<<rblocks(n2), 256, 0, stream>>>(scr4, scr4+n2, scr4+2*n2, scr4+3*n2,
                                               band[s], band[s]+n2, band[s]+2*n2, band[s]+3*n2,
                                               n2, ST + 192 + s*80);
  }
  // s=3: expand2(lowpass) = pad lod[4] directly
  rows_pass(128, scr4, lod[4], 1, 4096, 16384, 64, INV, 64, 0, LOP_PAD, stream);
  cols_pass(128, scr4, scr4, 1, 16384, 16384, INV, 64, 0, 1.0f/4096.f, SOP_REAL, lp, 0, nullptr, 0, stream);
  ps_scaleC<<<rblocks(16384), 256, 0, stream>>>(band[3], band[3]+16384, band[3]+2*16384, band[3]+3*16384,
                                                lp, 16384, ST + 432);

  // ---- finalize ----
  ps_finalize<<<gr(out_size), 256, 0, stream>>>(ST, MM, out, out_size);
}

// Round 10
// 500.603 us; speedup vs baseline: 1.7368x; 1.0068x over previous
//
#include <hip/hip_runtime.h>
#include <math.h>

#define PI_F 3.14159265358979323846f

enum { LOP_NONE=0, LOP_R2C, LOP_PAD, LOP_BANDMASK, LOP_PADMASK };
enum { SOP_NONE=0, SOP_REAL };

// ---------------------------------------------------------------------------
// helpers
// ---------------------------------------------------------------------------
__host__ __device__ constexpr int P4(int a, int b){ return a*4 - a*(a-1)/2 + (b-a); }
__host__ __device__ constexpr int P5(int a, int b){ return a*5 - a*(a-1)/2 + (b-a); }

__device__ __forceinline__ unsigned encf(float f){
  unsigned u = __float_as_uint(f);
  return (u & 0x80000000u) ? ~u : (u | 0x80000000u);
}
__device__ __forceinline__ float decf(unsigned u){
  unsigned b = (u & 0x80000000u) ? (u ^ 0x80000000u) : ~u;
  return __uint_as_float(b);
}
__device__ __forceinline__ float2 cxmul(float2 a, float c, float s){
  return make_float2(c*a.x - s*a.y, c*a.y + s*a.x);
}
__device__ __forceinline__ float2 f2add(float2 a, float2 b){ return make_float2(a.x+b.x, a.y+b.y); }
__device__ __forceinline__ float2 f2sub(float2 a, float2 b){ return make_float2(a.x-b.x, a.y-b.y); }

// wave shuffle-reduce -> LDS -> ONE atomicAdd per counter per block.
template<int CNT, int WAVES>
__device__ __forceinline__ void block_reduce_add(float (&acc)[CNT], double* out){
  __shared__ float red[WAVES*CNT];
  int lane = threadIdx.x & 63;
  int wid  = threadIdx.x >> 6;
  #pragma unroll
  for (int k = 0; k < CNT; k++){
    float v = acc[k];
    #pragma unroll
    for (int o = 32; o > 0; o >>= 1) v += __shfl_down(v, o, 64);
    if (lane == 0) red[wid*CNT + k] = v;
  }
  __syncthreads();
  int t = threadIdx.x;
  if (t < CNT){
    double s = 0.0;
    #pragma unroll
    for (int w = 0; w < WAVES; w++) s += (double)red[w*CNT + t];
    atomicAdd(&out[t], s);
  }
  __syncthreads();
}

// float polar grid (ref computes masks in f64 then casts to f32)
__device__ __forceinline__ void polar_f(int iy, int ix, float& lr, float& ang){
  float yn = (float)(iy - 512) * (1.f/512.f);
  float xn = (float)(ix - 512) * (1.f/512.f);
  ang = atan2f(yn, xn);
  float rad = (iy == 512 && ix == 512) ? (1.f/512.f) : sqrtf(xn*xn + yn*yn);
  lr = log2f(rad);
}
__device__ __forceinline__ float f_hi(float lr, float shift){
  float v = fminf(fmaxf(lr - shift, -1.f), 0.f);
  return cosf((PI_F*0.5f) * v);
}
__device__ __forceinline__ float f_lo(float lr, float shift){
  float h = f_hi(lr, shift);
  float q = fminf(fmaxf(1.f - h*h, 0.f), 1.f);
  return sqrtf(q);
}
__device__ __forceinline__ float band_am(float ang, int b){
  float a0 = ang - (PI_F*0.25f)*(float)b + PI_F;
  float a = fmodf(a0, 2.f*PI_F);
  if (a < 0.f) a += 2.f*PI_F;
  a -= PI_F;
  float mk = 0.f;
  if (fabsf(a) < PI_F*0.5f){ float c = cosf(a); mk = 1.78885438199983f*c*c*c; }
  return mk;
}

// radix-4 butterfly on v[4]; fwd: omega=-i
__device__ __forceinline__ void bfly4(float2* v, bool fwd){
  float2 A = f2add(v[0], v[2]), B = f2sub(v[0], v[2]);
  float2 C = f2add(v[1], v[3]), D = f2sub(v[1], v[3]);
  float2 dj = fwd ? make_float2(D.y, -D.x) : make_float2(-D.y, D.x);
  v[0] = f2add(A, C);
  v[1] = f2add(B, dj);
  v[2] = f2sub(A, C);
  v[3] = f2sub(B, dj);
}

// ---------------------------------------------------------------------------
// FFT rows pass: one line per block, fused load-ops.
// LOP_BANDMASK: read lod (shared by 4 imgs), apply 1j*hi*am_{img} per band.
// LOP_PADMASK : zero-pad from H1 grid AND apply band mask while loading.
// ---------------------------------------------------------------------------
template<int N>
__global__ __launch_bounds__((N/4 < 64) ? 64 : N/4)
void ps_fft_rows(float2* __restrict__ dst, const void* __restrict__ vsrc,
                 int simg, int dimg, int srcH1,
                 float dir, int xin, int xout, int lop, int moff, float mshift)
{
  constexpr int T = (N/4 < 64) ? 64 : N/4;
  __shared__ float2 sm[N];
  const int t = threadIdx.x;
  const int l = blockIdx.x & (N-1);
  const int img = blockIdx.x / N;
  float2* dline = dst + (size_t)img*(size_t)dimg + (size_t)l*N;

  if (lop == LOP_PAD || lop == LOP_PADMASK){
    const int q = N/4;
    const int sl = l - q;
    if (sl < 0 || sl >= srcH1){
      for (int j = t; j < N; j += T) dline[j] = make_float2(0.f, 0.f);
      return;
    }
    const float2* s = (const float2*)vsrc + (size_t)img*simg + (size_t)sl*srcH1;
    if (lop == LOP_PAD){
      for (int j = t; j < N; j += T){
        int p = j ^ xin;
        sm[j] = (p >= q && p < q + srcH1) ? s[p - q] : make_float2(0.f, 0.f);
      }
    } else {
      for (int j = t; j < N; j += T){
        int p = j ^ xin;
        float2 r = make_float2(0.f, 0.f);
        if (p >= q && p < q + srcH1){
          int x = p - q;
          float lr, ang; polar_f(moff + sl, moff + x, lr, ang);
          float mf = f_hi(lr, mshift) * band_am(ang, img);
          float2 v = s[x];
          r = make_float2(-mf*v.y, mf*v.x);
        }
        sm[j] = r;
      }
    }
  } else if (lop == LOP_BANDMASK){
    const float2* s = (const float2*)vsrc + (size_t)l*N;   // simg==0: shared
    for (int j = t; j < N; j += T){
      int x = j ^ xin;
      float lr, ang; polar_f(moff + l, moff + x, lr, ang);
      float mf = f_hi(lr, mshift) * band_am(ang, img);
      float2 v = s[x];
      sm[j] = make_float2(-mf*v.y, mf*v.x);
    }
  } else if (lop == LOP_R2C){
    const float* s = (const float*)vsrc + (size_t)img*simg + (size_t)l*N;
    for (int j = t; j < N; j += T) sm[j] = make_float2(s[j ^ xin], 0.f);
  } else {
    const float2* s = (const float2*)vsrc + (size_t)img*simg + (size_t)l*N;
    for (int j = t; j < N; j += T) sm[j] = s[j ^ xin];
  }
  __syncthreads();

  const bool fwd = (dir < 0.f);
  int Ns = 1;
  if constexpr ((N & 0xAAAAAAAAu) != 0){           // odd log2: radix-2 first
    constexpr int NB2 = N/2;
    constexpr int P2 = (NB2 + T - 1)/T;
    float2 a[P2], b[P2];
    #pragma unroll
    for (int p = 0; p < P2; p++){
      int q = t + p*T;
      if (q < NB2){ a[p] = sm[q]; b[p] = sm[q + N/2]; }
    }
    __syncthreads();
    #pragma unroll
    for (int p = 0; p < P2; p++){
      int q = t + p*T;
      if (q < NB2){
        sm[2*q]   = f2add(a[p], b[p]);
        sm[2*q+1] = f2sub(a[p], b[p]);
      }
    }
    __syncthreads();
    Ns = 2;
  }
  constexpr int NB4 = N/4;
  for (; Ns < N; Ns <<= 2){
    float2 v[4];
    int q = t;
    int k = 0;
    if (q < NB4){
      k = q & (Ns - 1);
      #pragma unroll
      for (int r = 0; r < 4; r++) v[r] = sm[q + r*NB4];
      if (k){
        float ang = dir * (PI_F*0.5f) * (float)k / (float)Ns;
        float s1, c1; __sincosf(ang, &s1, &c1);
        float c2 = c1*c1 - s1*s1, s2 = 2.f*c1*s1;
        float c3 = c1*c2 - s1*s2, s3 = c1*s2 + s1*c2;
        v[1] = cxmul(v[1], c1, s1);
        v[2] = cxmul(v[2], c2, s2);
        v[3] = cxmul(v[3], c3, s3);
      }
      bfly4(v, fwd);
    }
    __syncthreads();
    if (q < NB4){
      int dd = ((q - k) << 2) + k;
      sm[dd]        = v[0];
      sm[dd + Ns]   = v[1];
      sm[dd + 2*Ns] = v[2];
      sm[dd + 3*Ns] = v[3];
    }
    __syncthreads();
  }
  for (int j = t; j < N; j += T) dline[j ^ xout] = sm[j];
}

// ---------------------------------------------------------------------------
// FFT cols pass: CB adjacent columns per block (coalesced). src/dst may alias.
// mout != null: accumulate 5 moments of (re*scale) into mout + img*mstride.
// ---------------------------------------------------------------------------
template<int N, int CB>
__global__ __launch_bounds__(512)
void ps_fft_cols(float2* __restrict__ dst, const float2* __restrict__ src,
                 int simg, int dimg,
                 float dir, int xin, int xout, float scale,
                 int sop, float* __restrict__ rdst, int rimg,
                 double* __restrict__ mout, int mstride)
{
  constexpr int T = 512;
  constexpr int LCB = (CB==2)?1:(CB==4)?2:(CB==8)?3:4;
  constexpr int NBK = N / CB;
  constexpr int NE = N*CB;
  __shared__ float2 sm[NE];
  const int t = threadIdx.x;
  const int img = blockIdx.x / NBK;
  const int c0 = (blockIdx.x % NBK) * CB;
  const float2* sbase = src + (size_t)img*(size_t)simg + c0;
  float2* dbase = dst + (size_t)img*(size_t)dimg + c0;

  for (int e = t; e < NE; e += T){
    int j = e >> LCB, c = e & (CB - 1);
    sm[e] = sbase[(size_t)(j ^ xin)*N + c];
  }
  __syncthreads();

  const bool fwd = (dir < 0.f);
  int Ns = 1;
  if constexpr ((N & 0xAAAAAAAAu) != 0){
    constexpr int NB2 = (N/2)*CB;
    constexpr int P2 = (NB2 + T - 1)/T;
    float2 a[P2], b[P2];
    #pragma unroll
    for (int p = 0; p < P2; p++){
      int q = t + p*T;
      if (q < NB2){
        int c = q & (CB-1), tt = q >> LCB;
        a[p] = sm[tt*CB + c];
        b[p] = sm[(tt + N/2)*CB + c];
      }
    }
    __syncthreads();
    #pragma unroll
    for (int p = 0; p < P2; p++){
      int q = t + p*T;
      if (q < NB2){
        int c = q & (CB-1), tt = q >> LCB;
        sm[(2*tt)*CB + c]   = f2add(a[p], b[p]);
        sm[(2*tt+1)*CB + c] = f2sub(a[p], b[p]);
      }
    }
    __syncthreads();
    Ns = 2;
  }
  constexpr int NB4 = (N/4)*CB;
  constexpr int PB = (NB4 + T - 1)/T;
  for (; Ns < N; Ns <<= 2){
    float2 v[PB][4];
    int kk[PB];
    #pragma unroll
    for (int p = 0; p < PB; p++){
      int q = t + p*T;
      if (q < NB4){
        int c = q & (CB-1), tt = q >> LCB;
        int k = tt & (Ns - 1);
        kk[p] = k;
        #pragma unroll
        for (int r = 0; r < 4; r++) v[p][r] = sm[(tt + r*(N/4))*CB + c];
        if (k){
          float ang = dir * (PI_F*0.5f) * (float)k / (float)Ns;
          float s1, c1; __sincosf(ang, &s1, &c1);
          float c2 = c1*c1 - s1*s1, s2 = 2.f*c1*s1;
          float c3 = c1*c2 - s1*s2, s3 = c1*s2 + s1*c2;
          v[p][1] = cxmul(v[p][1], c1, s1);
          v[p][2] = cxmul(v[p][2], c2, s2);
          v[p][3] = cxmul(v[p][3], c3, s3);
        }
        bfly4(v[p], fwd);
      }
    }
    __syncthreads();
    #pragma unroll
    for (int p = 0; p < PB; p++){
      int q = t + p*T;
      if (q < NB4){
        int c = q & (CB-1), tt = q >> LCB;
        int k = kk[p];
        int dd = ((tt - k) << 2) + k;
        sm[(dd)*CB + c]        = v[p][0];
        sm[(dd + Ns)*CB + c]   = v[p][1];
        sm[(dd + 2*Ns)*CB + c] = v[p][2];
        sm[(dd + 3*Ns)*CB + c] = v[p][3];
      }
    }
    __syncthreads();
  }

  if (sop == SOP_REAL){
    for (int e = t; e < NE; e += T){
      int j = e >> LCB, c = e & (CB - 1);
      rdst[(size_t)img*(size_t)rimg + (size_t)(j ^ xout)*N + c0 + c] = sm[j*CB + c].x * scale;
    }
  } else {
    for (int e = t; e < NE; e += T){
      int j = e >> LCB, c = e & (CB - 1);
      float2 v = sm[j*CB + c];
      dbase[(size_t)(j ^ xout)*N + c] = make_float2(v.x*scale, v.y*scale);
    }
  }
  if (mout){
    float acc[5] = {0.f,0.f,0.f,0.f,0.f};
    for (int e = t; e < NE; e += T){
      float r = sm[e].x * scale, r2 = r*r;
      acc[0] += r; acc[1] += r2; acc[2] += r2*r; acc[3] += r2*r2; acc[4] += fabsf(r);
    }
    block_reduce_add<5, 8>(acc, mout + (size_t)img*mstride);
  }
}

// ---------------------------------------------------------------------------
// spatial circular autocorrelation, 9x9 lags, ALL 21 arrays in ONE launch.
// 4 px/thread; tile row stride 41 (round-9 lesson: stride 40 + px0=4b gave
// addresses 40a+4b = 8-way bank conflict, 7.3M cycles; 41a+4b mod 32 = 2-way
// = free).
// ---------------------------------------------------------------------------
#define MAX_AC_TASKS 9
#define TSTR 41
struct AcTaskTab {
  const void* src[MAX_AC_TASKS];
  int isMag[MAX_AC_TASKS];
  int H[MAX_AC_TASKS];
  int npi[MAX_AC_TASKS];
  int nb[MAX_AC_TASKS];
  int stOff[MAX_AC_TASKS];
  int stStride[MAX_AC_TASKS];
  int blkStart[MAX_AC_TASKS+1];
  int nTasks;
};

__global__ __launch_bounds__(256, 1)
void ps_spat_ac_multi(AcTaskTab tt, double* __restrict__ ST)
{
  __shared__ float tile[40*TSTR];
  const int gb = blockIdx.x;
  int tk = 0;
  while (tk + 1 < tt.nTasks && gb >= tt.blkStart[tk+1]) tk++;
  const int lb  = gb - tt.blkStart[tk];
  const int nb  = tt.nb[tk];
  const int img = lb / nb;
  const int b0  = lb - img*nb;
  const int H = tt.H[tk];
  const int n_per_img = tt.npi[tk];
  const int isMag = tt.isMag[tk];
  const void* vsrc = tt.src[tk];
  const int t = threadIdx.x;
  const int tilesX = H >> 5;
  const int tiles = tilesX * tilesX;
  const int py  = t >> 3;          // 0..31
  const int px0 = (t & 7) << 2;    // 0,4,..,28
  float acc[41];
  #pragma unroll
  for (int k = 0; k < 41; k++) acc[k] = 0.f;

  for (int tl = b0; tl < tiles; tl += nb){
    int by = tl / tilesX, bx = tl - by*tilesX;
    int y0 = by << 5, x0 = bx << 5;
    __syncthreads();
    for (int e = t; e < 40*40; e += 256){
      int ly = e / 40, lx = e - ly*40;
      int gy = (y0 + ly - 4) & (H - 1);
      int gx = (x0 + lx - 4) & (H - 1);
      float v;
      if (isMag){
        float2 c = ((const float2*)vsrc)[(size_t)img*n_per_img + (size_t)gy*H + gx];
        v = sqrtf(c.x*c.x + c.y*c.y);
      } else {
        v = ((const float*)vsrc)[(size_t)img*n_per_img + (size_t)gy*H + gx];
      }
      tile[ly*TSTR + lx] = v;
    }
    __syncthreads();
    {
      const float* row0 = tile + (py+4)*TSTR + (px0+4);
      float c0 = row0[0], c1 = row0[1], c2 = row0[2], c3 = row0[3];
      {
        float r[8];
        #pragma unroll
        for (int i = 0; i < 8; i++) r[i] = row0[i];
        #pragma unroll
        for (int dx = 0; dx <= 4; dx++)
          acc[dx] += c0*r[dx] + c1*r[dx+1] + c2*r[dx+2] + c3*r[dx+3];
      }
      #pragma unroll
      for (int dy = 1; dy <= 4; dy++){
        const float* rw = tile + (py+4+dy)*TSTR + px0;
        float r[12];
        #pragma unroll
        for (int i = 0; i < 12; i++) r[i] = rw[i];
        #pragma unroll
        for (int dx = -4; dx <= 4; dx++)
          acc[5 + (dy-1)*9 + (dx+4)] += c0*r[4+dx] + c1*r[5+dx] + c2*r[6+dx] + c3*r[7+dx];
      }
    }
  }
  block_reduce_add<41, 4>(acc, ST + tt.stOff[tk] + (size_t)img*tt.stStride[tk]);
}

// ---------------------------------------------------------------------------
// elementwise kernels (float masks)
// ---------------------------------------------------------------------------
__global__ __launch_bounds__(256)
void ps_mask_hl(float2* __restrict__ lo1, float2* __restrict__ lo2,
                float2* __restrict__ hi_dst, const float2* __restrict__ src){
  int i = blockIdx.x*blockDim.x + threadIdx.x;
  if (i >= 1024*1024) return;
  int y = i >> 10, x = i & 1023;
  float lr, ang; polar_f(y, x, lr, ang);
  float2 v = src[i];
  float lo = f_lo(lr, 0.f), hi = f_hi(lr, 0.f);
  float2 lv = make_float2(v.x*lo, v.y*lo);
  lo1[i] = lv;
  lo2[i] = lv;
  hi_dst[i] = make_float2(v.x*hi, v.y*hi);
}
__global__ __launch_bounds__(256)
void ps_crop_lo(float2* dst, const float2* src, int Hs, int offNew, float shift){
  int Hd = Hs/2;
  int i = blockIdx.x*blockDim.x + threadIdx.x;
  if (i >= Hd*Hd) return;
  int y = i / Hd, x = i - y*Hd;
  float lr, ang; polar_f(offNew + y, offNew + x, lr, ang);
  float mk = f_lo(lr, shift);
  float2 v = src[(y + Hs/4)*Hs + (x + Hs/4)];
  dst[i] = make_float2(v.x*mk, v.y*mk);
}

// ---------------------------------------------------------------------------
// reductions
// ---------------------------------------------------------------------------
__global__ void ps_init_mm(unsigned* mm){ mm[0] = 0xFFFFFFFFu; mm[1] = 0u; }

__global__ __launch_bounds__(256, 1)
void ps_im_stats(const float4* __restrict__ x4, int n4, double* out, unsigned* mm){
  float acc[4] = {0.f,0.f,0.f,0.f};
  float mn = INFINITY, mx = -INFINITY;
  for (int i = blockIdx.x*blockDim.x + threadIdx.x; i < n4; i += gridDim.x*blockDim.x){
    float4 v = x4[i];
    float a0 = v.x, a1 = v.y, a2 = v.z, a3 = v.w;
    acc[0] += a0 + a1 + a2 + a3;
    acc[1] += a0*a0 + a1*a1 + a2*a2 + a3*a3;
    acc[2] += a0*a0*a0 + a1*a1*a1 + a2*a2*a2 + a3*a3*a3;
    acc[3] += a0*a0*a0*a0 + a1*a1*a1*a1 + a2*a2*a2*a2 + a3*a3*a3*a3;
    mn = fminf(mn, fminf(fminf(a0,a1), fminf(a2,a3)));
    mx = fmaxf(mx, fmaxf(fmaxf(a0,a1), fmaxf(a2,a3)));
  }
  block_reduce_add<4, 4>(acc, out);
  #pragma unroll
  for (int o = 32; o > 0; o >>= 1){
    mn = fminf(mn, __shfl_down(mn, o, 64));
    mx = fmaxf(mx, __shfl_down(mx, o, 64));
  }
  if ((threadIdx.x & 63) == 0){
    atomicMin(&mm[0], encf(mn));
    atomicMax(&mm[1], encf(mx));
  }
}

struct ScaleATab { const float2* b[4]; int n[4]; };
__global__ __launch_bounds__(256, 1)
void ps_scaleA_multi(ScaleATab tt, double* __restrict__ ST){
  int s = blockIdx.y;
  int n = tt.n[s];
  if ((size_t)blockIdx.x*blockDim.x >= (size_t)n) return;
  const float2* bb = tt.b[s];
  double* outp = ST + 64 + s*32;
  float acc[28];
  #pragma unroll
  for (int k = 0; k < 28; k++) acc[k] = 0.f;
  for (int i = blockIdx.x*blockDim.x + threadIdx.x; i < n; i += gridDim.x*blockDim.x){
    float2 v0 = bb[i], v1 = bb[(size_t)n + i], v2 = bb[2*(size_t)n + i], v3 = bb[3*(size_t)n + i];
    float ab[4] = { sqrtf(v0.x*v0.x+v0.y*v0.y), sqrtf(v1.x*v1.x+v1.y*v1.y),
                    sqrtf(v2.x*v2.x+v2.y*v2.y), sqrtf(v3.x*v3.x+v3.y*v3.y) };
    float re[4] = { v0.x, v1.x, v2.x, v3.x };
    #pragma unroll
    for (int a = 0; a < 4; a++){
      #pragma unroll
      for (int c = a; c < 4; c++){
        acc[P4(a,c)]      += ab[a]*ab[c];
        acc[10 + P4(a,c)] += re[a]*re[c];
      }
      acc[20 + a] += ab[a];
      acc[24 + a] += re[a];
    }
  }
  block_reduce_add<28, 4>(acc, outp);
}
__global__ __launch_bounds__(256, 1)
void ps_scaleB(const float2* __restrict__ u0, const float2* __restrict__ u1,
               const float2* __restrict__ u2, const float2* __restrict__ u3,
               const float2* __restrict__ s0, const float2* __restrict__ s1,
               const float2* __restrict__ s2, const float2* __restrict__ s3,
               int n, double* out){
  float acc[72];
  #pragma unroll
  for (int k = 0; k < 72; k++) acc[k] = 0.f;
  for (int i = blockIdx.x*blockDim.x + threadIdx.x; i < n; i += gridDim.x*blockDim.x){
    float2 u[4] = { u0[i], u1[i], u2[i], u3[i] };
    float2 bb[4] = { s0[i], s1[i], s2[i], s3[i] };
    float au[4], dre[4], dim[4], M[4], R[4];
    #pragma unroll
    for (int c = 0; c < 4; c++){
      float xx = u[c].x, yy = u[c].y;
      float mag = sqrtf(xx*xx + yy*yy);
      float den = mag + 1e-12f;
      au[c] = mag;
      dre[c] = (xx*xx - yy*yy)/den;
      dim[c] = (2.f*xx*yy)/den;
      M[c] = sqrtf(bb[c].x*bb[c].x + bb[c].y*bb[c].y);
      R[c] = bb[c].x;
    }
    #pragma unroll
    for (int c = 0; c < 4; c++){
      acc[c]      += au[c];
      acc[4 + c]  += au[c]*au[c];
      acc[24 + c] += dre[c];
      acc[28 + c] += dim[c];
      acc[32 + c] += dre[c]*dre[c];
      acc[36 + c] += dim[c]*dim[c];
    }
    #pragma unroll
    for (int a = 0; a < 4; a++)
      #pragma unroll
      for (int c = 0; c < 4; c++){
        acc[8 + a*4 + c]  += M[a]*au[c];
        acc[40 + a*4 + c] += R[a]*dre[c];
        acc[56 + a*4 + c] += R[a]*dim[c];
      }
  }
  block_reduce_add<72, 4>(acc, out);
}
__global__ __launch_bounds__(256, 1)
void ps_scaleC(const float2* __restrict__ s0, const float2* __restrict__ s1,
               const float2* __restrict__ s2, const float2* __restrict__ s3,
               const float* __restrict__ lp, int n, double* out){
  float acc[36];
  #pragma unroll
  for (int k = 0; k < 36; k++) acc[k] = 0.f;
  for (int i = blockIdx.x*blockDim.x + threadIdx.x; i < n; i += gridDim.x*blockDim.x){
    int y = i >> 7, x = i & 127;
    float L[5];
    L[0] = lp[i];
    L[1] = lp[(y << 7) | ((x + 126) & 127)];
    L[2] = lp[(y << 7) | ((x + 2) & 127)];
    L[3] = lp[(((y + 126) & 127) << 7) | x];
    L[4] = lp[(((y + 2) & 127) << 7) | x];
    float R[4] = { s0[i].x, s1[i].x, s2[i].x, s3[i].x };
    acc[0] += L[0];
    #pragma unroll
    for (int a = 0; a < 5; a++)
      #pragma unroll
      for (int c = a; c < 5; c++)
        acc[1 + P5(a,c)] += L[a]*L[c];
    #pragma unroll
    for (int a = 0; a < 4; a++)
      #pragma unroll
      for (int j = 0; j < 5; j++)
        acc[16 + a*5 + j] += R[a]*L[j];
  }
  block_reduce_add<36, 4>(acc, out);
}

// ---------------------------------------------------------------------------
// finalize — one thread per output element.
// ---------------------------------------------------------------------------
__device__ __forceinline__ double d_ns(int s){ double h = (double)(1024 >> s); return h*h; }
__device__ __forceinline__ void d_moments(const double* Mo, double n,
                                          double& sk, double& ku, double& var){
  double m = Mo[0]/n, e2 = Mo[1]/n, e3 = Mo[2]/n, e4 = Mo[3]/n;
  var = e2 - m*m;
  double c3 = e3 - 3.0*m*e2 + 2.0*m*m*m;
  double c4 = e4 - 4.0*m*e3 + 6.0*m*m*e2 - 3.0*m*m*m*m;
  sk = c3/pow(var,1.5); ku = c4/(var*var);
}
__device__ __forceinline__ int ac_o(int w, int& dy, int& dx){
  dy = w/9 - 4; dx = w - (w/9)*9 - 4;
  int ady = dy, adx = dx;
  if (dy < 0 || (dy == 0 && dx < 0)){ ady = -dy; adx = -dx; }
  return (ady == 0) ? adx : (5 + (ady-1)*9 + (adx+4));
}

__global__ __launch_bounds__(256)
void ps_finalize(const double* __restrict__ ST, const unsigned* __restrict__ MM,
                 float* __restrict__ out, int out_size){
  int idx = blockIdx.x*blockDim.x + threadIdx.x;
  if (idx >= out_size) return;
  const double n0 = 1048576.0;
  double val = 0.0;

  if (idx <= 5){
    if (idx == 4){ out[4] = decf(MM[0]); return; }
    if (idx == 5){ out[5] = decf(MM[1]); return; }
    double sk, ku, v; d_moments(ST, n0, sk, ku, v);
    val = (idx == 0) ? ST[0]/n0 : (idx == 1) ? v : (idx == 2) ? sk : ku;
  } else if (idx == 6){
    val = ST[8]/n0;
  } else if (idx <= 22){
    int i = idx - 7; int s = i >> 2, b = i & 3;
    val = ST[64 + s*32 + 20 + b] / d_ns(s);
  } else if (idx == 23){
    val = ST[10 + 4*6 + 4] / 4096.0;
  } else if (idx <= 1319){                      // band-mag ACs
    int i = idx - 24; int w = i >> 4; int j = i & 15;
    int s = j >> 2, b = j & 3;
    double n = d_ns(s);
    const double* R = ST + 752 + j*48;
    double mu = ST[64 + s*32 + 20 + b]/n, mu2 = mu*mu;
    int dy, dx; int o = ac_o(w, dy, dx);
    val = (R[o]/n - mu2) / (R[0]/n - mu2 + 1e-12);
  } else if (idx <= 1329){                      // skew_r / kurt_r
    int i = idx - 1320; bool kq = (i >= 5); int r = kq ? i - 5 : i;
    double n = (r == 4) ? 4096.0 : d_ns(r);
    double sk, ku, v; d_moments(ST + 10 + r*6, n, sk, ku, v);
    val = kq ? ku : sk;
  } else if (idx <= 1734){                      // recon ACs
    int i = idx - 1330; int w = i / 5; int r = i - w*5;
    double n = (r == 4) ? 4096.0 : d_ns(r);
    const double* R = ST + 512 + r*48;
    double mu = ST[10 + r*6]/n, mu2 = mu*mu;
    int dy, dx; int o = ac_o(w, dy, dx);
    val = (R[o]/n - mu2) / (R[0]/n - mu2 + 1e-12);
  } else if (idx <= 1739){                      // std_r
    int r = idx - 1735;
    double n = (r == 4) ? 4096.0 : d_ns(r);
    double sk, ku, v; d_moments(ST + 10 + r*6, n, sk, ku, v);
    val = sqrt(v);
  } else if (idx <= 1819){                      // com
    int i = idx - 1740; int s = i % 5; int q = i / 5; int a = q >> 2, b = q & 3;
    if (s < 4){
      double n = d_ns(s); const double* A = ST + 64 + s*32;
      double ma = A[20+a]/n, mb = A[20+b]/n;
      double caa = A[P4(a,a)]/n - ma*ma, cbb = A[P4(b,b)]/n - mb*mb;
      int lo = a < b ? a : b, hi = a < b ? b : a;
      double cab = A[P4(lo,hi)]/n - ma*mb;
      val = cab / (sqrt(caa)*sqrt(cbb) + 1e-12);
    }
  } else if (idx <= 1883){                      // csm
    int i = idx - 1820; int s = i & 3; int q = i >> 2; int a = q >> 2, c = q & 3;
    if (s < 3){
      double n = d_ns(s); const double* A = ST + 64 + s*32; const double* B = ST + 192 + s*80;
      double mM = A[20+a]/n; double sdM = sqrt(A[P4(a,a)]/n - mM*mM);
      double mU = B[c]/n;    double sdU = sqrt(B[4+c]/n - mU*mU);
      val = (B[8 + a*4 + c]/n - mM*mU) / (sdM*sdU + 1e-12);
    }
  } else if (idx <= 2203){                      // cor
    int i = idx - 1884; int s = i % 5; int q = i / 5; int a = q >> 3, b = q & 7;
    if (s < 4){
      if (a < 4 && b < 4){
        double n = d_ns(s); const double* A = ST + 64 + s*32;
        double ma = A[24+a]/n, mb = A[24+b]/n;
        double caa = A[10+P4(a,a)]/n - ma*ma, cbb = A[10+P4(b,b)]/n - mb*mb;
        int lo = a < b ? a : b, hi = a < b ? b : a;
        double cab = A[10+P4(lo,hi)]/n - ma*mb;
        val = cab / (sqrt(caa)*sqrt(cbb) + 1e-12);
      }
    } else {
      if (a < 5 && b < 5){
        const double* C = ST + 432; const double n3 = 16384.0;
        double lb = C[0]/n3;
        double caa = C[1+P5(a,a)]/n3 - lb*lb, cbb = C[1+P5(b,b)]/n3 - lb*lb;
        int lo = a < b ? a : b, hi = a < b ? b : a;
        double cab = C[1+P5(lo,hi)]/n3 - lb*lb;
        val = cab / (sqrt(caa)*sqrt(cbb) + 1e-12);
      }
    }
  } else if (idx <= 2459){                      // csr
    int i = idx - 2204; int s = i & 3; int q = i >> 2; int a = q >> 3, c = q & 7;
    if (a < 4){
      double n = d_ns(s); const double* A = ST + 64 + s*32;
      double mR = A[24+a]/n; double sdR = sqrt(A[10+P4(a,a)]/n - mR*mR);
      if (s < 3 && c < 8){
        const double* B = ST + 192 + s*80;
        if (c < 4){
          double md = B[24+c]/n; double sd = sqrt(B[32+c]/n - md*md);
          val = (B[40 + a*4 + c]/n - mR*md) / (sdR*sd + 1e-12);
        } else {
          int cc = c - 4;
          double md = B[28+cc]/n; double sd = sqrt(B[36+cc]/n - md*md);
          val = (B[56 + a*4 + cc]/n - mR*md) / (sdR*sd + 1e-12);
        }
      } else if (s == 3 && c < 5){
        const double* C = ST + 432; const double n3 = 16384.0;
        double lb = C[0]/n3;
        double sdL = sqrt(C[1+P5(c,c)]/n3 - lb*lb);
        val = (C[16 + a*5 + c]/n3 - mR*lb) / (sdR*sdL + 1e-12);
      }
    }
  } else {
    val = ST[5]/n0 - (ST[4]/n0)*(ST[4]/n0);
  }
  out[idx] = (float)val;
}

// ---------------------------------------------------------------------------
// host orchestration
// ---------------------------------------------------------------------------
static void rows_pass(int H, float2* dst, const void* src,
                      int nimg, int simg, int dimg, int srcH1,
                      float dir, int xin, int xout, int lop,
                      int moff, float mshift, hipStream_t st){
  dim3 g(nimg * H);
  switch (H){
    case 64:   ps_fft_rows<64>  <<<g, 64,  0, st>>>(dst, src, simg, dimg, srcH1, dir, xin, xout, lop, moff, mshift); break;
    case 128:  ps_fft_rows<128> <<<g, 64,  0, st>>>(dst, src, simg, dimg, srcH1, dir, xin, xout, lop, moff, mshift); break;
    case 256:  ps_fft_rows<256> <<<g, 64,  0, st>>>(dst, src, simg, dimg, srcH1, dir, xin, xout, lop, moff, mshift); break;
    case 512:  ps_fft_rows<512> <<<g, 128, 0, st>>>(dst, src, simg, dimg, srcH1, dir, xin, xout, lop, moff, mshift); break;
    case 1024: ps_fft_rows<1024><<<g, 256, 0, st>>>(dst, src, simg, dimg, srcH1, dir, xin, xout, lop, moff, mshift); break;
    default: break;
  }
}
static void cols_pass(int H, float2* dst, const float2* src, int nimg, int simg, int dimg,
                      float dir, int xin, int xout, float scale,
                      int sop, float* rdst, int rimg, double* mout, int mstride,
                      hipStream_t st){
  switch (H){
    case 64:   ps_fft_cols<64,16>  <<<dim3(nimg*(64/16)),  512, 0, st>>>(dst, src, simg, dimg, dir, xin, xout, scale, sop, rdst, rimg, mout, mstride); break;
    case 128:  ps_fft_cols<128,16> <<<dim3(nimg*(128/16)), 512, 0, st>>>(dst, src, simg, dimg, dir, xin, xout, scale, sop, rdst, rimg, mout, mstride); break;
    case 256:  ps_fft_cols<256,8>  <<<dim3(nimg*(256/8)),  512, 0, st>>>(dst, src, simg, dimg, dir, xin, xout, scale, sop, rdst, rimg, mout, mstride); break;
    case 512:  ps_fft_cols<512,8>  <<<dim3(nimg*(512/8)),  512, 0, st>>>(dst, src, simg, dimg, dir, xin, xout, scale, sop, rdst, rimg, mout, mstride); break;
    case 1024: ps_fft_cols<1024,4> <<<dim3(nimg*(1024/4)), 512, 0, st>>>(dst, src, simg, dimg, dir, xin, xout, scale, sop, rdst, rimg, mout, mstride); break;
    default: break;
  }
}

static inline dim3 gr(int n){ return dim3((n + 255)/256); }
static inline int  rblocks(int n){ int b = (n + 255)/256; return b > 512 ? 512 : b; }

#define FWD (-1.0f)
#define INV (+1.0f)

extern "C" void kernel_launch(void* const* d_in, const int* in_sizes, int n_in,
                              void* d_out, int out_size, void* d_ws, size_t ws_size,
                              hipStream_t stream){
  (void)in_sizes; (void)n_in;
  const float* im = (const float*)d_in[0];
  float* out = (float*)d_out;

  const int Hs[5]   = {1024, 512, 256, 128, 64};
  const int offs[5] = {0, 256, 384, 448, 480};

  // ---- carve workspace ----
  char* base = (char*)d_ws;
  size_t off = 0;
  auto carve = [&](size_t bytes)->void*{
    void* r = base + off;
    off = (off + bytes + 255) & ~(size_t)255;
    return r;
  };
  const int n0 = 1024*1024;
  float2* lod[5];
  for (int s = 0; s < 5; s++) lod[s] = (float2*)carve((size_t)Hs[s]*Hs[s]*sizeof(float2));
  float2* band[4];
  for (int s = 0; s < 4; s++) band[s] = (float2*)carve((size_t)4*Hs[s]*Hs[s]*sizeof(float2));
  float* reals0 = (float*)carve((size_t)2*n0*sizeof(float));  // [hp_real | recon0]
  float* recon[5];
  recon[0] = reals0 + n0;
  for (int s = 1; s < 5; s++) recon[s] = (float*)carve((size_t)Hs[s]*Hs[s]*sizeof(float));
  float* lp = (float*)carve(128*128*sizeof(float));
  float2* scr  = (float2*)carve((size_t)n0*sizeof(float2));
  float2* scr4 = (float2*)carve((size_t)4*n0*sizeof(float2));
  double* ST = (double*)carve(2048*sizeof(double));
  unsigned* MM = (unsigned*)carve(64*sizeof(unsigned));
  if (off > ws_size) return;

  // ---- init ----
  hipMemsetAsync(ST, 0, 2048*sizeof(double), stream);
  ps_init_mm<<<1, 1, 0, stream>>>(MM);
  ps_im_stats<<<256, 256, 0, stream>>>((const float4*)im, n0/4, ST + 0, MM);

  // ---- imdft (shifted) ----
  rows_pass(1024, scr, im, 1, 0, 0, 0, FWD, 0, 512, LOP_R2C, 0, 0.f, stream);
  cols_pass(1024, scr, scr, 1, 0, 0, FWD, 0, 512, 1.0f, SOP_NONE, nullptr, 0, nullptr, 0, stream);
  // hi -> scr4[img0], lo -> lod[0] and scr4[img1]
  ps_mask_hl<<<gr(n0), 256, 0, stream>>>(lod[0], scr4 + n0, scr4, scr);
  // batched 2-img inverse: img0 = hipass (stats->ST+4), img1 = recon0 (stats->ST+10)
  rows_pass(1024, scr4, scr4, 2, n0, n0, 0, INV, 512, 0, LOP_NONE, 0, 0.f, stream);
  cols_pass(1024, scr4, scr4, 2, n0, n0, INV, 512, 0, 1.0f/(float)n0,
            SOP_REAL, reals0, n0, ST + 4, 6, stream);

  // ---- pyramid scales: recon (stored + stats), bands (mask fused), lod chain ----
  for (int s = 0; s < 4; s++){
    int H = Hs[s], n = H*H;
    float invn = 1.0f/((float)H*(float)H);
    if (s > 0){
      rows_pass(H, scr, lod[s], 1, 0, 0, 0, INV, H/2, 0, LOP_NONE, 0, 0.f, stream);
      cols_pass(H, scr, scr, 1, 0, 0, INV, H/2, 0, invn, SOP_REAL, recon[s], 0,
                ST + 10 + s*6, 0, stream);
    }
    // band inverse with orientation mask fused into the rows load (img = band)
    rows_pass(H, band[s], lod[s], 4, 0, n, 0, INV, H/2, 0, LOP_BANDMASK,
              offs[s], -(float)(s+1), stream);
    cols_pass(H, band[s], band[s], 4, n, n, INV, H/2, 0, invn, SOP_NONE, nullptr, 0, nullptr, 0, stream);
    ps_crop_lo<<<gr((H/2)*(H/2)), 256, 0, stream>>>(lod[s+1], lod[s], H, offs[s+1], -(float)(s+1));
  }
  rows_pass(64, scr, lod[4], 1, 0, 0, 0, INV, 32, 0, LOP_NONE, 0, 0.f, stream);
  cols_pass(64, scr, scr, 1, 0, 0, INV, 32, 0, 1.0f/4096.f, SOP_REAL, recon[4], 0,
            ST + 10 + 4*6, 0, stream);

  // ---- all 21 autocorrelations in one launch ----
  {
    AcTaskTab tt{};
    int nt = 0, blk = 0;
    for (int r = 0; r < 5; r++){
      int H = Hs[r]; int tiles = (H>>5)*(H>>5); int nb = tiles < 128 ? tiles : 128;
      tt.src[nt] = recon[r]; tt.isMag[nt] = 0; tt.H[nt] = H; tt.npi[nt] = H*H;
      tt.nb[nt] = nb; tt.stOff[nt] = 512 + r*48; tt.stStride[nt] = 48;
      tt.blkStart[nt] = blk; blk += nb; nt++;
    }
    for (int s = 0; s < 4; s++){
      int H = Hs[s]; int tiles = (H>>5)*(H>>5); int nb = tiles < 128 ? tiles : 128;
      tt.src[nt] = band[s]; tt.isMag[nt] = 1; tt.H[nt] = H; tt.npi[nt] = H*H;
      tt.nb[nt] = nb; tt.stOff[nt] = 752 + s*4*48; tt.stStride[nt] = 48;
      tt.blkStart[nt] = blk; blk += nb*4; nt++;
    }
    tt.blkStart[nt] = blk; tt.nTasks = nt;
    ps_spat_ac_multi<<<dim3(blk), 256, 0, stream>>>(tt, ST);
  }

  // ---- per-scale band Grams (one launch) ----
  {
    ScaleATab ta{};
    for (int s = 0; s < 4; s++){ ta.b[s] = band[s]; ta.n[s] = Hs[s]*Hs[s]; }
    ps_scaleA_multi<<<dim3(512, 4), 256, 0, stream>>>(ta, ST);
  }

  // ---- cross-scale: pad + band-mask lod[s+1] directly (no staged band dfts) ----
  for (int s = 0; s < 3; s++){
    int H1 = Hs[s+1], H2 = Hs[s];
    int n2 = H2*H2;
    rows_pass(H2, scr4, lod[s+1], 4, 0, n2, H1, INV, H2/2, 0, LOP_PADMASK,
              offs[s+1], -(float)(s+2), stream);
    cols_pass(H2, scr4, scr4, 4, n2, n2, INV, H2/2, 0, 1.0f/(float)(H1*H1),
              SOP_NONE, nullptr, 0, nullptr, 0, stream);
    ps_scaleB<<<rblocks(n2), 256, 0, stream>>>(scr4, scr4+n2, scr4+2*n2, scr4+3*n2,
                                               band[s], band[s]+n2, band[s]+2*n2, band[s]+3*n2,
                                               n2, ST + 192 + s*80);
  }
  // s=3: expand2(lowpass) = pad lod[4] directly (no mask)
  rows_pass(128, scr4, lod[4], 1, 4096, 16384, 64, INV, 64, 0, LOP_PAD, 0, 0.f, stream);
  cols_pass(128, scr4, scr4, 1, 16384, 16384, INV, 64, 0, 1.0f/4096.f, SOP_REAL, lp, 0, nullptr, 0, stream);
  ps_scaleC<<<rblocks(16384), 256, 0, stream>>>(band[3], band[3]+16384, band[3]+2*16384, band[3]+3*16384,
                                                lp, 16384, ST + 432);

  // ---- finalize ----
  ps_finalize<<<gr(out_size), 256, 0, stream>>>(ST, MM, out, out_size);
}

// Round 11
// 480.772 us; speedup vs baseline: 1.8084x; 1.0412x over previous
//
#include <hip/hip_runtime.h>
#include <math.h>

#define PI_F 3.14159265358979323846f

enum { LOP_NONE=0, LOP_R2C, LOP_PAD, LOP_PADMASK, LOP_MIX };
enum { SOP_NONE=0, SOP_REAL, SOP_MIX };

// ---------------------------------------------------------------------------
// helpers
// ---------------------------------------------------------------------------
__host__ __device__ constexpr int P4(int a, int b){ return a*4 - a*(a-1)/2 + (b-a); }
__host__ __device__ constexpr int P5(int a, int b){ return a*5 - a*(a-1)/2 + (b-a); }

__device__ __forceinline__ unsigned encf(float f){
  unsigned u = __float_as_uint(f);
  return (u & 0x80000000u) ? ~u : (u | 0x80000000u);
}
__device__ __forceinline__ float decf(unsigned u){
  unsigned b = (u & 0x80000000u) ? (u ^ 0x80000000u) : ~u;
  return __uint_as_float(b);
}
__device__ __forceinline__ float2 cxmul(float2 a, float c, float s){
  return make_float2(c*a.x - s*a.y, c*a.y + s*a.x);
}
__device__ __forceinline__ float2 f2add(float2 a, float2 b){ return make_float2(a.x+b.x, a.y+b.y); }
__device__ __forceinline__ float2 f2sub(float2 a, float2 b){ return make_float2(a.x-b.x, a.y-b.y); }

// wave shuffle-reduce -> LDS -> ONE atomicAdd per counter per block.
template<int CNT, int WAVES>
__device__ __forceinline__ void block_reduce_add(float (&acc)[CNT], double* out){
  __shared__ float red[WAVES*CNT];
  int lane = threadIdx.x & 63;
  int wid  = threadIdx.x >> 6;
  #pragma unroll
  for (int k = 0; k < CNT; k++){
    float v = acc[k];
    #pragma unroll
    for (int o = 32; o > 0; o >>= 1) v += __shfl_down(v, o, 64);
    if (lane == 0) red[wid*CNT + k] = v;
  }
  __syncthreads();
  int t = threadIdx.x;
  if (t < CNT){
    double s = 0.0;
    #pragma unroll
    for (int w = 0; w < WAVES; w++) s += (double)red[w*CNT + t];
    atomicAdd(&out[t], s);
  }
  __syncthreads();
}

// float polar grid (ref computes masks in f64 then casts to f32)
__device__ __forceinline__ void polar_f(int iy, int ix, float& lr, float& ang){
  float yn = (float)(iy - 512) * (1.f/512.f);
  float xn = (float)(ix - 512) * (1.f/512.f);
  ang = atan2f(yn, xn);
  float rad = (iy == 512 && ix == 512) ? (1.f/512.f) : sqrtf(xn*xn + yn*yn);
  lr = log2f(rad);
}
__device__ __forceinline__ float f_hi(float lr, float shift){
  float v = fminf(fmaxf(lr - shift, -1.f), 0.f);
  return cosf((PI_F*0.5f) * v);
}
__device__ __forceinline__ float f_lo(float lr, float shift){
  float h = f_hi(lr, shift);
  float q = fminf(fmaxf(1.f - h*h, 0.f), 1.f);
  return sqrtf(q);
}
__device__ __forceinline__ float band_am(float ang, int b){
  float a0 = ang - (PI_F*0.25f)*(float)b + PI_F;
  float a = fmodf(a0, 2.f*PI_F);
  if (a < 0.f) a += 2.f*PI_F;
  a -= PI_F;
  float mk = 0.f;
  if (fabsf(a) < PI_F*0.5f){ float c = cosf(a); mk = 1.78885438199983f*c*c*c; }
  return mk;
}

// radix-4 butterfly on v[4]; fwd: omega=-i
__device__ __forceinline__ void bfly4(float2* v, bool fwd){
  float2 A = f2add(v[0], v[2]), B = f2sub(v[0], v[2]);
  float2 C = f2add(v[1], v[3]), D = f2sub(v[1], v[3]);
  float2 dj = fwd ? make_float2(D.y, -D.x) : make_float2(-D.y, D.x);
  v[0] = f2add(A, C);
  v[1] = f2add(B, dj);
  v[2] = f2sub(A, C);
  v[3] = f2sub(B, dj);
}

// ---------------------------------------------------------------------------
// FFT rows pass: one line per block, fused load-ops.
// LOP_MIX: img<nA -> plain load from vsrc (+img*simg); img>=nA -> read vsrc2
//          (shared lod) and apply 1j*hi*am_{img-nA}.
// LOP_PADMASK: zero-pad from H1 grid AND apply band mask while loading.
// ---------------------------------------------------------------------------
template<int N>
__global__ __launch_bounds__((N/4 < 64) ? 64 : N/4)
void ps_fft_rows(float2* __restrict__ dst, const void* __restrict__ vsrc,
                 const void* __restrict__ vsrc2, int nA,
                 int simg, int dimg, int srcH1,
                 float dir, int xin, int xout, int lop, int moff, float mshift)
{
  constexpr int T = (N/4 < 64) ? 64 : N/4;
  __shared__ float2 sm[N];
  const int t = threadIdx.x;
  const int l = blockIdx.x & (N-1);
  const int img = blockIdx.x / N;
  float2* dline = dst + (size_t)img*(size_t)dimg + (size_t)l*N;

  if (lop == LOP_PAD || lop == LOP_PADMASK){
    const int q = N/4;
    const int sl = l - q;
    if (sl < 0 || sl >= srcH1){
      for (int j = t; j < N; j += T) dline[j] = make_float2(0.f, 0.f);
      return;
    }
    const float2* s = (const float2*)vsrc + (size_t)img*simg + (size_t)sl*srcH1;
    if (lop == LOP_PAD){
      for (int j = t; j < N; j += T){
        int p = j ^ xin;
        sm[j] = (p >= q && p < q + srcH1) ? s[p - q] : make_float2(0.f, 0.f);
      }
    } else {
      for (int j = t; j < N; j += T){
        int p = j ^ xin;
        float2 r = make_float2(0.f, 0.f);
        if (p >= q && p < q + srcH1){
          int x = p - q;
          float lr, ang; polar_f(moff + sl, moff + x, lr, ang);
          float mf = f_hi(lr, mshift) * band_am(ang, img);
          float2 v = s[x];
          r = make_float2(-mf*v.y, mf*v.x);
        }
        sm[j] = r;
      }
    }
  } else if (lop == LOP_MIX){
    if (img < nA){
      const float2* s = (const float2*)vsrc + (size_t)img*(size_t)simg + (size_t)l*N;
      for (int j = t; j < N; j += T) sm[j] = s[j ^ xin];
    } else {
      const float2* s = (const float2*)vsrc2 + (size_t)l*N;
      const int b = img - nA;
      for (int j = t; j < N; j += T){
        int x = j ^ xin;
        float lr, ang; polar_f(moff + l, moff + x, lr, ang);
        float mf = f_hi(lr, mshift) * band_am(ang, b);
        float2 v = s[x];
        sm[j] = make_float2(-mf*v.y, mf*v.x);
      }
    }
  } else if (lop == LOP_R2C){
    const float* s = (const float*)vsrc + (size_t)img*simg + (size_t)l*N;
    for (int j = t; j < N; j += T) sm[j] = make_float2(s[j ^ xin], 0.f);
  } else {
    const float2* s = (const float2*)vsrc + (size_t)img*simg + (size_t)l*N;
    for (int j = t; j < N; j += T) sm[j] = s[j ^ xin];
  }
  __syncthreads();

  const bool fwd = (dir < 0.f);
  int Ns = 1;
  if constexpr ((N & 0xAAAAAAAAu) != 0){           // odd log2: radix-2 first
    constexpr int NB2 = N/2;
    constexpr int P2 = (NB2 + T - 1)/T;
    float2 a[P2], b[P2];
    #pragma unroll
    for (int p = 0; p < P2; p++){
      int q = t + p*T;
      if (q < NB2){ a[p] = sm[q]; b[p] = sm[q + N/2]; }
    }
    __syncthreads();
    #pragma unroll
    for (int p = 0; p < P2; p++){
      int q = t + p*T;
      if (q < NB2){
        sm[2*q]   = f2add(a[p], b[p]);
        sm[2*q+1] = f2sub(a[p], b[p]);
      }
    }
    __syncthreads();
    Ns = 2;
  }
  constexpr int NB4 = N/4;
  for (; Ns < N; Ns <<= 2){
    float2 v[4];
    int q = t;
    int k = 0;
    if (q < NB4){
      k = q & (Ns - 1);
      #pragma unroll
      for (int r = 0; r < 4; r++) v[r] = sm[q + r*NB4];
      if (k){
        float ang = dir * (PI_F*0.5f) * (float)k / (float)Ns;
        float s1, c1; __sincosf(ang, &s1, &c1);
        float c2 = c1*c1 - s1*s1, s2 = 2.f*c1*s1;
        float c3 = c1*c2 - s1*s2, s3 = c1*s2 + s1*c2;
        v[1] = cxmul(v[1], c1, s1);
        v[2] = cxmul(v[2], c2, s2);
        v[3] = cxmul(v[3], c3, s3);
      }
      bfly4(v, fwd);
    }
    __syncthreads();
    if (q < NB4){
      int dd = ((q - k) << 2) + k;
      sm[dd]        = v[0];
      sm[dd + Ns]   = v[1];
      sm[dd + 2*Ns] = v[2];
      sm[dd + 3*Ns] = v[3];
    }
    __syncthreads();
  }
  for (int j = t; j < N; j += T) dline[j ^ xout] = sm[j];
}

// ---------------------------------------------------------------------------
// FFT cols pass: CB adjacent columns per block (coalesced). src/dst may alias.
// SOP_MIX: img<nA -> real store to rdst(+img*rimg) + 5-moment stats to
//          mout(+img*mstride); img>=nA -> complex store to dst(+(img-nA)*dimg).
// ---------------------------------------------------------------------------
template<int N, int CB>
__global__ __launch_bounds__(512)
void ps_fft_cols(float2* __restrict__ dst, const float2* __restrict__ src,
                 int nA, int simg, int dimg,
                 float dir, int xin, int xout, float scale,
                 int sop, float* __restrict__ rdst, int rimg,
                 double* __restrict__ mout, int mstride)
{
  constexpr int T = 512;
  constexpr int LCB = (CB==2)?1:(CB==4)?2:(CB==8)?3:4;
  constexpr int NBK = N / CB;
  constexpr int NE = N*CB;
  __shared__ float2 sm[NE];
  const int t = threadIdx.x;
  const int img = blockIdx.x / NBK;
  const int c0 = (blockIdx.x % NBK) * CB;
  const float2* sbase = src + (size_t)img*(size_t)simg + c0;

  for (int e = t; e < NE; e += T){
    int j = e >> LCB, c = e & (CB - 1);
    sm[e] = sbase[(size_t)(j ^ xin)*N + c];
  }
  __syncthreads();

  const bool fwd = (dir < 0.f);
  int Ns = 1;
  if constexpr ((N & 0xAAAAAAAAu) != 0){
    constexpr int NB2 = (N/2)*CB;
    constexpr int P2 = (NB2 + T - 1)/T;
    float2 a[P2], b[P2];
    #pragma unroll
    for (int p = 0; p < P2; p++){
      int q = t + p*T;
      if (q < NB2){
        int c = q & (CB-1), tt = q >> LCB;
        a[p] = sm[tt*CB + c];
        b[p] = sm[(tt + N/2)*CB + c];
      }
    }
    __syncthreads();
    #pragma unroll
    for (int p = 0; p < P2; p++){
      int q = t + p*T;
      if (q < NB2){
        int c = q & (CB-1), tt = q >> LCB;
        sm[(2*tt)*CB + c]   = f2add(a[p], b[p]);
        sm[(2*tt+1)*CB + c] = f2sub(a[p], b[p]);
      }
    }
    __syncthreads();
    Ns = 2;
  }
  constexpr int NB4 = (N/4)*CB;
  constexpr int PB = (NB4 + T - 1)/T;
  for (; Ns < N; Ns <<= 2){
    float2 v[PB][4];
    int kk[PB];
    #pragma unroll
    for (int p = 0; p < PB; p++){
      int q = t + p*T;
      if (q < NB4){
        int c = q & (CB-1), tt = q >> LCB;
        int k = tt & (Ns - 1);
        kk[p] = k;
        #pragma unroll
        for (int r = 0; r < 4; r++) v[p][r] = sm[(tt + r*(N/4))*CB + c];
        if (k){
          float ang = dir * (PI_F*0.5f) * (float)k / (float)Ns;
          float s1, c1; __sincosf(ang, &s1, &c1);
          float c2 = c1*c1 - s1*s1, s2 = 2.f*c1*s1;
          float c3 = c1*c2 - s1*s2, s3 = c1*s2 + s1*c2;
          v[p][1] = cxmul(v[p][1], c1, s1);
          v[p][2] = cxmul(v[p][2], c2, s2);
          v[p][3] = cxmul(v[p][3], c3, s3);
        }
        bfly4(v[p], fwd);
      }
    }
    __syncthreads();
    #pragma unroll
    for (int p = 0; p < PB; p++){
      int q = t + p*T;
      if (q < NB4){
        int c = q & (CB-1), tt = q >> LCB;
        int k = kk[p];
        int dd = ((tt - k) << 2) + k;
        sm[(dd)*CB + c]        = v[p][0];
        sm[(dd + Ns)*CB + c]   = v[p][1];
        sm[(dd + 2*Ns)*CB + c] = v[p][2];
        sm[(dd + 3*Ns)*CB + c] = v[p][3];
      }
    }
    __syncthreads();
  }

  bool doReal = (sop == SOP_REAL) || (sop == SOP_MIX && img < nA);
  if (doReal){
    int ri = (sop == SOP_MIX) ? img : img;
    for (int e = t; e < NE; e += T){
      int j = e >> LCB, c = e & (CB - 1);
      rdst[(size_t)ri*(size_t)rimg + (size_t)(j ^ xout)*N + c0 + c] = sm[j*CB + c].x * scale;
    }
  } else {
    int di = (sop == SOP_MIX) ? (img - nA) : img;
    float2* dbase = dst + (size_t)di*(size_t)dimg + c0;
    for (int e = t; e < NE; e += T){
      int j = e >> LCB, c = e & (CB - 1);
      float2 v = sm[j*CB + c];
      dbase[(size_t)(j ^ xout)*N + c] = make_float2(v.x*scale, v.y*scale);
    }
  }
  if (mout && doReal){
    float acc[5] = {0.f,0.f,0.f,0.f,0.f};
    for (int e = t; e < NE; e += T){
      float r = sm[e].x * scale, r2 = r*r;
      acc[0] += r; acc[1] += r2; acc[2] += r2*r; acc[3] += r2*r2; acc[4] += fabsf(r);
    }
    block_reduce_add<5, 8>(acc, mout + (size_t)img*mstride);
  }
}

// ---------------------------------------------------------------------------
// spatial circular autocorrelation, 9x9 lags, ALL 21 arrays in ONE launch.
// 4 px/thread; tile stride 41 (round-9: stride 40 -> 8-way conflict).
// Round-10 lesson: conflicts weren't the limiter; occupancy/tail was ->
// nb cap raised 128->256, big tasks first.
// ---------------------------------------------------------------------------
#define MAX_AC_TASKS 9
#define TSTR 41
struct AcTaskTab {
  const void* src[MAX_AC_TASKS];
  int isMag[MAX_AC_TASKS];
  int H[MAX_AC_TASKS];
  int npi[MAX_AC_TASKS];
  int nb[MAX_AC_TASKS];
  int stOff[MAX_AC_TASKS];
  int stStride[MAX_AC_TASKS];
  int blkStart[MAX_AC_TASKS+1];
  int nTasks;
};

__global__ __launch_bounds__(256, 1)
void ps_spat_ac_multi(AcTaskTab tt, double* __restrict__ ST)
{
  __shared__ float tile[40*TSTR];
  const int gb = blockIdx.x;
  int tk = 0;
  while (tk + 1 < tt.nTasks && gb >= tt.blkStart[tk+1]) tk++;
  const int lb  = gb - tt.blkStart[tk];
  const int nb  = tt.nb[tk];
  const int img = lb / nb;
  const int b0  = lb - img*nb;
  const int H = tt.H[tk];
  const int n_per_img = tt.npi[tk];
  const int isMag = tt.isMag[tk];
  const void* vsrc = tt.src[tk];
  const int t = threadIdx.x;
  const int tilesX = H >> 5;
  const int tiles = tilesX * tilesX;
  const int py  = t >> 3;          // 0..31
  const int px0 = (t & 7) << 2;    // 0,4,..,28
  float acc[41];
  #pragma unroll
  for (int k = 0; k < 41; k++) acc[k] = 0.f;

  for (int tl = b0; tl < tiles; tl += nb){
    int by = tl / tilesX, bx = tl - by*tilesX;
    int y0 = by << 5, x0 = bx << 5;
    __syncthreads();
    for (int e = t; e < 40*40; e += 256){
      int ly = e / 40, lx = e - ly*40;
      int gy = (y0 + ly - 4) & (H - 1);
      int gx = (x0 + lx - 4) & (H - 1);
      float v;
      if (isMag){
        float2 c = ((const float2*)vsrc)[(size_t)img*n_per_img + (size_t)gy*H + gx];
        v = sqrtf(c.x*c.x + c.y*c.y);
      } else {
        v = ((const float*)vsrc)[(size_t)img*n_per_img + (size_t)gy*H + gx];
      }
      tile[ly*TSTR + lx] = v;
    }
    __syncthreads();
    {
      const float* row0 = tile + (py+4)*TSTR + (px0+4);
      float c0 = row0[0], c1 = row0[1], c2 = row0[2], c3 = row0[3];
      {
        float r[8];
        #pragma unroll
        for (int i = 0; i < 8; i++) r[i] = row0[i];
        #pragma unroll
        for (int dx = 0; dx <= 4; dx++)
          acc[dx] += c0*r[dx] + c1*r[dx+1] + c2*r[dx+2] + c3*r[dx+3];
      }
      #pragma unroll
      for (int dy = 1; dy <= 4; dy++){
        const float* rw = tile + (py+4+dy)*TSTR + px0;
        float r[12];
        #pragma unroll
        for (int i = 0; i < 12; i++) r[i] = rw[i];
        #pragma unroll
        for (int dx = -4; dx <= 4; dx++)
          acc[5 + (dy-1)*9 + (dx+4)] += c0*r[4+dx] + c1*r[5+dx] + c2*r[6+dx] + c3*r[7+dx];
      }
    }
  }
  block_reduce_add<41, 4>(acc, ST + tt.stOff[tk] + (size_t)img*tt.stStride[tk]);
}

// ---------------------------------------------------------------------------
// elementwise kernels (float masks)
// ---------------------------------------------------------------------------
__global__ __launch_bounds__(256)
void ps_mask_hl(float2* __restrict__ lo1, float2* __restrict__ lo2,
                float2* __restrict__ hi_dst, const float2* __restrict__ src){
  int i = blockIdx.x*blockDim.x + threadIdx.x;
  if (i >= 1024*1024) return;
  int y = i >> 10, x = i & 1023;
  float lr, ang; polar_f(y, x, lr, ang);
  float2 v = src[i];
  float lo = f_lo(lr, 0.f), hi = f_hi(lr, 0.f);
  float2 lv = make_float2(v.x*lo, v.y*lo);
  lo1[i] = lv;
  lo2[i] = lv;
  hi_dst[i] = make_float2(v.x*hi, v.y*hi);
}
__global__ __launch_bounds__(256)
void ps_crop_lo(float2* dst, const float2* src, int Hs, int offNew, float shift){
  int Hd = Hs/2;
  int i = blockIdx.x*blockDim.x + threadIdx.x;
  if (i >= Hd*Hd) return;
  int y = i / Hd, x = i - y*Hd;
  float lr, ang; polar_f(offNew + y, offNew + x, lr, ang);
  float mk = f_lo(lr, shift);
  float2 v = src[(y + Hs/4)*Hs + (x + Hs/4)];
  dst[i] = make_float2(v.x*mk, v.y*mk);
}

// ---------------------------------------------------------------------------
// reductions
// ---------------------------------------------------------------------------
__global__ void ps_init_mm(unsigned* mm){ mm[0] = 0xFFFFFFFFu; mm[1] = 0u; }

__global__ __launch_bounds__(256, 1)
void ps_im_stats(const float4* __restrict__ x4, int n4, double* out, unsigned* mm){
  float acc[4] = {0.f,0.f,0.f,0.f};
  float mn = INFINITY, mx = -INFINITY;
  for (int i = blockIdx.x*blockDim.x + threadIdx.x; i < n4; i += gridDim.x*blockDim.x){
    float4 v = x4[i];
    float a0 = v.x, a1 = v.y, a2 = v.z, a3 = v.w;
    acc[0] += a0 + a1 + a2 + a3;
    acc[1] += a0*a0 + a1*a1 + a2*a2 + a3*a3;
    acc[2] += a0*a0*a0 + a1*a1*a1 + a2*a2*a2 + a3*a3*a3;
    acc[3] += a0*a0*a0*a0 + a1*a1*a1*a1 + a2*a2*a2*a2 + a3*a3*a3*a3;
    mn = fminf(mn, fminf(fminf(a0,a1), fminf(a2,a3)));
    mx = fmaxf(mx, fmaxf(fmaxf(a0,a1), fmaxf(a2,a3)));
  }
  block_reduce_add<4, 4>(acc, out);
  #pragma unroll
  for (int o = 32; o > 0; o >>= 1){
    mn = fminf(mn, __shfl_down(mn, o, 64));
    mx = fmaxf(mx, __shfl_down(mx, o, 64));
  }
  if ((threadIdx.x & 63) == 0){
    atomicMin(&mm[0], encf(mn));
    atomicMax(&mm[1], encf(mx));
  }
}

struct ScaleATab { const float2* b[4]; int n[4]; };
__global__ __launch_bounds__(256, 1)
void ps_scaleA_multi(ScaleATab tt, double* __restrict__ ST){
  int s = blockIdx.y;
  int n = tt.n[s];
  if ((size_t)blockIdx.x*blockDim.x >= (size_t)n) return;
  const float2* bb = tt.b[s];
  double* outp = ST + 64 + s*32;
  float acc[28];
  #pragma unroll
  for (int k = 0; k < 28; k++) acc[k] = 0.f;
  for (int i = blockIdx.x*blockDim.x + threadIdx.x; i < n; i += gridDim.x*blockDim.x){
    float2 v0 = bb[i], v1 = bb[(size_t)n + i], v2 = bb[2*(size_t)n + i], v3 = bb[3*(size_t)n + i];
    float ab[4] = { sqrtf(v0.x*v0.x+v0.y*v0.y), sqrtf(v1.x*v1.x+v1.y*v1.y),
                    sqrtf(v2.x*v2.x+v2.y*v2.y), sqrtf(v3.x*v3.x+v3.y*v3.y) };
    float re[4] = { v0.x, v1.x, v2.x, v3.x };
    #pragma unroll
    for (int a = 0; a < 4; a++){
      #pragma unroll
      for (int c = a; c < 4; c++){
        acc[P4(a,c)]      += ab[a]*ab[c];
        acc[10 + P4(a,c)] += re[a]*re[c];
      }
      acc[20 + a] += ab[a];
      acc[24 + a] += re[a];
    }
  }
  block_reduce_add<28, 4>(acc, outp);
}
__global__ __launch_bounds__(256, 1)
void ps_scaleB(const float2* __restrict__ u0, const float2* __restrict__ u1,
               const float2* __restrict__ u2, const float2* __restrict__ u3,
               const float2* __restrict__ s0, const float2* __restrict__ s1,
               const float2* __restrict__ s2, const float2* __restrict__ s3,
               int n, double* out){
  float acc[72];
  #pragma unroll
  for (int k = 0; k < 72; k++) acc[k] = 0.f;
  for (int i = blockIdx.x*blockDim.x + threadIdx.x; i < n; i += gridDim.x*blockDim.x){
    float2 u[4] = { u0[i], u1[i], u2[i], u3[i] };
    float2 bb[4] = { s0[i], s1[i], s2[i], s3[i] };
    float au[4], dre[4], dim[4], M[4], R[4];
    #pragma unroll
    for (int c = 0; c < 4; c++){
      float xx = u[c].x, yy = u[c].y;
      float mag = sqrtf(xx*xx + yy*yy);
      float den = mag + 1e-12f;
      au[c] = mag;
      dre[c] = (xx*xx - yy*yy)/den;
      dim[c] = (2.f*xx*yy)/den;
      M[c] = sqrtf(bb[c].x*bb[c].x + bb[c].y*bb[c].y);
      R[c] = bb[c].x;
    }
    #pragma unroll
    for (int c = 0; c < 4; c++){
      acc[c]      += au[c];
      acc[4 + c]  += au[c]*au[c];
      acc[24 + c] += dre[c];
      acc[28 + c] += dim[c];
      acc[32 + c] += dre[c]*dre[c];
      acc[36 + c] += dim[c]*dim[c];
    }
    #pragma unroll
    for (int a = 0; a < 4; a++)
      #pragma unroll
      for (int c = 0; c < 4; c++){
        acc[8 + a*4 + c]  += M[a]*au[c];
        acc[40 + a*4 + c] += R[a]*dre[c];
        acc[56 + a*4 + c] += R[a]*dim[c];
      }
  }
  block_reduce_add<72, 4>(acc, out);
}
__global__ __launch_bounds__(256, 1)
void ps_scaleC(const float2* __restrict__ s0, const float2* __restrict__ s1,
               const float2* __restrict__ s2, const float2* __restrict__ s3,
               const float* __restrict__ lp, int n, double* out){
  float acc[36];
  #pragma unroll
  for (int k = 0; k < 36; k++) acc[k] = 0.f;
  for (int i = blockIdx.x*blockDim.x + threadIdx.x; i < n; i += gridDim.x*blockDim.x){
    int y = i >> 7, x = i & 127;
    float L[5];
    L[0] = lp[i];
    L[1] = lp[(y << 7) | ((x + 126) & 127)];
    L[2] = lp[(y << 7) | ((x + 2) & 127)];
    L[3] = lp[(((y + 126) & 127) << 7) | x];
    L[4] = lp[(((y + 2) & 127) << 7) | x];
    float R[4] = { s0[i].x, s1[i].x, s2[i].x, s3[i].x };
    acc[0] += L[0];
    #pragma unroll
    for (int a = 0; a < 5; a++)
      #pragma unroll
      for (int c = a; c < 5; c++)
        acc[1 + P5(a,c)] += L[a]*L[c];
    #pragma unroll
    for (int a = 0; a < 4; a++)
      #pragma unroll
      for (int j = 0; j < 5; j++)
        acc[16 + a*5 + j] += R[a]*L[j];
  }
  block_reduce_add<36, 4>(acc, out);
}

// ---------------------------------------------------------------------------
// finalize — one thread per output element.
// ---------------------------------------------------------------------------
__device__ __forceinline__ double d_ns(int s){ double h = (double)(1024 >> s); return h*h; }
__device__ __forceinline__ void d_moments(const double* Mo, double n,
                                          double& sk, double& ku, double& var){
  double m = Mo[0]/n, e2 = Mo[1]/n, e3 = Mo[2]/n, e4 = Mo[3]/n;
  var = e2 - m*m;
  double c3 = e3 - 3.0*m*e2 + 2.0*m*m*m;
  double c4 = e4 - 4.0*m*e3 + 6.0*m*m*e2 - 3.0*m*m*m*m;
  sk = c3/pow(var,1.5); ku = c4/(var*var);
}
__device__ __forceinline__ int ac_o(int w, int& dy, int& dx){
  dy = w/9 - 4; dx = w - (w/9)*9 - 4;
  int ady = dy, adx = dx;
  if (dy < 0 || (dy == 0 && dx < 0)){ ady = -dy; adx = -dx; }
  return (ady == 0) ? adx : (5 + (ady-1)*9 + (adx+4));
}

__global__ __launch_bounds__(256)
void ps_finalize(const double* __restrict__ ST, const unsigned* __restrict__ MM,
                 float* __restrict__ out, int out_size){
  int idx = blockIdx.x*blockDim.x + threadIdx.x;
  if (idx >= out_size) return;
  const double n0 = 1048576.0;
  double val = 0.0;

  if (idx <= 5){
    if (idx == 4){ out[4] = decf(MM[0]); return; }
    if (idx == 5){ out[5] = decf(MM[1]); return; }
    double sk, ku, v; d_moments(ST, n0, sk, ku, v);
    val = (idx == 0) ? ST[0]/n0 : (idx == 1) ? v : (idx == 2) ? sk : ku;
  } else if (idx == 6){
    val = ST[8]/n0;
  } else if (idx <= 22){
    int i = idx - 7; int s = i >> 2, b = i & 3;
    val = ST[64 + s*32 + 20 + b] / d_ns(s);
  } else if (idx == 23){
    val = ST[10 + 4*6 + 4] / 4096.0;
  } else if (idx <= 1319){                      // band-mag ACs
    int i = idx - 24; int w = i >> 4; int j = i & 15;
    int s = j >> 2, b = j & 3;
    double n = d_ns(s);
    const double* R = ST + 752 + j*48;
    double mu = ST[64 + s*32 + 20 + b]/n, mu2 = mu*mu;
    int dy, dx; int o = ac_o(w, dy, dx);
    val = (R[o]/n - mu2) / (R[0]/n - mu2 + 1e-12);
  } else if (idx <= 1329){                      // skew_r / kurt_r
    int i = idx - 1320; bool kq = (i >= 5); int r = kq ? i - 5 : i;
    double n = (r == 4) ? 4096.0 : d_ns(r);
    double sk, ku, v; d_moments(ST + 10 + r*6, n, sk, ku, v);
    val = kq ? ku : sk;
  } else if (idx <= 1734){                      // recon ACs
    int i = idx - 1330; int w = i / 5; int r = i - w*5;
    double n = (r == 4) ? 4096.0 : d_ns(r);
    const double* R = ST + 512 + r*48;
    double mu = ST[10 + r*6]/n, mu2 = mu*mu;
    int dy, dx; int o = ac_o(w, dy, dx);
    val = (R[o]/n - mu2) / (R[0]/n - mu2 + 1e-12);
  } else if (idx <= 1739){                      // std_r
    int r = idx - 1735;
    double n = (r == 4) ? 4096.0 : d_ns(r);
    double sk, ku, v; d_moments(ST + 10 + r*6, n, sk, ku, v);
    val = sqrt(v);
  } else if (idx <= 1819){                      // com
    int i = idx - 1740; int s = i % 5; int q = i / 5; int a = q >> 2, b = q & 3;
    if (s < 4){
      double n = d_ns(s); const double* A = ST + 64 + s*32;
      double ma = A[20+a]/n, mb = A[20+b]/n;
      double caa = A[P4(a,a)]/n - ma*ma, cbb = A[P4(b,b)]/n - mb*mb;
      int lo = a < b ? a : b, hi = a < b ? b : a;
      double cab = A[P4(lo,hi)]/n - ma*mb;
      val = cab / (sqrt(caa)*sqrt(cbb) + 1e-12);
    }
  } else if (idx <= 1883){                      // csm
    int i = idx - 1820; int s = i & 3; int q = i >> 2; int a = q >> 2, c = q & 3;
    if (s < 3){
      double n = d_ns(s); const double* A = ST + 64 + s*32; const double* B = ST + 192 + s*80;
      double mM = A[20+a]/n; double sdM = sqrt(A[P4(a,a)]/n - mM*mM);
      double mU = B[c]/n;    double sdU = sqrt(B[4+c]/n - mU*mU);
      val = (B[8 + a*4 + c]/n - mM*mU) / (sdM*sdU + 1e-12);
    }
  } else if (idx <= 2203){                      // cor
    int i = idx - 1884; int s = i % 5; int q = i / 5; int a = q >> 3, b = q & 7;
    if (s < 4){
      if (a < 4 && b < 4){
        double n = d_ns(s); const double* A = ST + 64 + s*32;
        double ma = A[24+a]/n, mb = A[24+b]/n;
        double caa = A[10+P4(a,a)]/n - ma*ma, cbb = A[10+P4(b,b)]/n - mb*mb;
        int lo = a < b ? a : b, hi = a < b ? b : a;
        double cab = A[10+P4(lo,hi)]/n - ma*mb;
        val = cab / (sqrt(caa)*sqrt(cbb) + 1e-12);
      }
    } else {
      if (a < 5 && b < 5){
        const double* C = ST + 432; const double n3 = 16384.0;
        double lb = C[0]/n3;
        double caa = C[1+P5(a,a)]/n3 - lb*lb, cbb = C[1+P5(b,b)]/n3 - lb*lb;
        int lo = a < b ? a : b, hi = a < b ? b : a;
        double cab = C[1+P5(lo,hi)]/n3 - lb*lb;
        val = cab / (sqrt(caa)*sqrt(cbb) + 1e-12);
      }
    }
  } else if (idx <= 2459){                      // csr
    int i = idx - 2204; int s = i & 3; int q = i >> 2; int a = q >> 3, c = q & 7;
    if (a < 4){
      double n = d_ns(s); const double* A = ST + 64 + s*32;
      double mR = A[24+a]/n; double sdR = sqrt(A[10+P4(a,a)]/n - mR*mR);
      if (s < 3 && c < 8){
        const double* B = ST + 192 + s*80;
        if (c < 4){
          double md = B[24+c]/n; double sd = sqrt(B[32+c]/n - md*md);
          val = (B[40 + a*4 + c]/n - mR*md) / (sdR*sd + 1e-12);
        } else {
          int cc = c - 4;
          double md = B[28+cc]/n; double sd = sqrt(B[36+cc]/n - md*md);
          val = (B[56 + a*4 + cc]/n - mR*md) / (sdR*sd + 1e-12);
        }
      } else if (s == 3 && c < 5){
        const double* C = ST + 432; const double n3 = 16384.0;
        double lb = C[0]/n3;
        double sdL = sqrt(C[1+P5(c,c)]/n3 - lb*lb);
        val = (C[16 + a*5 + c]/n3 - mR*lb) / (sdR*sdL + 1e-12);
      }
    }
  } else {
    val = ST[5]/n0 - (ST[4]/n0)*(ST[4]/n0);
  }
  out[idx] = (float)val;
}

// ---------------------------------------------------------------------------
// host orchestration
// ---------------------------------------------------------------------------
static void rows_pass(int H, float2* dst, const void* src, const void* src2, int nA,
                      int nimg, int simg, int dimg, int srcH1,
                      float dir, int xin, int xout, int lop,
                      int moff, float mshift, hipStream_t st){
  dim3 g(nimg * H);
  switch (H){
    case 64:   ps_fft_rows<64>  <<<g, 64,  0, st>>>(dst, src, src2, nA, simg, dimg, srcH1, dir, xin, xout, lop, moff, mshift); break;
    case 128:  ps_fft_rows<128> <<<g, 64,  0, st>>>(dst, src, src2, nA, simg, dimg, srcH1, dir, xin, xout, lop, moff, mshift); break;
    case 256:  ps_fft_rows<256> <<<g, 64,  0, st>>>(dst, src, src2, nA, simg, dimg, srcH1, dir, xin, xout, lop, moff, mshift); break;
    case 512:  ps_fft_rows<512> <<<g, 128, 0, st>>>(dst, src, src2, nA, simg, dimg, srcH1, dir, xin, xout, lop, moff, mshift); break;
    case 1024: ps_fft_rows<1024><<<g, 256, 0, st>>>(dst, src, src2, nA, simg, dimg, srcH1, dir, xin, xout, lop, moff, mshift); break;
    default: break;
  }
}
static void cols_pass(int H, float2* dst, const float2* src, int nA,
                      int nimg, int simg, int dimg,
                      float dir, int xin, int xout, float scale,
                      int sop, float* rdst, int rimg, double* mout, int mstride,
                      hipStream_t st){
  switch (H){
    case 64:   ps_fft_cols<64,16>  <<<dim3(nimg*(64/16)),  512, 0, st>>>(dst, src, nA, simg, dimg, dir, xin, xout, scale, sop, rdst, rimg, mout, mstride); break;
    case 128:  ps_fft_cols<128,16> <<<dim3(nimg*(128/16)), 512, 0, st>>>(dst, src, nA, simg, dimg, dir, xin, xout, scale, sop, rdst, rimg, mout, mstride); break;
    case 256:  ps_fft_cols<256,8>  <<<dim3(nimg*(256/8)),  512, 0, st>>>(dst, src, nA, simg, dimg, dir, xin, xout, scale, sop, rdst, rimg, mout, mstride); break;
    case 512:  ps_fft_cols<512,8>  <<<dim3(nimg*(512/8)),  512, 0, st>>>(dst, src, nA, simg, dimg, dir, xin, xout, scale, sop, rdst, rimg, mout, mstride); break;
    case 1024: ps_fft_cols<1024,4> <<<dim3(nimg*(1024/4)), 512, 0, st>>>(dst, src, nA, simg, dimg, dir, xin, xout, scale, sop, rdst, rimg, mout, mstride); break;
    default: break;
  }
}

static inline dim3 gr(int n){ return dim3((n + 255)/256); }
static inline int  rblocks(int n){ int b = (n + 255)/256; return b > 512 ? 512 : b; }

#define FWD (-1.0f)
#define INV (+1.0f)

extern "C" void kernel_launch(void* const* d_in, const int* in_sizes, int n_in,
                              void* d_out, int out_size, void* d_ws, size_t ws_size,
                              hipStream_t stream){
  (void)in_sizes; (void)n_in;
  const float* im = (const float*)d_in[0];
  float* out = (float*)d_out;

  const int Hs[5]   = {1024, 512, 256, 128, 64};
  const int offs[5] = {0, 256, 384, 448, 480};

  // ---- carve workspace ----
  char* base = (char*)d_ws;
  size_t off = 0;
  auto carve = [&](size_t bytes)->void*{
    void* r = base + off;
    off = (off + bytes + 255) & ~(size_t)255;
    return r;
  };
  const int n0 = 1024*1024;
  float2* lod[5];
  for (int s = 0; s < 5; s++) lod[s] = (float2*)carve((size_t)Hs[s]*Hs[s]*sizeof(float2));
  float2* band[4];
  for (int s = 0; s < 4; s++) band[s] = (float2*)carve((size_t)4*Hs[s]*Hs[s]*sizeof(float2));
  float* reals0 = (float*)carve((size_t)2*n0*sizeof(float));  // [hp_real | recon0]
  float* recon[5];
  recon[0] = reals0 + n0;
  for (int s = 1; s < 5; s++) recon[s] = (float*)carve((size_t)Hs[s]*Hs[s]*sizeof(float));
  float* lp = (float*)carve(128*128*sizeof(float));
  float2* scr  = (float2*)carve((size_t)n0*sizeof(float2));
  float2* scr4 = (float2*)carve((size_t)6*n0*sizeof(float2));
  double* ST = (double*)carve(2048*sizeof(double));
  unsigned* MM = (unsigned*)carve(64*sizeof(unsigned));
  if (off > ws_size) return;

  // ---- init ----
  hipMemsetAsync(ST, 0, 2048*sizeof(double), stream);
  ps_init_mm<<<1, 1, 0, stream>>>(MM);
  ps_im_stats<<<256, 256, 0, stream>>>((const float4*)im, n0/4, ST + 0, MM);

  // ---- imdft (shifted) ----
  rows_pass(1024, scr, im, nullptr, 0, 1, 0, 0, 0, FWD, 0, 512, LOP_R2C, 0, 0.f, stream);
  cols_pass(1024, scr, scr, 0, 1, 0, 0, FWD, 0, 512, 1.0f, SOP_NONE, nullptr, 0, nullptr, 0, stream);
  // hi -> scr4[0], lo -> lod[0] and scr4[1]
  ps_mask_hl<<<gr(n0), 256, 0, stream>>>(lod[0], scr4 + n0, scr4, scr);

  // ---- pyramid scales: MIX pass = [hp,recon]*nA + 4 masked bands ----
  for (int s = 0; s < 4; s++){
    int H = Hs[s], n = H*H;
    float invn = 1.0f/((float)H*(float)H);
    int nA = (s == 0) ? 2 : 1;
    int nimg = nA + 4;
    const void* srcA = (s == 0) ? (const void*)scr4 : (const void*)lod[s];
    int simgA = (s == 0) ? n0 : 0;
    float* rT = (s == 0) ? reals0 : recon[s];
    int rimg = (s == 0) ? n0 : 0;
    double* mT = (s == 0) ? (ST + 4) : (ST + 10 + s*6);
    int mstr = (s == 0) ? 6 : 0;
    rows_pass(H, scr4, srcA, lod[s], nA, nimg, simgA, n, 0, INV, H/2, 0,
              LOP_MIX, offs[s], -(float)(s+1), stream);
    cols_pass(H, band[s], scr4, nA, nimg, n, n, INV, H/2, 0, invn,
              SOP_MIX, rT, rimg, mT, mstr, stream);
    ps_crop_lo<<<gr((H/2)*(H/2)), 256, 0, stream>>>(lod[s+1], lod[s], H, offs[s+1], -(float)(s+1));
  }
  // lowpass
  rows_pass(64, scr, lod[4], nullptr, 0, 1, 0, 0, 0, INV, 32, 0, LOP_NONE, 0, 0.f, stream);
  cols_pass(64, scr, scr, 0, 1, 0, 0, INV, 32, 0, 1.0f/4096.f, SOP_REAL, recon[4], 0,
            ST + 10 + 4*6, 0, stream);

  // ---- all 21 autocorrelations in one launch (big tasks first) ----
  {
    AcTaskTab tt{};
    int nt = 0, blk = 0;
    auto addTask = [&](const void* src, int isMag, int H, int nimgs, int stOff){
      int tiles = (H>>5)*(H>>5);
      int nb = tiles < 256 ? tiles : 256;
      tt.src[nt] = src; tt.isMag[nt] = isMag; tt.H[nt] = H; tt.npi[nt] = H*H;
      tt.nb[nt] = nb; tt.stOff[nt] = stOff; tt.stStride[nt] = 48;
      tt.blkStart[nt] = blk; blk += nb*nimgs; nt++;
    };
    addTask(band[0], 1, 1024, 4, 752 + 0*4*48);
    addTask(recon[0], 0, 1024, 1, 512 + 0*48);
    addTask(band[1], 1, 512, 4, 752 + 1*4*48);
    addTask(recon[1], 0, 512, 1, 512 + 1*48);
    addTask(band[2], 1, 256, 4, 752 + 2*4*48);
    addTask(recon[2], 0, 256, 1, 512 + 2*48);
    addTask(band[3], 1, 128, 4, 752 + 3*4*48);
    addTask(recon[3], 0, 128, 1, 512 + 3*48);
    addTask(recon[4], 0, 64, 1, 512 + 4*48);
    tt.blkStart[nt] = blk; tt.nTasks = nt;
    ps_spat_ac_multi<<<dim3(blk), 256, 0, stream>>>(tt, ST);
  }

  // ---- per-scale band Grams (one launch) ----
  {
    ScaleATab ta{};
    for (int s = 0; s < 4; s++){ ta.b[s] = band[s]; ta.n[s] = Hs[s]*Hs[s]; }
    ps_scaleA_multi<<<dim3(512, 4), 256, 0, stream>>>(ta, ST);
  }

  // ---- cross-scale: pad + band-mask lod[s+1] directly ----
  for (int s = 0; s < 3; s++){
    int H1 = Hs[s+1], H2 = Hs[s];
    int n2 = H2*H2;
    rows_pass(H2, scr4, lod[s+1], nullptr, 0, 4, 0, n2, H1, INV, H2/2, 0, LOP_PADMASK,
              offs[s+1], -(float)(s+2), stream);
    cols_pass(H2, scr4, scr4, 0, 4, n2, n2, INV, H2/2, 0, 1.0f/(float)(H1*H1),
              SOP_NONE, nullptr, 0, nullptr, 0, stream);
    ps_scaleB<<<rblocks(n2), 256, 0, stream>>>(scr4, scr4+n2, scr4+2*n2, scr4+3*n2,
                                               band[s], band[s]+n2, band[s]+2*n2, band[s]+3*n2,
                                               n2, ST + 192 + s*80);
  }
  // s=3: expand2(lowpass) = pad lod[4] directly (no mask)
  rows_pass(128, scr4, lod[4], nullptr, 0, 1, 4096, 16384, 64, INV, 64, 0, LOP_PAD, 0, 0.f, stream);
  cols_pass(128, scr4, scr4, 0, 1, 16384, 16384, INV, 64, 0, 1.0f/4096.f, SOP_REAL, lp, 0, nullptr, 0, stream);
  ps_scaleC<<<rblocks(16384), 256, 0, stream>>>(band[3], band[3]+16384, band[3]+2*16384, band[3]+3*16384,
                                                lp, 16384, ST + 432);

  // ---- finalize ----
  ps_finalize<<<gr(out_size), 256, 0, stream>>>(ST, MM, out, out_size);
}

// Round 12
// 459.362 us; speedup vs baseline: 1.8927x; 1.0466x over previous
//
#include <hip/hip_runtime.h>
#include <math.h>

#define PI_F 3.14159265358979323846f

enum { LOP_NONE=0, LOP_R2C, LOP_PAD, LOP_PADMASK, LOP_MIX };
enum { SOP_NONE=0, SOP_REAL, SOP_MIX, SOP_HL };

// ---------------------------------------------------------------------------
// helpers
// ---------------------------------------------------------------------------
__host__ __device__ constexpr int P4(int a, int b){ return a*4 - a*(a-1)/2 + (b-a); }
__host__ __device__ constexpr int P5(int a, int b){ return a*5 - a*(a-1)/2 + (b-a); }

__device__ __forceinline__ unsigned encf(float f){
  unsigned u = __float_as_uint(f);
  return (u & 0x80000000u) ? ~u : (u | 0x80000000u);
}
__device__ __forceinline__ float decf(unsigned u){
  unsigned b = (u & 0x80000000u) ? (u ^ 0x80000000u) : ~u;
  return __uint_as_float(b);
}
__device__ __forceinline__ float2 cxmul(float2 a, float c, float s){
  return make_float2(c*a.x - s*a.y, c*a.y + s*a.x);
}
__device__ __forceinline__ float2 f2add(float2 a, float2 b){ return make_float2(a.x+b.x, a.y+b.y); }
__device__ __forceinline__ float2 f2sub(float2 a, float2 b){ return make_float2(a.x-b.x, a.y-b.y); }

// wave shuffle-reduce -> LDS -> ONE atomicAdd per counter per block.
template<int CNT, int WAVES>
__device__ __forceinline__ void block_reduce_add(float (&acc)[CNT], double* out){
  __shared__ float red[WAVES*CNT];
  int lane = threadIdx.x & 63;
  int wid  = threadIdx.x >> 6;
  #pragma unroll
  for (int k = 0; k < CNT; k++){
    float v = acc[k];
    #pragma unroll
    for (int o = 32; o > 0; o >>= 1) v += __shfl_down(v, o, 64);
    if (lane == 0) red[wid*CNT + k] = v;
  }
  __syncthreads();
  int t = threadIdx.x;
  if (t < CNT){
    double s = 0.0;
    #pragma unroll
    for (int w = 0; w < WAVES; w++) s += (double)red[w*CNT + t];
    atomicAdd(&out[t], s);
  }
  __syncthreads();
}

// float polar grid (ref computes masks in f64 then casts to f32)
__device__ __forceinline__ void polar_f(int iy, int ix, float& lr, float& ang){
  float yn = (float)(iy - 512) * (1.f/512.f);
  float xn = (float)(ix - 512) * (1.f/512.f);
  ang = atan2f(yn, xn);
  float rad = (iy == 512 && ix == 512) ? (1.f/512.f) : sqrtf(xn*xn + yn*yn);
  lr = log2f(rad);
}
__device__ __forceinline__ float f_hi(float lr, float shift){
  float v = fminf(fmaxf(lr - shift, -1.f), 0.f);
  return cosf((PI_F*0.5f) * v);
}
__device__ __forceinline__ float f_lo(float lr, float shift){
  float h = f_hi(lr, shift);
  float q = fminf(fmaxf(1.f - h*h, 0.f), 1.f);
  return sqrtf(q);
}
__device__ __forceinline__ float band_am(float ang, int b){
  float a0 = ang - (PI_F*0.25f)*(float)b + PI_F;
  float a = fmodf(a0, 2.f*PI_F);
  if (a < 0.f) a += 2.f*PI_F;
  a -= PI_F;
  float mk = 0.f;
  if (fabsf(a) < PI_F*0.5f){ float c = cosf(a); mk = 1.78885438199983f*c*c*c; }
  return mk;
}

// radix-4 butterfly on v[4]; fwd: omega=-i
__device__ __forceinline__ void bfly4(float2* v, bool fwd){
  float2 A = f2add(v[0], v[2]), B = f2sub(v[0], v[2]);
  float2 C = f2add(v[1], v[3]), D = f2sub(v[1], v[3]);
  float2 dj = fwd ? make_float2(D.y, -D.x) : make_float2(-D.y, D.x);
  v[0] = f2add(A, C);
  v[1] = f2add(B, dj);
  v[2] = f2sub(A, C);
  v[3] = f2sub(B, dj);
}

// ---------------------------------------------------------------------------
// FFT rows pass: one line per block, fused load-ops.
// ---------------------------------------------------------------------------
template<int N>
__global__ __launch_bounds__((N/4 < 64) ? 64 : N/4)
void ps_fft_rows(float2* __restrict__ dst, const void* __restrict__ vsrc,
                 const void* __restrict__ vsrc2, int nA,
                 int simg, int dimg, int srcH1,
                 float dir, int xin, int xout, int lop, int moff, float mshift)
{
  constexpr int T = (N/4 < 64) ? 64 : N/4;
  __shared__ float2 sm[N];
  const int t = threadIdx.x;
  const int l = blockIdx.x & (N-1);
  const int img = blockIdx.x / N;
  float2* dline = dst + (size_t)img*(size_t)dimg + (size_t)l*N;

  if (lop == LOP_PAD || lop == LOP_PADMASK){
    const int q = N/4;
    const int sl = l - q;
    if (sl < 0 || sl >= srcH1){
      for (int j = t; j < N; j += T) dline[j] = make_float2(0.f, 0.f);
      return;
    }
    const float2* s = (const float2*)vsrc + (size_t)img*simg + (size_t)sl*srcH1;
    if (lop == LOP_PAD){
      for (int j = t; j < N; j += T){
        int p = j ^ xin;
        sm[j] = (p >= q && p < q + srcH1) ? s[p - q] : make_float2(0.f, 0.f);
      }
    } else {
      for (int j = t; j < N; j += T){
        int p = j ^ xin;
        float2 r = make_float2(0.f, 0.f);
        if (p >= q && p < q + srcH1){
          int x = p - q;
          float lr, ang; polar_f(moff + sl, moff + x, lr, ang);
          float mf = f_hi(lr, mshift) * band_am(ang, img);
          float2 v = s[x];
          r = make_float2(-mf*v.y, mf*v.x);
        }
        sm[j] = r;
      }
    }
  } else if (lop == LOP_MIX){
    if (img < nA){
      const float2* s = (const float2*)vsrc + (size_t)img*(size_t)simg + (size_t)l*N;
      for (int j = t; j < N; j += T) sm[j] = s[j ^ xin];
    } else {
      const float2* s = (const float2*)vsrc2 + (size_t)l*N;
      const int b = img - nA;
      for (int j = t; j < N; j += T){
        int x = j ^ xin;
        float lr, ang; polar_f(moff + l, moff + x, lr, ang);
        float mf = f_hi(lr, mshift) * band_am(ang, b);
        float2 v = s[x];
        sm[j] = make_float2(-mf*v.y, mf*v.x);
      }
    }
  } else if (lop == LOP_R2C){
    const float* s = (const float*)vsrc + (size_t)img*simg + (size_t)l*N;
    for (int j = t; j < N; j += T) sm[j] = make_float2(s[j ^ xin], 0.f);
  } else {
    const float2* s = (const float2*)vsrc + (size_t)img*simg + (size_t)l*N;
    for (int j = t; j < N; j += T) sm[j] = s[j ^ xin];
  }
  __syncthreads();

  const bool fwd = (dir < 0.f);
  int Ns = 1;
  if constexpr ((N & 0xAAAAAAAAu) != 0){           // odd log2: radix-2 first
    constexpr int NB2 = N/2;
    constexpr int P2 = (NB2 + T - 1)/T;
    float2 a[P2], b[P2];
    #pragma unroll
    for (int p = 0; p < P2; p++){
      int q = t + p*T;
      if (q < NB2){ a[p] = sm[q]; b[p] = sm[q + N/2]; }
    }
    __syncthreads();
    #pragma unroll
    for (int p = 0; p < P2; p++){
      int q = t + p*T;
      if (q < NB2){
        sm[2*q]   = f2add(a[p], b[p]);
        sm[2*q+1] = f2sub(a[p], b[p]);
      }
    }
    __syncthreads();
    Ns = 2;
  }
  constexpr int NB4 = N/4;
  for (; Ns < N; Ns <<= 2){
    float2 v[4];
    int q = t;
    int k = 0;
    if (q < NB4){
      k = q & (Ns - 1);
      #pragma unroll
      for (int r = 0; r < 4; r++) v[r] = sm[q + r*NB4];
      if (k){
        float ang = dir * (PI_F*0.5f) * (float)k / (float)Ns;
        float s1, c1; __sincosf(ang, &s1, &c1);
        float c2 = c1*c1 - s1*s1, s2 = 2.f*c1*s1;
        float c3 = c1*c2 - s1*s2, s3 = c1*s2 + s1*c2;
        v[1] = cxmul(v[1], c1, s1);
        v[2] = cxmul(v[2], c2, s2);
        v[3] = cxmul(v[3], c3, s3);
      }
      bfly4(v, fwd);
    }
    __syncthreads();
    if (q < NB4){
      int dd = ((q - k) << 2) + k;
      sm[dd]        = v[0];
      sm[dd + Ns]   = v[1];
      sm[dd + 2*Ns] = v[2];
      sm[dd + 3*Ns] = v[3];
    }
    __syncthreads();
  }
  for (int j = t; j < N; j += T) dline[j ^ xout] = sm[j];
}

// ---------------------------------------------------------------------------
// FFT cols pass: CB adjacent columns per block (coalesced). src/dst may alias.
// SOP_MIX: img<nA -> real store + 5-moment stats; img>=nA -> complex store.
// SOP_HL : store lo*v -> dst, hi*v -> dstB, lo*v -> dstB+dimgB (fused radial
//          masks of the imdft; kills ps_mask_hl + one scr round-trip).
// ---------------------------------------------------------------------------
template<int N, int CB>
__global__ __launch_bounds__(512)
void ps_fft_cols(float2* __restrict__ dst, const float2* __restrict__ src,
                 float2* __restrict__ dstB, int dimgB,
                 int nA, int simg, int dimg,
                 float dir, int xin, int xout, float scale,
                 int sop, float* __restrict__ rdst, int rimg,
                 double* __restrict__ mout, int mstride)
{
  constexpr int T = 512;
  constexpr int LCB = (CB==2)?1:(CB==4)?2:(CB==8)?3:4;
  constexpr int NBK = N / CB;
  constexpr int NE = N*CB;
  __shared__ float2 sm[NE];
  const int t = threadIdx.x;
  const int img = blockIdx.x / NBK;
  const int c0 = (blockIdx.x % NBK) * CB;
  const float2* sbase = src + (size_t)img*(size_t)simg + c0;

  for (int e = t; e < NE; e += T){
    int j = e >> LCB, c = e & (CB - 1);
    sm[e] = sbase[(size_t)(j ^ xin)*N + c];
  }
  __syncthreads();

  const bool fwd = (dir < 0.f);
  int Ns = 1;
  if constexpr ((N & 0xAAAAAAAAu) != 0){
    constexpr int NB2 = (N/2)*CB;
    constexpr int P2 = (NB2 + T - 1)/T;
    float2 a[P2], b[P2];
    #pragma unroll
    for (int p = 0; p < P2; p++){
      int q = t + p*T;
      if (q < NB2){
        int c = q & (CB-1), tt = q >> LCB;
        a[p] = sm[tt*CB + c];
        b[p] = sm[(tt + N/2)*CB + c];
      }
    }
    __syncthreads();
    #pragma unroll
    for (int p = 0; p < P2; p++){
      int q = t + p*T;
      if (q < NB2){
        int c = q & (CB-1), tt = q >> LCB;
        sm[(2*tt)*CB + c]   = f2add(a[p], b[p]);
        sm[(2*tt+1)*CB + c] = f2sub(a[p], b[p]);
      }
    }
    __syncthreads();
    Ns = 2;
  }
  constexpr int NB4 = (N/4)*CB;
  constexpr int PB = (NB4 + T - 1)/T;
  for (; Ns < N; Ns <<= 2){
    float2 v[PB][4];
    int kk[PB];
    #pragma unroll
    for (int p = 0; p < PB; p++){
      int q = t + p*T;
      if (q < NB4){
        int c = q & (CB-1), tt = q >> LCB;
        int k = tt & (Ns - 1);
        kk[p] = k;
        #pragma unroll
        for (int r = 0; r < 4; r++) v[p][r] = sm[(tt + r*(N/4))*CB + c];
        if (k){
          float ang = dir * (PI_F*0.5f) * (float)k / (float)Ns;
          float s1, c1; __sincosf(ang, &s1, &c1);
          float c2 = c1*c1 - s1*s1, s2 = 2.f*c1*s1;
          float c3 = c1*c2 - s1*s2, s3 = c1*s2 + s1*c2;
          v[p][1] = cxmul(v[p][1], c1, s1);
          v[p][2] = cxmul(v[p][2], c2, s2);
          v[p][3] = cxmul(v[p][3], c3, s3);
        }
        bfly4(v[p], fwd);
      }
    }
    __syncthreads();
    #pragma unroll
    for (int p = 0; p < PB; p++){
      int q = t + p*T;
      if (q < NB4){
        int c = q & (CB-1), tt = q >> LCB;
        int k = kk[p];
        int dd = ((tt - k) << 2) + k;
        sm[(dd)*CB + c]        = v[p][0];
        sm[(dd + Ns)*CB + c]   = v[p][1];
        sm[(dd + 2*Ns)*CB + c] = v[p][2];
        sm[(dd + 3*Ns)*CB + c] = v[p][3];
      }
    }
    __syncthreads();
  }

  if (sop == SOP_HL){
    for (int e = t; e < NE; e += T){
      int j = e >> LCB, c = e & (CB - 1);
      int row = j ^ xout, col = c0 + c;
      float lr, ang; polar_f(row, col, lr, ang);
      float lo = f_lo(lr, 0.f), hi = f_hi(lr, 0.f);
      float2 v = sm[j*CB + c];
      float2 lv = make_float2(v.x*lo, v.y*lo);
      size_t o = (size_t)row*N + col;
      dst[o] = lv;
      dstB[o] = make_float2(v.x*hi, v.y*hi);
      dstB[(size_t)dimgB + o] = lv;
    }
    return;
  }
  bool doReal = (sop == SOP_REAL) || (sop == SOP_MIX && img < nA);
  if (doReal){
    for (int e = t; e < NE; e += T){
      int j = e >> LCB, c = e & (CB - 1);
      rdst[(size_t)img*(size_t)rimg + (size_t)(j ^ xout)*N + c0 + c] = sm[j*CB + c].x * scale;
    }
  } else {
    int di = (sop == SOP_MIX) ? (img - nA) : img;
    float2* dbase = dst + (size_t)di*(size_t)dimg + c0;
    for (int e = t; e < NE; e += T){
      int j = e >> LCB, c = e & (CB - 1);
      float2 v = sm[j*CB + c];
      dbase[(size_t)(j ^ xout)*N + c] = make_float2(v.x*scale, v.y*scale);
    }
  }
  if (mout && doReal){
    float acc[5] = {0.f,0.f,0.f,0.f,0.f};
    for (int e = t; e < NE; e += T){
      float r = sm[e].x * scale, r2 = r*r;
      acc[0] += r; acc[1] += r2; acc[2] += r2*r; acc[3] += r2*r2; acc[4] += fabsf(r);
    }
    block_reduce_add<5, 8>(acc, mout + (size_t)img*mstride);
  }
}

// ---------------------------------------------------------------------------
// spatial circular autocorrelation, 9x9 lags, ALL 21 arrays in ONE launch.
// Round-11 lesson: nb=256 + reg-blocking REGRESSED (74us); revert to the
// round-8 proven form: 1 px/thread, flat 40-stride tile (conflict-free),
// nb=128. Keep big-task-first ordering only.
// ---------------------------------------------------------------------------
#define MAX_AC_TASKS 9
struct AcTaskTab {
  const void* src[MAX_AC_TASKS];
  int isMag[MAX_AC_TASKS];
  int H[MAX_AC_TASKS];
  int npi[MAX_AC_TASKS];
  int nb[MAX_AC_TASKS];
  int stOff[MAX_AC_TASKS];
  int stStride[MAX_AC_TASKS];
  int blkStart[MAX_AC_TASKS+1];
  int nTasks;
};

__global__ __launch_bounds__(256, 1)
void ps_spat_ac_multi(AcTaskTab tt, double* __restrict__ ST)
{
  __shared__ float tile[40*40];
  const int gb = blockIdx.x;
  int tk = 0;
  while (tk + 1 < tt.nTasks && gb >= tt.blkStart[tk+1]) tk++;
  const int lb  = gb - tt.blkStart[tk];
  const int nb  = tt.nb[tk];
  const int img = lb / nb;
  const int b0  = lb - img*nb;
  const int H = tt.H[tk];
  const int n_per_img = tt.npi[tk];
  const int isMag = tt.isMag[tk];
  const void* vsrc = tt.src[tk];
  const int t = threadIdx.x;
  const int tilesX = H >> 5;
  const int tiles = tilesX * tilesX;
  float acc[41];
  #pragma unroll
  for (int k = 0; k < 41; k++) acc[k] = 0.f;

  for (int tl = b0; tl < tiles; tl += nb){
    int by = tl / tilesX, bx = tl - by*tilesX;
    int y0 = by << 5, x0 = bx << 5;
    __syncthreads();
    for (int e = t; e < 40*40; e += 256){
      int ly = e / 40, lx = e - ly*40;
      int gy = (y0 + ly - 4) & (H - 1);
      int gx = (x0 + lx - 4) & (H - 1);
      float v;
      if (isMag){
        float2 c = ((const float2*)vsrc)[(size_t)img*n_per_img + (size_t)gy*H + gx];
        v = sqrtf(c.x*c.x + c.y*c.y);
      } else {
        v = ((const float*)vsrc)[(size_t)img*n_per_img + (size_t)gy*H + gx];
      }
      tile[e] = v;
    }
    __syncthreads();
    for (int p = t; p < 32*32; p += 256){
      int py = p >> 5, px = p & 31;
      const float* row0 = tile + (py+4)*40 + (px+4);
      float c = row0[0];
      #pragma unroll
      for (int dx = 0; dx <= 4; dx++)
        acc[dx] += c * row0[dx];
      #pragma unroll
      for (int dy = 1; dy <= 4; dy++){
        const float* rw = row0 + dy*40;
        #pragma unroll
        for (int dx = -4; dx <= 4; dx++)
          acc[5 + (dy-1)*9 + (dx+4)] += c * rw[dx];
      }
    }
  }
  block_reduce_add<41, 4>(acc, ST + tt.stOff[tk] + (size_t)img*tt.stStride[tk]);
}

// ---------------------------------------------------------------------------
// elementwise kernels
// ---------------------------------------------------------------------------
__global__ __launch_bounds__(256)
void ps_crop_lo(float2* dst, const float2* src, int Hs, int offNew, float shift){
  int Hd = Hs/2;
  int i = blockIdx.x*blockDim.x + threadIdx.x;
  if (i >= Hd*Hd) return;
  int y = i / Hd, x = i - y*Hd;
  float lr, ang; polar_f(offNew + y, offNew + x, lr, ang);
  float mk = f_lo(lr, shift);
  float2 v = src[(y + Hs/4)*Hs + (x + Hs/4)];
  dst[i] = make_float2(v.x*mk, v.y*mk);
}

// ---------------------------------------------------------------------------
// reductions
// ---------------------------------------------------------------------------
__global__ void ps_init_mm(unsigned* mm){ mm[0] = 0xFFFFFFFFu; mm[1] = 0u; }

__global__ __launch_bounds__(256, 1)
void ps_im_stats(const float4* __restrict__ x4, int n4, double* out, unsigned* mm){
  float acc[4] = {0.f,0.f,0.f,0.f};
  float mn = INFINITY, mx = -INFINITY;
  for (int i = blockIdx.x*blockDim.x + threadIdx.x; i < n4; i += gridDim.x*blockDim.x){
    float4 v = x4[i];
    float a0 = v.x, a1 = v.y, a2 = v.z, a3 = v.w;
    acc[0] += a0 + a1 + a2 + a3;
    acc[1] += a0*a0 + a1*a1 + a2*a2 + a3*a3;
    acc[2] += a0*a0*a0 + a1*a1*a1 + a2*a2*a2 + a3*a3*a3;
    acc[3] += a0*a0*a0*a0 + a1*a1*a1*a1 + a2*a2*a2*a2 + a3*a3*a3*a3;
    mn = fminf(mn, fminf(fminf(a0,a1), fminf(a2,a3)));
    mx = fmaxf(mx, fmaxf(fmaxf(a0,a1), fmaxf(a2,a3)));
  }
  block_reduce_add<4, 4>(acc, out);
  #pragma unroll
  for (int o = 32; o > 0; o >>= 1){
    mn = fminf(mn, __shfl_down(mn, o, 64));
    mx = fmaxf(mx, __shfl_down(mx, o, 64));
  }
  if ((threadIdx.x & 63) == 0){
    atomicMin(&mm[0], encf(mn));
    atomicMax(&mm[1], encf(mx));
  }
}

struct ScaleATab { const float2* b[4]; int n[4]; };
__global__ __launch_bounds__(256, 1)
void ps_scaleA_multi(ScaleATab tt, double* __restrict__ ST){
  int s = blockIdx.y;
  int n = tt.n[s];
  if ((size_t)blockIdx.x*blockDim.x >= (size_t)n) return;
  const float2* bb = tt.b[s];
  double* outp = ST + 64 + s*32;
  float acc[28];
  #pragma unroll
  for (int k = 0; k < 28; k++) acc[k] = 0.f;
  for (int i = blockIdx.x*blockDim.x + threadIdx.x; i < n; i += gridDim.x*blockDim.x){
    float2 v0 = bb[i], v1 = bb[(size_t)n + i], v2 = bb[2*(size_t)n + i], v3 = bb[3*(size_t)n + i];
    float ab[4] = { sqrtf(v0.x*v0.x+v0.y*v0.y), sqrtf(v1.x*v1.x+v1.y*v1.y),
                    sqrtf(v2.x*v2.x+v2.y*v2.y), sqrtf(v3.x*v3.x+v3.y*v3.y) };
    float re[4] = { v0.x, v1.x, v2.x, v3.x };
    #pragma unroll
    for (int a = 0; a < 4; a++){
      #pragma unroll
      for (int c = a; c < 4; c++){
        acc[P4(a,c)]      += ab[a]*ab[c];
        acc[10 + P4(a,c)] += re[a]*re[c];
      }
      acc[20 + a] += ab[a];
      acc[24 + a] += re[a];
    }
  }
  block_reduce_add<28, 4>(acc, outp);
}
__global__ __launch_bounds__(256, 1)
void ps_scaleB(const float2* __restrict__ u0, const float2* __restrict__ u1,
               const float2* __restrict__ u2, const float2* __restrict__ u3,
               const float2* __restrict__ s0, const float2* __restrict__ s1,
               const float2* __restrict__ s2, const float2* __restrict__ s3,
               int n, double* out){
  float acc[72];
  #pragma unroll
  for (int k = 0; k < 72; k++) acc[k] = 0.f;
  for (int i = blockIdx.x*blockDim.x + threadIdx.x; i < n; i += gridDim.x*blockDim.x){
    float2 u[4] = { u0[i], u1[i], u2[i], u3[i] };
    float2 bb[4] = { s0[i], s1[i], s2[i], s3[i] };
    float au[4], dre[4], dim[4], M[4], R[4];
    #pragma unroll
    for (int c = 0; c < 4; c++){
      float xx = u[c].x, yy = u[c].y;
      float mag = sqrtf(xx*xx + yy*yy);
      float den = mag + 1e-12f;
      au[c] = mag;
      dre[c] = (xx*xx - yy*yy)/den;
      dim[c] = (2.f*xx*yy)/den;
      M[c] = sqrtf(bb[c].x*bb[c].x + bb[c].y*bb[c].y);
      R[c] = bb[c].x;
    }
    #pragma unroll
    for (int c = 0; c < 4; c++){
      acc[c]      += au[c];
      acc[4 + c]  += au[c]*au[c];
      acc[24 + c] += dre[c];
      acc[28 + c] += dim[c];
      acc[32 + c] += dre[c]*dre[c];
      acc[36 + c] += dim[c]*dim[c];
    }
    #pragma unroll
    for (int a = 0; a < 4; a++)
      #pragma unroll
      for (int c = 0; c < 4; c++){
        acc[8 + a*4 + c]  += M[a]*au[c];
        acc[40 + a*4 + c] += R[a]*dre[c];
        acc[56 + a*4 + c] += R[a]*dim[c];
      }
  }
  block_reduce_add<72, 4>(acc, out);
}
__global__ __launch_bounds__(256, 1)
void ps_scaleC(const float2* __restrict__ s0, const float2* __restrict__ s1,
               const float2* __restrict__ s2, const float2* __restrict__ s3,
               const float* __restrict__ lp, int n, double* out){
  float acc[36];
  #pragma unroll
  for (int k = 0; k < 36; k++) acc[k] = 0.f;
  for (int i = blockIdx.x*blockDim.x + threadIdx.x; i < n; i += gridDim.x*blockDim.x){
    int y = i >> 7, x = i & 127;
    float L[5];
    L[0] = lp[i];
    L[1] = lp[(y << 7) | ((x + 126) & 127)];
    L[2] = lp[(y << 7) | ((x + 2) & 127)];
    L[3] = lp[(((y + 126) & 127) << 7) | x];
    L[4] = lp[(((y + 2) & 127) << 7) | x];
    float R[4] = { s0[i].x, s1[i].x, s2[i].x, s3[i].x };
    acc[0] += L[0];
    #pragma unroll
    for (int a = 0; a < 5; a++)
      #pragma unroll
      for (int c = a; c < 5; c++)
        acc[1 + P5(a,c)] += L[a]*L[c];
    #pragma unroll
    for (int a = 0; a < 4; a++)
      #pragma unroll
      for (int j = 0; j < 5; j++)
        acc[16 + a*5 + j] += R[a]*L[j];
  }
  block_reduce_add<36, 4>(acc, out);
}

// ---------------------------------------------------------------------------
// finalize — one thread per output element.
// ---------------------------------------------------------------------------
__device__ __forceinline__ double d_ns(int s){ double h = (double)(1024 >> s); return h*h; }
__device__ __forceinline__ void d_moments(const double* Mo, double n,
                                          double& sk, double& ku, double& var){
  double m = Mo[0]/n, e2 = Mo[1]/n, e3 = Mo[2]/n, e4 = Mo[3]/n;
  var = e2 - m*m;
  double c3 = e3 - 3.0*m*e2 + 2.0*m*m*m;
  double c4 = e4 - 4.0*m*e3 + 6.0*m*m*e2 - 3.0*m*m*m*m;
  sk = c3/pow(var,1.5); ku = c4/(var*var);
}
__device__ __forceinline__ int ac_o(int w, int& dy, int& dx){
  dy = w/9 - 4; dx = w - (w/9)*9 - 4;
  int ady = dy, adx = dx;
  if (dy < 0 || (dy == 0 && dx < 0)){ ady = -dy; adx = -dx; }
  return (ady == 0) ? adx : (5 + (ady-1)*9 + (adx+4));
}

__global__ __launch_bounds__(256)
void ps_finalize(const double* __restrict__ ST, const unsigned* __restrict__ MM,
                 float* __restrict__ out, int out_size){
  int idx = blockIdx.x*blockDim.x + threadIdx.x;
  if (idx >= out_size) return;
  const double n0 = 1048576.0;
  double val = 0.0;

  if (idx <= 5){
    if (idx == 4){ out[4] = decf(MM[0]); return; }
    if (idx == 5){ out[5] = decf(MM[1]); return; }
    double sk, ku, v; d_moments(ST, n0, sk, ku, v);
    val = (idx == 0) ? ST[0]/n0 : (idx == 1) ? v : (idx == 2) ? sk : ku;
  } else if (idx == 6){
    val = ST[8]/n0;
  } else if (idx <= 22){
    int i = idx - 7; int s = i >> 2, b = i & 3;
    val = ST[64 + s*32 + 20 + b] / d_ns(s);
  } else if (idx == 23){
    val = ST[10 + 4*6 + 4] / 4096.0;
  } else if (idx <= 1319){                      // band-mag ACs
    int i = idx - 24; int w = i >> 4; int j = i & 15;
    int s = j >> 2, b = j & 3;
    double n = d_ns(s);
    const double* R = ST + 752 + j*48;
    double mu = ST[64 + s*32 + 20 + b]/n, mu2 = mu*mu;
    int dy, dx; int o = ac_o(w, dy, dx);
    val = (R[o]/n - mu2) / (R[0]/n - mu2 + 1e-12);
  } else if (idx <= 1329){                      // skew_r / kurt_r
    int i = idx - 1320; bool kq = (i >= 5); int r = kq ? i - 5 : i;
    double n = (r == 4) ? 4096.0 : d_ns(r);
    double sk, ku, v; d_moments(ST + 10 + r*6, n, sk, ku, v);
    val = kq ? ku : sk;
  } else if (idx <= 1734){                      // recon ACs
    int i = idx - 1330; int w = i / 5; int r = i - w*5;
    double n = (r == 4) ? 4096.0 : d_ns(r);
    const double* R = ST + 512 + r*48;
    double mu = ST[10 + r*6]/n, mu2 = mu*mu;
    int dy, dx; int o = ac_o(w, dy, dx);
    val = (R[o]/n - mu2) / (R[0]/n - mu2 + 1e-12);
  } else if (idx <= 1739){                      // std_r
    int r = idx - 1735;
    double n = (r == 4) ? 4096.0 : d_ns(r);
    double sk, ku, v; d_moments(ST + 10 + r*6, n, sk, ku, v);
    val = sqrt(v);
  } else if (idx <= 1819){                      // com
    int i = idx - 1740; int s = i % 5; int q = i / 5; int a = q >> 2, b = q & 3;
    if (s < 4){
      double n = d_ns(s); const double* A = ST + 64 + s*32;
      double ma = A[20+a]/n, mb = A[20+b]/n;
      double caa = A[P4(a,a)]/n - ma*ma, cbb = A[P4(b,b)]/n - mb*mb;
      int lo = a < b ? a : b, hi = a < b ? b : a;
      double cab = A[P4(lo,hi)]/n - ma*mb;
      val = cab / (sqrt(caa)*sqrt(cbb) + 1e-12);
    }
  } else if (idx <= 1883){                      // csm
    int i = idx - 1820; int s = i & 3; int q = i >> 2; int a = q >> 2, c = q & 3;
    if (s < 3){
      double n = d_ns(s); const double* A = ST + 64 + s*32; const double* B = ST + 192 + s*80;
      double mM = A[20+a]/n; double sdM = sqrt(A[P4(a,a)]/n - mM*mM);
      double mU = B[c]/n;    double sdU = sqrt(B[4+c]/n - mU*mU);
      val = (B[8 + a*4 + c]/n - mM*mU) / (sdM*sdU + 1e-12);
    }
  } else if (idx <= 2203){                      // cor
    int i = idx - 1884; int s = i % 5; int q = i / 5; int a = q >> 3, b = q & 7;
    if (s < 4){
      if (a < 4 && b < 4){
        double n = d_ns(s); const double* A = ST + 64 + s*32;
        double ma = A[24+a]/n, mb = A[24+b]/n;
        double caa = A[10+P4(a,a)]/n - ma*ma, cbb = A[10+P4(b,b)]/n - mb*mb;
        int lo = a < b ? a : b, hi = a < b ? b : a;
        double cab = A[10+P4(lo,hi)]/n - ma*mb;
        val = cab / (sqrt(caa)*sqrt(cbb) + 1e-12);
      }
    } else {
      if (a < 5 && b < 5){
        const double* C = ST + 432; const double n3 = 16384.0;
        double lb = C[0]/n3;
        double caa = C[1+P5(a,a)]/n3 - lb*lb, cbb = C[1+P5(b,b)]/n3 - lb*lb;
        int lo = a < b ? a : b, hi = a < b ? b : a;
        double cab = C[1+P5(lo,hi)]/n3 - lb*lb;
        val = cab / (sqrt(caa)*sqrt(cbb) + 1e-12);
      }
    }
  } else if (idx <= 2459){                      // csr
    int i = idx - 2204; int s = i & 3; int q = i >> 2; int a = q >> 3, c = q & 7;
    if (a < 4){
      double n = d_ns(s); const double* A = ST + 64 + s*32;
      double mR = A[24+a]/n; double sdR = sqrt(A[10+P4(a,a)]/n - mR*mR);
      if (s < 3 && c < 8){
        const double* B = ST + 192 + s*80;
        if (c < 4){
          double md = B[24+c]/n; double sd = sqrt(B[32+c]/n - md*md);
          val = (B[40 + a*4 + c]/n - mR*md) / (sdR*sd + 1e-12);
        } else {
          int cc = c - 4;
          double md = B[28+cc]/n; double sd = sqrt(B[36+cc]/n - md*md);
          val = (B[56 + a*4 + cc]/n - mR*md) / (sdR*sd + 1e-12);
        }
      } else if (s == 3 && c < 5){
        const double* C = ST + 432; const double n3 = 16384.0;
        double lb = C[0]/n3;
        double sdL = sqrt(C[1+P5(c,c)]/n3 - lb*lb);
        val = (C[16 + a*5 + c]/n3 - mR*lb) / (sdR*sdL + 1e-12);
      }
    }
  } else {
    val = ST[5]/n0 - (ST[4]/n0)*(ST[4]/n0);
  }
  out[idx] = (float)val;
}

// ---------------------------------------------------------------------------
// host orchestration
// ---------------------------------------------------------------------------
static void rows_pass(int H, float2* dst, const void* src, const void* src2, int nA,
                      int nimg, int simg, int dimg, int srcH1,
                      float dir, int xin, int xout, int lop,
                      int moff, float mshift, hipStream_t st){
  dim3 g(nimg * H);
  switch (H){
    case 64:   ps_fft_rows<64>  <<<g, 64,  0, st>>>(dst, src, src2, nA, simg, dimg, srcH1, dir, xin, xout, lop, moff, mshift); break;
    case 128:  ps_fft_rows<128> <<<g, 64,  0, st>>>(dst, src, src2, nA, simg, dimg, srcH1, dir, xin, xout, lop, moff, mshift); break;
    case 256:  ps_fft_rows<256> <<<g, 64,  0, st>>>(dst, src, src2, nA, simg, dimg, srcH1, dir, xin, xout, lop, moff, mshift); break;
    case 512:  ps_fft_rows<512> <<<g, 128, 0, st>>>(dst, src, src2, nA, simg, dimg, srcH1, dir, xin, xout, lop, moff, mshift); break;
    case 1024: ps_fft_rows<1024><<<g, 256, 0, st>>>(dst, src, src2, nA, simg, dimg, srcH1, dir, xin, xout, lop, moff, mshift); break;
    default: break;
  }
}
static void cols_pass(int H, float2* dst, const float2* src, float2* dstB, int dimgB,
                      int nA, int nimg, int simg, int dimg,
                      float dir, int xin, int xout, float scale,
                      int sop, float* rdst, int rimg, double* mout, int mstride,
                      hipStream_t st){
  switch (H){
    case 64:   ps_fft_cols<64,16>  <<<dim3(nimg*(64/16)),  512, 0, st>>>(dst, src, dstB, dimgB, nA, simg, dimg, dir, xin, xout, scale, sop, rdst, rimg, mout, mstride); break;
    case 128:  ps_fft_cols<128,16> <<<dim3(nimg*(128/16)), 512, 0, st>>>(dst, src, dstB, dimgB, nA, simg, dimg, dir, xin, xout, scale, sop, rdst, rimg, mout, mstride); break;
    case 256:  ps_fft_cols<256,8>  <<<dim3(nimg*(256/8)),  512, 0, st>>>(dst, src, dstB, dimgB, nA, simg, dimg, dir, xin, xout, scale, sop, rdst, rimg, mout, mstride); break;
    case 512:  ps_fft_cols<512,8>  <<<dim3(nimg*(512/8)),  512, 0, st>>>(dst, src, dstB, dimgB, nA, simg, dimg, dir, xin, xout, scale, sop, rdst, rimg, mout, mstride); break;
    case 1024: ps_fft_cols<1024,4> <<<dim3(nimg*(1024/4)), 512, 0, st>>>(dst, src, dstB, dimgB, nA, simg, dimg, dir, xin, xout, scale, sop, rdst, rimg, mout, mstride); break;
    default: break;
  }
}

static inline dim3 gr(int n){ return dim3((n + 255)/256); }
static inline int  rblocks(int n){ int b = (n + 255)/256; return b > 512 ? 512 : b; }

#define FWD (-1.0f)
#define INV (+1.0f)

extern "C" void kernel_launch(void* const* d_in, const int* in_sizes, int n_in,
                              void* d_out, int out_size, void* d_ws, size_t ws_size,
                              hipStream_t stream){
  (void)in_sizes; (void)n_in;
  const float* im = (const float*)d_in[0];
  float* out = (float*)d_out;

  const int Hs[5]   = {1024, 512, 256, 128, 64};
  const int offs[5] = {0, 256, 384, 448, 480};

  // ---- carve workspace ----
  char* base = (char*)d_ws;
  size_t off = 0;
  auto carve = [&](size_t bytes)->void*{
    void* r = base + off;
    off = (off + bytes + 255) & ~(size_t)255;
    return r;
  };
  const int n0 = 1024*1024;
  float2* lod[5];
  for (int s = 0; s < 5; s++) lod[s] = (float2*)carve((size_t)Hs[s]*Hs[s]*sizeof(float2));
  float2* band[4];
  for (int s = 0; s < 4; s++) band[s] = (float2*)carve((size_t)4*Hs[s]*Hs[s]*sizeof(float2));
  float* reals0 = (float*)carve((size_t)2*n0*sizeof(float));  // [hp_real | recon0]
  float* recon[5];
  recon[0] = reals0 + n0;
  for (int s = 1; s < 5; s++) recon[s] = (float*)carve((size_t)Hs[s]*Hs[s]*sizeof(float));
  float* lp = (float*)carve(128*128*sizeof(float));
  float2* scr  = (float2*)carve((size_t)n0*sizeof(float2));
  float2* scr4 = (float2*)carve((size_t)6*n0*sizeof(float2));
  double* ST = (double*)carve(2048*sizeof(double));
  unsigned* MM = (unsigned*)carve(64*sizeof(unsigned));
  if (off > ws_size) return;

  // ---- init ----
  hipMemsetAsync(ST, 0, 2048*sizeof(double), stream);
  ps_init_mm<<<1, 1, 0, stream>>>(MM);
  ps_im_stats<<<256, 256, 0, stream>>>((const float4*)im, n0/4, ST + 0, MM);

  // ---- imdft (shifted); cols store fuses hi/lo masks:
  //      lod[0]=lo*V, scr4[0]=hi*V, scr4[1]=lo*V ----
  rows_pass(1024, scr, im, nullptr, 0, 1, 0, 0, 0, FWD, 0, 512, LOP_R2C, 0, 0.f, stream);
  cols_pass(1024, lod[0], scr, scr4, n0, 0, 1, 0, 0, FWD, 0, 512, 1.0f,
            SOP_HL, nullptr, 0, nullptr, 0, stream);

  // ---- pyramid scales: MIX pass = [hp,recon]*nA + 4 masked bands ----
  for (int s = 0; s < 4; s++){
    int H = Hs[s], n = H*H;
    float invn = 1.0f/((float)H*(float)H);
    int nA = (s == 0) ? 2 : 1;
    int nimg = nA + 4;
    const void* srcA = (s == 0) ? (const void*)scr4 : (const void*)lod[s];
    int simgA = (s == 0) ? n0 : 0;
    float* rT = (s == 0) ? reals0 : recon[s];
    int rimg = (s == 0) ? n0 : 0;
    double* mT = (s == 0) ? (ST + 4) : (ST + 10 + s*6);
    int mstr = (s == 0) ? 6 : 0;
    rows_pass(H, scr4, srcA, lod[s], nA, nimg, simgA, n, 0, INV, H/2, 0,
              LOP_MIX, offs[s], -(float)(s+1), stream);
    cols_pass(H, band[s], scr4, nullptr, 0, nA, nimg, n, n, INV, H/2, 0, invn,
              SOP_MIX, rT, rimg, mT, mstr, stream);
    ps_crop_lo<<<gr((H/2)*(H/2)), 256, 0, stream>>>(lod[s+1], lod[s], H, offs[s+1], -(float)(s+1));
  }
  // lowpass
  rows_pass(64, scr, lod[4], nullptr, 0, 1, 0, 0, 0, INV, 32, 0, LOP_NONE, 0, 0.f, stream);
  cols_pass(64, scr, scr, nullptr, 0, 0, 1, 0, 0, INV, 32, 0, 1.0f/4096.f,
            SOP_REAL, recon[4], 0, ST + 10 + 4*6, 0, stream);

  // ---- all 21 autocorrelations in one launch (big tasks first, nb<=128) ----
  {
    AcTaskTab tt{};
    int nt = 0, blk = 0;
    auto addTask = [&](const void* src, int isMag, int H, int nimgs, int stOff){
      int tiles = (H>>5)*(H>>5);
      int nb = tiles < 128 ? tiles : 128;
      tt.src[nt] = src; tt.isMag[nt] = isMag; tt.H[nt] = H; tt.npi[nt] = H*H;
      tt.nb[nt] = nb; tt.stOff[nt] = stOff; tt.stStride[nt] = 48;
      tt.blkStart[nt] = blk; blk += nb*nimgs; nt++;
    };
    addTask(band[0], 1, 1024, 4, 752 + 0*4*48);
    addTask(recon[0], 0, 1024, 1, 512 + 0*48);
    addTask(band[1], 1, 512, 4, 752 + 1*4*48);
    addTask(recon[1], 0, 512, 1, 512 + 1*48);
    addTask(band[2], 1, 256, 4, 752 + 2*4*48);
    addTask(recon[2], 0, 256, 1, 512 + 2*48);
    addTask(band[3], 1, 128, 4, 752 + 3*4*48);
    addTask(recon[3], 0, 128, 1, 512 + 3*48);
    addTask(recon[4], 0, 64, 1, 512 + 4*48);
    tt.blkStart[nt] = blk; tt.nTasks = nt;
    ps_spat_ac_multi<<<dim3(blk), 256, 0, stream>>>(tt, ST);
  }

  // ---- per-scale band Grams (one launch) ----
  {
    ScaleATab ta{};
    for (int s = 0; s < 4; s++){ ta.b[s] = band[s]; ta.n[s] = Hs[s]*Hs[s]; }
    ps_scaleA_multi<<<dim3(512, 4), 256, 0, stream>>>(ta, ST);
  }

  // ---- cross-scale: pad + band-mask lod[s+1] directly ----
  for (int s = 0; s < 3; s++){
    int H1 = Hs[s+1], H2 = Hs[s];
    int n2 = H2*H2;
    rows_pass(H2, scr4, lod[s+1], nullptr, 0, 4, 0, n2, H1, INV, H2/2, 0, LOP_PADMASK,
              offs[s+1], -(float)(s+2), stream);
    cols_pass(H2, scr4, scr4, nullptr, 0, 0, 4, n2, n2, INV, H2/2, 0, 1.0f/(float)(H1*H1),
              SOP_NONE, nullptr, 0, nullptr, 0, stream);
    ps_scaleB<<<rblocks(n2), 256, 0, stream>>>(scr4, scr4+n2, scr4+2*n2, scr4+3*n2,
                                               band[s], band[s]+n2, band[s]+2*n2, band[s]+3*n2,
                                               n2, ST + 192 + s*80);
  }
  // s=3: expand2(lowpass) = pad lod[4] directly (no mask)
  rows_pass(128, scr4, lod[4], nullptr, 0, 1, 4096, 16384, 64, INV, 64, 0, LOP_PAD, 0, 0.f, stream);
  cols_pass(128, scr4, scr4, nullptr, 0, 0, 1, 16384, 16384, INV, 64, 0, 1.0f/4096.f,
            SOP_REAL, lp, 0, nullptr, 0, stream);
  ps_scaleC<<<rblocks(16384), 256, 0, stream>>>(band[3], band[3]+16384, band[3]+2*16384, band[3]+3*16384,
                                                lp, 16384, ST + 432);

  // ---- finalize ----
  ps_finalize<<<gr(out_size), 256, 0, stream>>>(ST, MM, out, out_size);
}

// Round 13
// 424.241 us; speedup vs baseline: 2.0494x; 1.0828x over previous
//
#include <hip/hip_runtime.h>
#include <hip/hip_fp16.h>
#include <math.h>

#define PI_F 3.14159265358979323846f

enum { LOP_NONE=0, LOP_R2C, LOP_PAD };
enum { SOP_REAL=0, SOP_HL };

// ---------------------------------------------------------------------------
// helpers
// ---------------------------------------------------------------------------
__host__ __device__ constexpr int P4(int a, int b){ return a*4 - a*(a-1)/2 + (b-a); }
__host__ __device__ constexpr int P5(int a, int b){ return a*5 - a*(a-1)/2 + (b-a); }

__device__ __forceinline__ unsigned encf(float f){
  unsigned u = __float_as_uint(f);
  return (u & 0x80000000u) ? ~u : (u | 0x80000000u);
}
__device__ __forceinline__ float decf(unsigned u){
  unsigned b = (u & 0x80000000u) ? (u ^ 0x80000000u) : ~u;
  return __uint_as_float(b);
}
__device__ __forceinline__ float2 cxmul(float2 a, float c, float s){
  return make_float2(c*a.x - s*a.y, c*a.y + s*a.x);
}
__device__ __forceinline__ float2 f2add(float2 a, float2 b){ return make_float2(a.x+b.x, a.y+b.y); }
__device__ __forceinline__ float2 f2sub(float2 a, float2 b){ return make_float2(a.x-b.x, a.y-b.y); }
__device__ __forceinline__ float2 h2f(__half2 h){ return __half22float2(h); }
__device__ __forceinline__ __half2 f2h(float2 f){ return __float22half2_rn(f); }

// wave shuffle-reduce -> LDS -> ONE atomicAdd per counter per block.
template<int CNT, int WAVES>
__device__ __forceinline__ void block_reduce_add(float (&acc)[CNT], double* out){
  __shared__ float red[WAVES*CNT];
  int lane = threadIdx.x & 63;
  int wid  = threadIdx.x >> 6;
  #pragma unroll
  for (int k = 0; k < CNT; k++){
    float v = acc[k];
    #pragma unroll
    for (int o = 32; o > 0; o >>= 1) v += __shfl_down(v, o, 64);
    if (lane == 0) red[wid*CNT + k] = v;
  }
  __syncthreads();
  int t = threadIdx.x;
  if (t < CNT){
    double s = 0.0;
    #pragma unroll
    for (int w = 0; w < WAVES; w++) s += (double)red[w*CNT + t];
    atomicAdd(&out[t], s);
  }
  __syncthreads();
}

// float polar grid (ref computes masks in f64 then casts to f32)
__device__ __forceinline__ void polar_f(int iy, int ix, float& lr, float& ang){
  float yn = (float)(iy - 512) * (1.f/512.f);
  float xn = (float)(ix - 512) * (1.f/512.f);
  ang = atan2f(yn, xn);
  float rad = (iy == 512 && ix == 512) ? (1.f/512.f) : sqrtf(xn*xn + yn*yn);
  lr = log2f(rad);
}
__device__ __forceinline__ float f_hi(float lr, float shift){
  float v = fminf(fmaxf(lr - shift, -1.f), 0.f);
  return cosf((PI_F*0.5f) * v);
}
__device__ __forceinline__ float f_lo(float lr, float shift){
  float h = f_hi(lr, shift);
  float q = fminf(fmaxf(1.f - h*h, 0.f), 1.f);
  return sqrtf(q);
}
__device__ __forceinline__ float band_am(float ang, int b){
  float a0 = ang - (PI_F*0.25f)*(float)b + PI_F;
  float a = fmodf(a0, 2.f*PI_F);
  if (a < 0.f) a += 2.f*PI_F;
  a -= PI_F;
  float mk = 0.f;
  if (fabsf(a) < PI_F*0.5f){ float c = cosf(a); mk = 1.78885438199983f*c*c*c; }
  return mk;
}

// radix-4 butterfly on v[4]; fwd: omega=-i
__device__ __forceinline__ void bfly4(float2* v, bool fwd){
  float2 A = f2add(v[0], v[2]), B = f2sub(v[0], v[2]);
  float2 C = f2add(v[1], v[3]), D = f2sub(v[1], v[3]);
  float2 dj = fwd ? make_float2(D.y, -D.x) : make_float2(-D.y, D.x);
  v[0] = f2add(A, C);
  v[1] = f2add(B, dj);
  v[2] = f2sub(A, C);
  v[3] = f2sub(B, dj);
}

// shared radix-4 (radix-2 first if odd log2) Stockham body over sm[N]
template<int N, int T>
__device__ __forceinline__ void fft_rows_body(float2* sm, int t, float dir){
  const bool fwd = (dir < 0.f);
  int Ns = 1;
  if constexpr ((N & 0xAAAAAAAAu) != 0){
    constexpr int NB2 = N/2;
    constexpr int P2 = (NB2 + T - 1)/T;
    float2 a[P2], b[P2];
    #pragma unroll
    for (int p = 0; p < P2; p++){
      int q = t + p*T;
      if (q < NB2){ a[p] = sm[q]; b[p] = sm[q + N/2]; }
    }
    __syncthreads();
    #pragma unroll
    for (int p = 0; p < P2; p++){
      int q = t + p*T;
      if (q < NB2){
        sm[2*q]   = f2add(a[p], b[p]);
        sm[2*q+1] = f2sub(a[p], b[p]);
      }
    }
    __syncthreads();
    Ns = 2;
  }
  constexpr int NB4 = N/4;
  for (; Ns < N; Ns <<= 2){
    float2 v[4];
    int q = t, k = 0;
    if (q < NB4){
      k = q & (Ns - 1);
      #pragma unroll
      for (int r = 0; r < 4; r++) v[r] = sm[q + r*NB4];
      if (k){
        float ang = dir * (PI_F*0.5f) * (float)k / (float)Ns;
        float s1, c1; __sincosf(ang, &s1, &c1);
        float c2 = c1*c1 - s1*s1, s2 = 2.f*c1*s1;
        float c3 = c1*c2 - s1*s2, s3 = c1*s2 + s1*c2;
        v[1] = cxmul(v[1], c1, s1);
        v[2] = cxmul(v[2], c2, s2);
        v[3] = cxmul(v[3], c3, s3);
      }
      bfly4(v, fwd);
    }
    __syncthreads();
    if (q < NB4){
      int dd = ((q - k) << 2) + k;
      sm[dd]        = v[0];
      sm[dd + Ns]   = v[1];
      sm[dd + 2*Ns] = v[2];
      sm[dd + 3*Ns] = v[3];
    }
    __syncthreads();
  }
}

// ---------------------------------------------------------------------------
// simple FFT rows (f32, single image): R2C / NONE / PAD
// ---------------------------------------------------------------------------
template<int N>
__global__ __launch_bounds__((N/4 < 64) ? 64 : N/4)
void ps_fft_rows(float2* __restrict__ dst, const void* __restrict__ vsrc,
                 int srcH1, float dir, int xin, int xout, int lop)
{
  constexpr int T = (N/4 < 64) ? 64 : N/4;
  __shared__ float2 sm[N];
  const int t = threadIdx.x;
  const int l = blockIdx.x;
  float2* dline = dst + (size_t)l*N;
  if (lop == LOP_PAD){
    const int q = N/4;
    const int sl = l - q;
    if (sl < 0 || sl >= srcH1){
      for (int j = t; j < N; j += T) dline[j] = make_float2(0.f, 0.f);
      return;
    }
    const float2* s = (const float2*)vsrc + (size_t)sl*srcH1;
    for (int j = t; j < N; j += T){
      int p = j ^ xin;
      sm[j] = (p >= q && p < q + srcH1) ? s[p - q] : make_float2(0.f, 0.f);
    }
  } else if (lop == LOP_R2C){
    const float* s = (const float*)vsrc + (size_t)l*N;
    for (int j = t; j < N; j += T) sm[j] = make_float2(s[j ^ xin], 0.f);
  } else {
    const float2* s = (const float2*)vsrc + (size_t)l*N;
    for (int j = t; j < N; j += T) sm[j] = s[j ^ xin];
  }
  __syncthreads();
  fft_rows_body<N, T>(sm, t, dir);
  for (int j = t; j < N; j += T) dline[j ^ xout] = sm[j];
}

// ---------------------------------------------------------------------------
// merged pyramid rows (inverse): nA plain imgs + 4 band-masked + up to 4
// pad+masked ups. Output half2, scale applied at store (keeps half in range).
// dst slots: A -> h4[img], B -> bandD[img-nA], C -> h4[img-4].
// ---------------------------------------------------------------------------
template<int N>
__global__ __launch_bounds__((N/4 < 64) ? 64 : N/4)
void ps_fft_rows_m(__half2* __restrict__ h4, __half2* __restrict__ bandD,
                   const float2* __restrict__ lodS, const float2* __restrict__ lodS1,
                   int nA, int inAHalf, int n, int srcH1,
                   int moffB, float shiftB, int moffC, float shiftC, float scale)
{
  constexpr int T = (N/4 < 64) ? 64 : N/4;
  constexpr int XIN = N/2;
  __shared__ float2 sm[N];
  const int t = threadIdx.x;
  const int l = blockIdx.x & (N-1);
  const int img = blockIdx.x / N;
  __half2* dline;
  if (img < nA)          dline = h4 + (size_t)img*n + (size_t)l*N;
  else if (img < nA + 4) dline = bandD + (size_t)(img - nA)*n + (size_t)l*N;
  else                   dline = h4 + (size_t)(img - 4)*n + (size_t)l*N;

  if (img < nA){
    if (inAHalf){
      const __half2* s = h4 + (size_t)img*n + (size_t)l*N;
      for (int j = t; j < N; j += T) sm[j] = h2f(s[j ^ XIN]);
    } else {
      const float2* s = lodS + (size_t)l*N;
      for (int j = t; j < N; j += T) sm[j] = s[j ^ XIN];
    }
  } else if (img < nA + 4){
    const int b = img - nA;
    const float2* s = lodS + (size_t)l*N;
    for (int j = t; j < N; j += T){
      int x = j ^ XIN;
      float lr, ang; polar_f(moffB + l, moffB + x, lr, ang);
      float mf = f_hi(lr, shiftB) * band_am(ang, b);
      float2 v = s[x];
      sm[j] = make_float2(-mf*v.y, mf*v.x);
    }
  } else {
    const int b = img - nA - 4;
    const int q = N/4;
    const int sl = l - q;
    if (sl < 0 || sl >= srcH1){
      __half2 z = f2h(make_float2(0.f, 0.f));
      for (int j = t; j < N; j += T) dline[j] = z;
      return;
    }
    const float2* s = lodS1 + (size_t)sl*srcH1;
    for (int j = t; j < N; j += T){
      int p = j ^ XIN;
      float2 r = make_float2(0.f, 0.f);
      if (p >= q && p < q + srcH1){
        int x = p - q;
        float lr, ang; polar_f(moffC + sl, moffC + x, lr, ang);
        float mf = f_hi(lr, shiftC) * band_am(ang, b);
        float2 v = s[x];
        r = make_float2(-mf*v.y, mf*v.x);
      }
      sm[j] = r;
    }
  }
  __syncthreads();
  fft_rows_body<N, T>(sm, t, +1.f);
  for (int j = t; j < N; j += T){
    float2 v = sm[j];
    dline[j] = f2h(make_float2(v.x*scale, v.y*scale));
  }
}

// ---------------------------------------------------------------------------
// simple FFT cols (f32, single image): SOP_HL (imdft masks) / SOP_REAL(+stats)
// ---------------------------------------------------------------------------
template<int N, int CB>
__global__ __launch_bounds__(512)
void ps_fft_cols(float2* __restrict__ dst, const float2* __restrict__ src,
                 __half2* __restrict__ hdst, int hstride,
                 float dir, int xin, int xout, float scale,
                 int sop, float* __restrict__ rdst, double* __restrict__ mout)
{
  constexpr int T = 512;
  constexpr int LCB = (CB==2)?1:(CB==4)?2:(CB==8)?3:4;
  constexpr int NE = N*CB;
  __shared__ float2 sm[NE];
  const int t = threadIdx.x;
  const int c0 = blockIdx.x * CB;
  const float2* sbase = src + c0;

  for (int e = t; e < NE; e += T){
    int j = e >> LCB, c = e & (CB - 1);
    sm[e] = sbase[(size_t)(j ^ xin)*N + c];
  }
  __syncthreads();
  {
    const bool fwd = (dir < 0.f);
    int Ns = 1;
    if constexpr ((N & 0xAAAAAAAAu) != 0){
      constexpr int NB2 = (N/2)*CB;
      constexpr int P2 = (NB2 + T - 1)/T;
      float2 a[P2], b[P2];
      #pragma unroll
      for (int p = 0; p < P2; p++){
        int q = t + p*T;
        if (q < NB2){
          int c = q & (CB-1), tt = q >> LCB;
          a[p] = sm[tt*CB + c];
          b[p] = sm[(tt + N/2)*CB + c];
        }
      }
      __syncthreads();
      #pragma unroll
      for (int p = 0; p < P2; p++){
        int q = t + p*T;
        if (q < NB2){
          int c = q & (CB-1), tt = q >> LCB;
          sm[(2*tt)*CB + c]   = f2add(a[p], b[p]);
          sm[(2*tt+1)*CB + c] = f2sub(a[p], b[p]);
        }
      }
      __syncthreads();
      Ns = 2;
    }
    constexpr int NB4 = (N/4)*CB;
    constexpr int PB = (NB4 + T - 1)/T;
    for (; Ns < N; Ns <<= 2){
      float2 v[PB][4];
      int kk[PB];
      #pragma unroll
      for (int p = 0; p < PB; p++){
        int q = t + p*T;
        if (q < NB4){
          int c = q & (CB-1), tt = q >> LCB;
          int k = tt & (Ns - 1);
          kk[p] = k;
          #pragma unroll
          for (int r = 0; r < 4; r++) v[p][r] = sm[(tt + r*(N/4))*CB + c];
          if (k){
            float ang = dir * (PI_F*0.5f) * (float)k / (float)Ns;
            float s1, c1; __sincosf(ang, &s1, &c1);
            float c2 = c1*c1 - s1*s1, s2 = 2.f*c1*s1;
            float c3 = c1*c2 - s1*s2, s3 = c1*s2 + s1*c2;
            v[p][1] = cxmul(v[p][1], c1, s1);
            v[p][2] = cxmul(v[p][2], c2, s2);
            v[p][3] = cxmul(v[p][3], c3, s3);
          }
          bfly4(v[p], fwd);
        }
      }
      __syncthreads();
      #pragma unroll
      for (int p = 0; p < PB; p++){
        int q = t + p*T;
        if (q < NB4){
          int c = q & (CB-1), tt = q >> LCB;
          int k = kk[p];
          int dd = ((tt - k) << 2) + k;
          sm[(dd)*CB + c]        = v[p][0];
          sm[(dd + Ns)*CB + c]   = v[p][1];
          sm[(dd + 2*Ns)*CB + c] = v[p][2];
          sm[(dd + 3*Ns)*CB + c] = v[p][3];
        }
      }
      __syncthreads();
    }
  }

  if (sop == SOP_HL){
    for (int e = t; e < NE; e += T){
      int j = e >> LCB, c = e & (CB - 1);
      int row = j ^ xout, col = c0 + c;
      float lr, ang; polar_f(row, col, lr, ang);
      float lo = f_lo(lr, 0.f), hi = f_hi(lr, 0.f);
      float2 v = sm[j*CB + c];
      float2 lv = make_float2(v.x*lo, v.y*lo);
      size_t o = (size_t)row*N + col;
      dst[o] = lv;                                   // lod[0] f32
      hdst[o] = f2h(make_float2(v.x*hi, v.y*hi));    // hi*V half
      hdst[(size_t)hstride + o] = f2h(lv);           // lo*V half
    }
    return;
  }
  // SOP_REAL
  for (int e = t; e < NE; e += T){
    int j = e >> LCB, c = e & (CB - 1);
    rdst[(size_t)(j ^ xout)*N + c0 + c] = sm[j*CB + c].x * scale;
  }
  if (mout){
    float acc[5] = {0.f,0.f,0.f,0.f,0.f};
    for (int e = t; e < NE; e += T){
      float r = sm[e].x * scale, r2 = r*r;
      acc[0] += r; acc[1] += r2; acc[2] += r2*r; acc[3] += r2*r2; acc[4] += fabsf(r);
    }
    block_reduce_add<5, 8>(acc, mout);
  }
}

// ---------------------------------------------------------------------------
// merged pyramid cols (inverse, half2 in/out in-place; group A -> real+stats)
// ---------------------------------------------------------------------------
template<int N, int CB>
__global__ __launch_bounds__(512)
void ps_fft_cols_m(__half2* __restrict__ h4, __half2* __restrict__ bandD,
                   int nA, int n,
                   float* __restrict__ rdst, int rimg, int rmask,
                   double* __restrict__ mout, int mstride)
{
  constexpr int T = 512;
  constexpr int LCB = (CB==2)?1:(CB==4)?2:(CB==8)?3:4;
  constexpr int NBK = N / CB;
  constexpr int NE = N*CB;
  constexpr int XIN = N/2;
  __shared__ float2 sm[NE];
  const int t = threadIdx.x;
  const int img = blockIdx.x / NBK;
  const int c0 = (blockIdx.x % NBK) * CB;
  __half2* hbase;
  if (img < nA)          hbase = h4 + (size_t)img*n + c0;
  else if (img < nA + 4) hbase = bandD + (size_t)(img - nA)*n + c0;
  else                   hbase = h4 + (size_t)(img - 4)*n + c0;

  for (int e = t; e < NE; e += T){
    int j = e >> LCB, c = e & (CB - 1);
    sm[e] = h2f(hbase[(size_t)(j ^ XIN)*N + c]);
  }
  __syncthreads();
  {
    int Ns = 1;
    if constexpr ((N & 0xAAAAAAAAu) != 0){
      constexpr int NB2 = (N/2)*CB;
      constexpr int P2 = (NB2 + T - 1)/T;
      float2 a[P2], b[P2];
      #pragma unroll
      for (int p = 0; p < P2; p++){
        int q = t + p*T;
        if (q < NB2){
          int c = q & (CB-1), tt = q >> LCB;
          a[p] = sm[tt*CB + c];
          b[p] = sm[(tt + N/2)*CB + c];
        }
      }
      __syncthreads();
      #pragma unroll
      for (int p = 0; p < P2; p++){
        int q = t + p*T;
        if (q < NB2){
          int c = q & (CB-1), tt = q >> LCB;
          sm[(2*tt)*CB + c]   = f2add(a[p], b[p]);
          sm[(2*tt+1)*CB + c] = f2sub(a[p], b[p]);
        }
      }
      __syncthreads();
      Ns = 2;
    }
    constexpr int NB4 = (N/4)*CB;
    constexpr int PB = (NB4 + T - 1)/T;
    for (; Ns < N; Ns <<= 2){
      float2 v[PB][4];
      int kk[PB];
      #pragma unroll
      for (int p = 0; p < PB; p++){
        int q = t + p*T;
        if (q < NB4){
          int c = q & (CB-1), tt = q >> LCB;
          int k = tt & (Ns - 1);
          kk[p] = k;
          #pragma unroll
          for (int r = 0; r < 4; r++) v[p][r] = sm[(tt + r*(N/4))*CB + c];
          if (k){
            float ang = (PI_F*0.5f) * (float)k / (float)Ns;   // inverse
            float s1, c1; __sincosf(ang, &s1, &c1);
            float c2 = c1*c1 - s1*s1, s2 = 2.f*c1*s1;
            float c3 = c1*c2 - s1*s2, s3 = c1*s2 + s1*c2;
            v[p][1] = cxmul(v[p][1], c1, s1);
            v[p][2] = cxmul(v[p][2], c2, s2);
            v[p][3] = cxmul(v[p][3], c3, s3);
          }
          bfly4(v[p], false);
        }
      }
      __syncthreads();
      #pragma unroll
      for (int p = 0; p < PB; p++){
        int q = t + p*T;
        if (q < NB4){
          int c = q & (CB-1), tt = q >> LCB;
          int k = kk[p];
          int dd = ((tt - k) << 2) + k;
          sm[(dd)*CB + c]        = v[p][0];
          sm[(dd + Ns)*CB + c]   = v[p][1];
          sm[(dd + 2*Ns)*CB + c] = v[p][2];
          sm[(dd + 3*Ns)*CB + c] = v[p][3];
        }
      }
      __syncthreads();
    }
  }

  if (img < nA){
    if ((rmask >> img) & 1){
      for (int e = t; e < NE; e += T){
        int j = e >> LCB, c = e & (CB - 1);
        rdst[(size_t)img*(size_t)rimg + (size_t)j*N + c0 + c] = sm[j*CB + c].x;
      }
    }
    float acc[5] = {0.f,0.f,0.f,0.f,0.f};
    for (int e = t; e < NE; e += T){
      float r = sm[e].x, r2 = r*r;
      acc[0] += r; acc[1] += r2; acc[2] += r2*r; acc[3] += r2*r2; acc[4] += fabsf(r);
    }
    block_reduce_add<5, 8>(acc, mout + (size_t)img*mstride);
  } else {
    float mul = (img < nA + 4) ? 1.f : 4.f;     // ups carries the expand2 x4
    for (int e = t; e < NE; e += T){
      int j = e >> LCB, c = e & (CB - 1);
      float2 v = sm[j*CB + c];
      hbase[(size_t)j*N + c] = f2h(make_float2(v.x*mul, v.y*mul));
    }
  }
}

// ---------------------------------------------------------------------------
// spatial circular autocorrelation (proven round-8 form; bands now half2)
// ---------------------------------------------------------------------------
#define MAX_AC_TASKS 9
struct AcTaskTab {
  const void* src[MAX_AC_TASKS];
  int isMag[MAX_AC_TASKS];
  int H[MAX_AC_TASKS];
  int npi[MAX_AC_TASKS];
  int nb[MAX_AC_TASKS];
  int stOff[MAX_AC_TASKS];
  int stStride[MAX_AC_TASKS];
  int blkStart[MAX_AC_TASKS+1];
  int nTasks;
};

__global__ __launch_bounds__(256, 1)
void ps_spat_ac_multi(AcTaskTab tt, double* __restrict__ ST)
{
  __shared__ float tile[40*40];
  const int gb = blockIdx.x;
  int tk = 0;
  while (tk + 1 < tt.nTasks && gb >= tt.blkStart[tk+1]) tk++;
  const int lb  = gb - tt.blkStart[tk];
  const int nb  = tt.nb[tk];
  const int img = lb / nb;
  const int b0  = lb - img*nb;
  const int H = tt.H[tk];
  const int n_per_img = tt.npi[tk];
  const int isMag = tt.isMag[tk];
  const void* vsrc = tt.src[tk];
  const int t = threadIdx.x;
  const int tilesX = H >> 5;
  const int tiles = tilesX * tilesX;
  float acc[41];
  #pragma unroll
  for (int k = 0; k < 41; k++) acc[k] = 0.f;

  for (int tl = b0; tl < tiles; tl += nb){
    int by = tl / tilesX, bx = tl - by*tilesX;
    int y0 = by << 5, x0 = bx << 5;
    __syncthreads();
    for (int e = t; e < 40*40; e += 256){
      int ly = e / 40, lx = e - ly*40;
      int gy = (y0 + ly - 4) & (H - 1);
      int gx = (x0 + lx - 4) & (H - 1);
      float v;
      if (isMag){
        float2 c = h2f(((const __half2*)vsrc)[(size_t)img*n_per_img + (size_t)gy*H + gx]);
        v = sqrtf(c.x*c.x + c.y*c.y);
      } else {
        v = ((const float*)vsrc)[(size_t)img*n_per_img + (size_t)gy*H + gx];
      }
      tile[e] = v;
    }
    __syncthreads();
    for (int p = t; p < 32*32; p += 256){
      int py = p >> 5, px = p & 31;
      const float* row0 = tile + (py+4)*40 + (px+4);
      float c = row0[0];
      #pragma unroll
      for (int dx = 0; dx <= 4; dx++)
        acc[dx] += c * row0[dx];
      #pragma unroll
      for (int dy = 1; dy <= 4; dy++){
        const float* rw = row0 + dy*40;
        #pragma unroll
        for (int dx = -4; dx <= 4; dx++)
          acc[5 + (dy-1)*9 + (dx+4)] += c * rw[dx];
      }
    }
  }
  block_reduce_add<41, 4>(acc, ST + tt.stOff[tk] + (size_t)img*tt.stStride[tk]);
}

// ---------------------------------------------------------------------------
// elementwise
// ---------------------------------------------------------------------------
__global__ __launch_bounds__(256)
void ps_crop_lo(float2* dst, const float2* src, int Hs, int offNew, float shift){
  int Hd = Hs/2;
  int i = blockIdx.x*blockDim.x + threadIdx.x;
  if (i >= Hd*Hd) return;
  int y = i / Hd, x = i - y*Hd;
  float lr, ang; polar_f(offNew + y, offNew + x, lr, ang);
  float mk = f_lo(lr, shift);
  float2 v = src[(y + Hs/4)*Hs + (x + Hs/4)];
  dst[i] = make_float2(v.x*mk, v.y*mk);
}

// ---------------------------------------------------------------------------
// reductions
// ---------------------------------------------------------------------------
__global__ void ps_init_mm(unsigned* mm){ mm[0] = 0xFFFFFFFFu; mm[1] = 0u; }

__global__ __launch_bounds__(256, 1)
void ps_im_stats(const float4* __restrict__ x4, int n4, double* out, unsigned* mm){
  float acc[4] = {0.f,0.f,0.f,0.f};
  float mn = INFINITY, mx = -INFINITY;
  for (int i = blockIdx.x*blockDim.x + threadIdx.x; i < n4; i += gridDim.x*blockDim.x){
    float4 v = x4[i];
    float a0 = v.x, a1 = v.y, a2 = v.z, a3 = v.w;
    acc[0] += a0 + a1 + a2 + a3;
    acc[1] += a0*a0 + a1*a1 + a2*a2 + a3*a3;
    acc[2] += a0*a0*a0 + a1*a1*a1 + a2*a2*a2 + a3*a3*a3;
    acc[3] += a0*a0*a0*a0 + a1*a1*a1*a1 + a2*a2*a2*a2 + a3*a3*a3*a3;
    mn = fminf(mn, fminf(fminf(a0,a1), fminf(a2,a3)));
    mx = fmaxf(mx, fmaxf(fmaxf(a0,a1), fmaxf(a2,a3)));
  }
  block_reduce_add<4, 4>(acc, out);
  #pragma unroll
  for (int o = 32; o > 0; o >>= 1){
    mn = fminf(mn, __shfl_down(mn, o, 64));
    mx = fmaxf(mx, __shfl_down(mx, o, 64));
  }
  if ((threadIdx.x & 63) == 0){
    atomicMin(&mm[0], encf(mn));
    atomicMax(&mm[1], encf(mx));
  }
}

struct ScaleATab { const __half2* b[4]; int n[4]; };
__global__ __launch_bounds__(256, 1)
void ps_scaleA_multi(ScaleATab tt, double* __restrict__ ST){
  int s = blockIdx.y;
  int n = tt.n[s];
  if ((size_t)blockIdx.x*blockDim.x >= (size_t)n) return;
  const __half2* bb = tt.b[s];
  double* outp = ST + 64 + s*32;
  float acc[28];
  #pragma unroll
  for (int k = 0; k < 28; k++) acc[k] = 0.f;
  for (int i = blockIdx.x*blockDim.x + threadIdx.x; i < n; i += gridDim.x*blockDim.x){
    float2 v0 = h2f(bb[i]), v1 = h2f(bb[(size_t)n + i]),
           v2 = h2f(bb[2*(size_t)n + i]), v3 = h2f(bb[3*(size_t)n + i]);
    float ab[4] = { sqrtf(v0.x*v0.x+v0.y*v0.y), sqrtf(v1.x*v1.x+v1.y*v1.y),
                    sqrtf(v2.x*v2.x+v2.y*v2.y), sqrtf(v3.x*v3.x+v3.y*v3.y) };
    float re[4] = { v0.x, v1.x, v2.x, v3.x };
    #pragma unroll
    for (int a = 0; a < 4; a++){
      #pragma unroll
      for (int c = a; c < 4; c++){
        acc[P4(a,c)]      += ab[a]*ab[c];
        acc[10 + P4(a,c)] += re[a]*re[c];
      }
      acc[20 + a] += ab[a];
      acc[24 + a] += re[a];
    }
  }
  block_reduce_add<28, 4>(acc, outp);
}
__global__ __launch_bounds__(256, 1)
void ps_scaleB(const __half2* __restrict__ u0, const __half2* __restrict__ u1,
               const __half2* __restrict__ u2, const __half2* __restrict__ u3,
               const __half2* __restrict__ s0, const __half2* __restrict__ s1,
               const __half2* __restrict__ s2, const __half2* __restrict__ s3,
               int n, double* out){
  float acc[72];
  #pragma unroll
  for (int k = 0; k < 72; k++) acc[k] = 0.f;
  for (int i = blockIdx.x*blockDim.x + threadIdx.x; i < n; i += gridDim.x*blockDim.x){
    float2 u[4] = { h2f(u0[i]), h2f(u1[i]), h2f(u2[i]), h2f(u3[i]) };
    float2 bb[4] = { h2f(s0[i]), h2f(s1[i]), h2f(s2[i]), h2f(s3[i]) };
    float au[4], dre[4], dim[4], M[4], R[4];
    #pragma unroll
    for (int c = 0; c < 4; c++){
      float xx = u[c].x, yy = u[c].y;
      float mag = sqrtf(xx*xx + yy*yy);
      float den = mag + 1e-12f;
      au[c] = mag;
      dre[c] = (xx*xx - yy*yy)/den;
      dim[c] = (2.f*xx*yy)/den;
      M[c] = sqrtf(bb[c].x*bb[c].x + bb[c].y*bb[c].y);
      R[c] = bb[c].x;
    }
    #pragma unroll
    for (int c = 0; c < 4; c++){
      acc[c]      += au[c];
      acc[4 + c]  += au[c]*au[c];
      acc[24 + c] += dre[c];
      acc[28 + c] += dim[c];
      acc[32 + c] += dre[c]*dre[c];
      acc[36 + c] += dim[c]*dim[c];
    }
    #pragma unroll
    for (int a = 0; a < 4; a++)
      #pragma unroll
      for (int c = 0; c < 4; c++){
        acc[8 + a*4 + c]  += M[a]*au[c];
        acc[40 + a*4 + c] += R[a]*dre[c];
        acc[56 + a*4 + c] += R[a]*dim[c];
      }
  }
  block_reduce_add<72, 4>(acc, out);
}
__global__ __launch_bounds__(256, 1)
void ps_scaleC(const __half2* __restrict__ s0, const __half2* __restrict__ s1,
               const __half2* __restrict__ s2, const __half2* __restrict__ s3,
               const float* __restrict__ lp, int n, double* out){
  float acc[36];
  #pragma unroll
  for (int k = 0; k < 36; k++) acc[k] = 0.f;
  for (int i = blockIdx.x*blockDim.x + threadIdx.x; i < n; i += gridDim.x*blockDim.x){
    int y = i >> 7, x = i & 127;
    float L[5];
    L[0] = lp[i];
    L[1] = lp[(y << 7) | ((x + 126) & 127)];
    L[2] = lp[(y << 7) | ((x + 2) & 127)];
    L[3] = lp[(((y + 126) & 127) << 7) | x];
    L[4] = lp[(((y + 2) & 127) << 7) | x];
    float R[4] = { h2f(s0[i]).x, h2f(s1[i]).x, h2f(s2[i]).x, h2f(s3[i]).x };
    acc[0] += L[0];
    #pragma unroll
    for (int a = 0; a < 5; a++)
      #pragma unroll
      for (int c = a; c < 5; c++)
        acc[1 + P5(a,c)] += L[a]*L[c];
    #pragma unroll
    for (int a = 0; a < 4; a++)
      #pragma unroll
      for (int j = 0; j < 5; j++)
        acc[16 + a*5 + j] += R[a]*L[j];
  }
  block_reduce_add<36, 4>(acc, out);
}

// ---------------------------------------------------------------------------
// finalize — one thread per output element (layout unchanged)
// ---------------------------------------------------------------------------
__device__ __forceinline__ double d_ns(int s){ double h = (double)(1024 >> s); return h*h; }
__device__ __forceinline__ void d_moments(const double* Mo, double n,
                                          double& sk, double& ku, double& var){
  double m = Mo[0]/n, e2 = Mo[1]/n, e3 = Mo[2]/n, e4 = Mo[3]/n;
  var = e2 - m*m;
  double c3 = e3 - 3.0*m*e2 + 2.0*m*m*m;
  double c4 = e4 - 4.0*m*e3 + 6.0*m*m*e2 - 3.0*m*m*m*m;
  sk = c3/pow(var,1.5); ku = c4/(var*var);
}
__device__ __forceinline__ int ac_o(int w){
  int dy = w/9 - 4, dx = w - (w/9)*9 - 4;
  int ady = dy, adx = dx;
  if (dy < 0 || (dy == 0 && dx < 0)){ ady = -dy; adx = -dx; }
  return (ady == 0) ? adx : (5 + (ady-1)*9 + (adx+4));
}

__global__ __launch_bounds__(256)
void ps_finalize(const double* __restrict__ ST, const unsigned* __restrict__ MM,
                 float* __restrict__ out, int out_size){
  int idx = blockIdx.x*blockDim.x + threadIdx.x;
  if (idx >= out_size) return;
  const double n0 = 1048576.0;
  double val = 0.0;

  if (idx <= 5){
    if (idx == 4){ out[4] = decf(MM[0]); return; }
    if (idx == 5){ out[5] = decf(MM[1]); return; }
    double sk, ku, v; d_moments(ST, n0, sk, ku, v);
    val = (idx == 0) ? ST[0]/n0 : (idx == 1) ? v : (idx == 2) ? sk : ku;
  } else if (idx == 6){
    val = ST[8]/n0;
  } else if (idx <= 22){
    int i = idx - 7; int s = i >> 2, b = i & 3;
    val = ST[64 + s*32 + 20 + b] / d_ns(s);
  } else if (idx == 23){
    val = ST[10 + 4*6 + 4] / 4096.0;
  } else if (idx <= 1319){                      // band-mag ACs
    int i = idx - 24; int w = i >> 4; int j = i & 15;
    int s = j >> 2, b = j & 3;
    double n = d_ns(s);
    const double* R = ST + 752 + j*48;
    double mu = ST[64 + s*32 + 20 + b]/n, mu2 = mu*mu;
    int o = ac_o(w);
    val = (R[o]/n - mu2) / (R[0]/n - mu2 + 1e-12);
  } else if (idx <= 1329){                      // skew_r / kurt_r
    int i = idx - 1320; bool kq = (i >= 5); int r = kq ? i - 5 : i;
    double n = (r == 4) ? 4096.0 : d_ns(r);
    double sk, ku, v; d_moments(ST + 10 + r*6, n, sk, ku, v);
    val = kq ? ku : sk;
  } else if (idx <= 1734){                      // recon ACs
    int i = idx - 1330; int w = i / 5; int r = i - w*5;
    double n = (r == 4) ? 4096.0 : d_ns(r);
    const double* R = ST + 512 + r*48;
    double mu = ST[10 + r*6]/n, mu2 = mu*mu;
    int o = ac_o(w);
    val = (R[o]/n - mu2) / (R[0]/n - mu2 + 1e-12);
  } else if (idx <= 1739){                      // std_r
    int r = idx - 1735;
    double n = (r == 4) ? 4096.0 : d_ns(r);
    double sk, ku, v; d_moments(ST + 10 + r*6, n, sk, ku, v);
    val = sqrt(v);
  } else if (idx <= 1819){                      // com
    int i = idx - 1740; int s = i % 5; int q = i / 5; int a = q >> 2, b = q & 3;
    if (s < 4){
      double n = d_ns(s); const double* A = ST + 64 + s*32;
      double ma = A[20+a]/n, mb = A[20+b]/n;
      double caa = A[P4(a,a)]/n - ma*ma, cbb = A[P4(b,b)]/n - mb*mb;
      int lo = a < b ? a : b, hi = a < b ? b : a;
      double cab = A[P4(lo,hi)]/n - ma*mb;
      val = cab / (sqrt(caa)*sqrt(cbb) + 1e-12);
    }
  } else if (idx <= 1883){                      // csm
    int i = idx - 1820; int s = i & 3; int q = i >> 2; int a = q >> 2, c = q & 3;
    if (s < 3){
      double n = d_ns(s); const double* A = ST + 64 + s*32; const double* B = ST + 192 + s*80;
      double mM = A[20+a]/n; double sdM = sqrt(A[P4(a,a)]/n - mM*mM);
      double mU = B[c]/n;    double sdU = sqrt(B[4+c]/n - mU*mU);
      val = (B[8 + a*4 + c]/n - mM*mU) / (sdM*sdU + 1e-12);
    }
  } else if (idx <= 2203){                      // cor
    int i = idx - 1884; int s = i % 5; int q = i / 5; int a = q >> 3, b = q & 7;
    if (s < 4){
      if (a < 4 && b < 4){
        double n = d_ns(s); const double* A = ST + 64 + s*32;
        double ma = A[24+a]/n, mb = A[24+b]/n;
        double caa = A[10+P4(a,a)]/n - ma*ma, cbb = A[10+P4(b,b)]/n - mb*mb;
        int lo = a < b ? a : b, hi = a < b ? b : a;
        double cab = A[10+P4(lo,hi)]/n - ma*mb;
        val = cab / (sqrt(caa)*sqrt(cbb) + 1e-12);
      }
    } else {
      if (a < 5 && b < 5){
        const double* C = ST + 432; const double n3 = 16384.0;
        double lb = C[0]/n3;
        double caa = C[1+P5(a,a)]/n3 - lb*lb, cbb = C[1+P5(b,b)]/n3 - lb*lb;
        int lo = a < b ? a : b, hi = a < b ? b : a;
        double cab = C[1+P5(lo,hi)]/n3 - lb*lb;
        val = cab / (sqrt(caa)*sqrt(cbb) + 1e-12);
      }
    }
  } else if (idx <= 2459){                      // csr
    int i = idx - 2204; int s = i & 3; int q = i >> 2; int a = q >> 3, c = q & 7;
    if (a < 4){
      double n = d_ns(s); const double* A = ST + 64 + s*32;
      double mR = A[24+a]/n; double sdR = sqrt(A[10+P4(a,a)]/n - mR*mR);
      if (s < 3 && c < 8){
        const double* B = ST + 192 + s*80;
        if (c < 4){
          double md = B[24+c]/n; double sd = sqrt(B[32+c]/n - md*md);
          val = (B[40 + a*4 + c]/n - mR*md) / (sdR*sd + 1e-12);
        } else {
          int cc = c - 4;
          double md = B[28+cc]/n; double sd = sqrt(B[36+cc]/n - md*md);
          val = (B[56 + a*4 + cc]/n - mR*md) / (sdR*sd + 1e-12);
        }
      } else if (s == 3 && c < 5){
        const double* C = ST + 432; const double n3 = 16384.0;
        double lb = C[0]/n3;
        double sdL = sqrt(C[1+P5(c,c)]/n3 - lb*lb);
        val = (C[16 + a*5 + c]/n3 - mR*lb) / (sdR*sdL + 1e-12);
      }
    }
  } else {
    val = ST[5]/n0 - (ST[4]/n0)*(ST[4]/n0);
  }
  out[idx] = (float)val;
}

// ---------------------------------------------------------------------------
// host orchestration
// ---------------------------------------------------------------------------
static void rows_s(int H, float2* dst, const void* src, int srcH1,
                   float dir, int xin, int xout, int lop, hipStream_t st){
  dim3 g(H);
  switch (H){
    case 64:   ps_fft_rows<64>  <<<g, 64,  0, st>>>(dst, src, srcH1, dir, xin, xout, lop); break;
    case 128:  ps_fft_rows<128> <<<g, 64,  0, st>>>(dst, src, srcH1, dir, xin, xout, lop); break;
    case 256:  ps_fft_rows<256> <<<g, 64,  0, st>>>(dst, src, srcH1, dir, xin, xout, lop); break;
    case 512:  ps_fft_rows<512> <<<g, 128, 0, st>>>(dst, src, srcH1, dir, xin, xout, lop); break;
    case 1024: ps_fft_rows<1024><<<g, 256, 0, st>>>(dst, src, srcH1, dir, xin, xout, lop); break;
    default: break;
  }
}
static void cols_s(int H, float2* dst, const float2* src, __half2* hdst, int hstride,
                   float dir, int xin, int xout, float scale,
                   int sop, float* rdst, double* mout, hipStream_t st){
  switch (H){
    case 64:   ps_fft_cols<64,16>  <<<dim3(64/16),  512, 0, st>>>(dst, src, hdst, hstride, dir, xin, xout, scale, sop, rdst, mout); break;
    case 128:  ps_fft_cols<128,16> <<<dim3(128/16), 512, 0, st>>>(dst, src, hdst, hstride, dir, xin, xout, scale, sop, rdst, mout); break;
    case 256:  ps_fft_cols<256,8>  <<<dim3(256/8),  512, 0, st>>>(dst, src, hdst, hstride, dir, xin, xout, scale, sop, rdst, mout); break;
    case 512:  ps_fft_cols<512,8>  <<<dim3(512/8),  512, 0, st>>>(dst, src, hdst, hstride, dir, xin, xout, scale, sop, rdst, mout); break;
    case 1024: ps_fft_cols<1024,4> <<<dim3(1024/4), 512, 0, st>>>(dst, src, hdst, hstride, dir, xin, xout, scale, sop, rdst, mout); break;
    default: break;
  }
}
static void rows_m(int H, __half2* h4, __half2* bandD, const float2* lodS, const float2* lodS1,
                   int nA, int inAHalf, int nimg, int n, int srcH1,
                   int moffB, float shiftB, int moffC, float shiftC, float scale, hipStream_t st){
  dim3 g(nimg * H);
  switch (H){
    case 128:  ps_fft_rows_m<128> <<<g, 64,  0, st>>>(h4, bandD, lodS, lodS1, nA, inAHalf, n, srcH1, moffB, shiftB, moffC, shiftC, scale); break;
    case 256:  ps_fft_rows_m<256> <<<g, 64,  0, st>>>(h4, bandD, lodS, lodS1, nA, inAHalf, n, srcH1, moffB, shiftB, moffC, shiftC, scale); break;
    case 512:  ps_fft_rows_m<512> <<<g, 128, 0, st>>>(h4, bandD, lodS, lodS1, nA, inAHalf, n, srcH1, moffB, shiftB, moffC, shiftC, scale); break;
    case 1024: ps_fft_rows_m<1024><<<g, 256, 0, st>>>(h4, bandD, lodS, lodS1, nA, inAHalf, n, srcH1, moffB, shiftB, moffC, shiftC, scale); break;
    default: break;
  }
}
static void cols_m(int H, __half2* h4, __half2* bandD, int nA, int nimg, int n,
                   float* rdst, int rimg, int rmask, double* mout, int mstride, hipStream_t st){
  switch (H){
    case 128:  ps_fft_cols_m<128,16> <<<dim3(nimg*(128/16)), 512, 0, st>>>(h4, bandD, nA, n, rdst, rimg, rmask, mout, mstride); break;
    case 256:  ps_fft_cols_m<256,8>  <<<dim3(nimg*(256/8)),  512, 0, st>>>(h4, bandD, nA, n, rdst, rimg, rmask, mout, mstride); break;
    case 512:  ps_fft_cols_m<512,8>  <<<dim3(nimg*(512/8)),  512, 0, st>>>(h4, bandD, nA, n, rdst, rimg, rmask, mout, mstride); break;
    case 1024: ps_fft_cols_m<1024,4> <<<dim3(nimg*(1024/4)), 512, 0, st>>>(h4, bandD, nA, n, rdst, rimg, rmask, mout, mstride); break;
    default: break;
  }
}

static inline dim3 gr(int n){ return dim3((n + 255)/256); }
static inline int  rblocks(int n){ int b = (n + 255)/256; return b > 512 ? 512 : b; }

#define FWD (-1.0f)
#define INV (+1.0f)

extern "C" void kernel_launch(void* const* d_in, const int* in_sizes, int n_in,
                              void* d_out, int out_size, void* d_ws, size_t ws_size,
                              hipStream_t stream){
  (void)in_sizes; (void)n_in;
  const float* im = (const float*)d_in[0];
  float* out = (float*)d_out;

  const int Hs[5]   = {1024, 512, 256, 128, 64};
  const int offs[5] = {0, 256, 384, 448, 480};

  // ---- carve workspace ----
  char* base = (char*)d_ws;
  size_t off = 0;
  auto carve = [&](size_t bytes)->void*{
    void* r = base + off;
    off = (off + bytes + 255) & ~(size_t)255;
    return r;
  };
  const int n0 = 1024*1024;
  float2* lod[5];
  for (int s = 0; s < 5; s++) lod[s] = (float2*)carve((size_t)Hs[s]*Hs[s]*sizeof(float2));
  __half2* band[4];
  for (int s = 0; s < 4; s++) band[s] = (__half2*)carve((size_t)4*Hs[s]*Hs[s]*sizeof(__half2));
  float* reals0 = (float*)carve((size_t)2*n0*sizeof(float));  // [unused hp slot | recon0]
  float* recon[5];
  recon[0] = reals0 + n0;
  for (int s = 1; s < 5; s++) recon[s] = (float*)carve((size_t)Hs[s]*Hs[s]*sizeof(float));
  float* lp = (float*)carve(128*128*sizeof(float));
  float2* scrF = (float2*)carve((size_t)n0*sizeof(float2));
  __half2* h4 = (__half2*)carve((size_t)6*n0*sizeof(__half2));
  double* ST = (double*)carve(2048*sizeof(double));
  unsigned* MM = (unsigned*)carve(64*sizeof(unsigned));
  if (off > ws_size) return;

  // ---- init ----
  hipMemsetAsync(ST, 0, 2048*sizeof(double), stream);
  ps_init_mm<<<1, 1, 0, stream>>>(MM);
  ps_im_stats<<<256, 256, 0, stream>>>((const float4*)im, n0/4, ST + 0, MM);

  // ---- imdft (shifted); cols fuses radial masks:
  //      lod[0]=lo*V (f32), h4[0]=hi*V, h4[1]=lo*V (half) ----
  rows_s(1024, scrF, im, 0, FWD, 0, 512, LOP_R2C, stream);
  cols_s(1024, lod[0], scrF, h4, n0, FWD, 0, 512, 1.0f, SOP_HL, nullptr, nullptr, stream);

  // ---- pyramid scales: crop first, then ONE merged rows+cols pair:
  //      [hp?,recon] + 4 masked bands + 4 masked-padded ups (s<3) ----
  for (int s = 0; s < 4; s++){
    int H = Hs[s], n = H*H;
    float invn = 1.0f/((float)H*(float)H);
    ps_crop_lo<<<gr((H/2)*(H/2)), 256, 0, stream>>>(lod[s+1], lod[s], H, offs[s+1], -(float)(s+1));
    int nA = (s == 0) ? 2 : 1;
    int nimg = nA + 4 + ((s < 3) ? 4 : 0);
    rows_m(H, h4, band[s], lod[s], lod[s+1], nA, (s == 0) ? 1 : 0, nimg, n, Hs[s+1],
           offs[s], -(float)(s+1), offs[s+1], -(float)(s+2), invn, stream);
    float* rT = (s == 0) ? reals0 : recon[s];
    int rimg = (s == 0) ? n0 : 0;
    int rmask = (s == 0) ? 2 : 1;     // s0: skip hp real store (stats only)
    double* mT = (s == 0) ? (ST + 4) : (ST + 10 + s*6);
    int mstr = (s == 0) ? 6 : 0;
    cols_m(H, h4, band[s], nA, nimg, n, rT, rimg, rmask, mT, mstr, stream);
    if (s < 3){
      __half2* u = h4 + (size_t)nA*n;
      ps_scaleB<<<rblocks(n), 256, 0, stream>>>(u, u+n, u+2*(size_t)n, u+3*(size_t)n,
                                                band[s], band[s]+n, band[s]+2*(size_t)n, band[s]+3*(size_t)n,
                                                n, ST + 192 + s*80);
    }
  }
  // lowpass recon (f32 path)
  rows_s(64, scrF, lod[4], 0, INV, 32, 0, LOP_NONE, stream);
  cols_s(64, nullptr, scrF, nullptr, 0, INV, 32, 0, 1.0f/4096.f, SOP_REAL, recon[4], ST + 34, stream);
  // lowpass expand2 (f32 path)
  rows_s(128, scrF, lod[4], 64, INV, 64, 0, LOP_PAD, stream);
  cols_s(128, nullptr, scrF, nullptr, 0, INV, 64, 0, 1.0f/4096.f, SOP_REAL, lp, nullptr, stream);
  ps_scaleC<<<rblocks(16384), 256, 0, stream>>>(band[3], band[3]+16384, band[3]+2*16384, band[3]+3*16384,
                                                lp, 16384, ST + 432);

  // ---- all 21 autocorrelations in one launch (big tasks first, nb<=128) ----
  {
    AcTaskTab tt{};
    int nt = 0, blk = 0;
    auto addTask = [&](const void* src, int isMag, int H, int nimgs, int stOff){
      int tiles = (H>>5)*(H>>5);
      int nb = tiles < 128 ? tiles : 128;
      tt.src[nt] = src; tt.isMag[nt] = isMag; tt.H[nt] = H; tt.npi[nt] = H*H;
      tt.nb[nt] = nb; tt.stOff[nt] = stOff; tt.stStride[nt] = 48;
      tt.blkStart[nt] = blk; blk += nb*nimgs; nt++;
    };
    addTask(band[0], 1, 1024, 4, 752 + 0*4*48);
    addTask(recon[0], 0, 1024, 1, 512 + 0*48);
    addTask(band[1], 1, 512, 4, 752 + 1*4*48);
    addTask(recon[1], 0, 512, 1, 512 + 1*48);
    addTask(band[2], 1, 256, 4, 752 + 2*4*48);
    addTask(recon[2], 0, 256, 1, 512 + 2*48);
    addTask(band[3], 1, 128, 4, 752 + 3*4*48);
    addTask(recon[3], 0, 128, 1, 512 + 3*48);
    addTask(recon[4], 0, 64, 1, 512 + 4*48);
    tt.blkStart[nt] = blk; tt.nTasks = nt;
    ps_spat_ac_multi<<<dim3(blk), 256, 0, stream>>>(tt, ST);
  }

  // ---- per-scale band Grams (one launch) ----
  {
    ScaleATab ta{};
    for (int s = 0; s < 4; s++){ ta.b[s] = band[s]; ta.n[s] = Hs[s]*Hs[s]; }
    ps_scaleA_multi<<<dim3(512, 4), 256, 0, stream>>>(ta, ST);
  }

  // ---- finalize ----
  ps_finalize<<<gr(out_size), 256, 0, stream>>>(ST, MM, out, out_size);
}

// Round 14
// 391.843 us; speedup vs baseline: 2.2189x; 1.0827x over previous
//
#include <hip/hip_runtime.h>
#include <hip/hip_fp16.h>
#include <math.h>

#define PI_F 3.14159265358979323846f

enum { LOP_NONE=0, LOP_R2C, LOP_PAD };
enum { SOP_REAL=0, SOP_HL };

// ---------------------------------------------------------------------------
// helpers
// ---------------------------------------------------------------------------
__host__ __device__ constexpr int P4(int a, int b){ return a*4 - a*(a-1)/2 + (b-a); }
__host__ __device__ constexpr int P5(int a, int b){ return a*5 - a*(a-1)/2 + (b-a); }

__device__ __forceinline__ unsigned encf(float f){
  unsigned u = __float_as_uint(f);
  return (u & 0x80000000u) ? ~u : (u | 0x80000000u);
}
__device__ __forceinline__ float decf(unsigned u){
  unsigned b = (u & 0x80000000u) ? (u ^ 0x80000000u) : ~u;
  return __uint_as_float(b);
}
__device__ __forceinline__ float2 cxmul(float2 a, float c, float s){
  return make_float2(c*a.x - s*a.y, c*a.y + s*a.x);
}
__device__ __forceinline__ float2 f2add(float2 a, float2 b){ return make_float2(a.x+b.x, a.y+b.y); }
__device__ __forceinline__ float2 f2sub(float2 a, float2 b){ return make_float2(a.x-b.x, a.y-b.y); }
__device__ __forceinline__ float2 h2f(__half2 h){ return __half22float2(h); }
__device__ __forceinline__ __half2 f2h(float2 f){ return __float22half2_rn(f); }

// wave shuffle-reduce -> LDS -> ONE atomicAdd per counter per block.
template<int CNT, int WAVES>
__device__ __forceinline__ void block_reduce_add(float (&acc)[CNT], double* out){
  __shared__ float red[WAVES*CNT];
  int lane = threadIdx.x & 63;
  int wid  = threadIdx.x >> 6;
  #pragma unroll
  for (int k = 0; k < CNT; k++){
    float v = acc[k];
    #pragma unroll
    for (int o = 32; o > 0; o >>= 1) v += __shfl_down(v, o, 64);
    if (lane == 0) red[wid*CNT + k] = v;
  }
  __syncthreads();
  int t = threadIdx.x;
  if (t < CNT){
    double s = 0.0;
    #pragma unroll
    for (int w = 0; w < WAVES; w++) s += (double)red[w*CNT + t];
    atomicAdd(&out[t], s);
  }
  __syncthreads();
}

// scratch variant: reuses caller-provided LDS (cols kernels run at the 64KB
// static-LDS limit, round-13 lesson: CB width sets fetch granule efficiency).
template<int CNT, int WAVES>
__device__ __forceinline__ void block_reduce_add_sc(float (&acc)[CNT], double* out, float* red){
  __syncthreads();   // everyone done reading the buffer red aliases
  int lane = threadIdx.x & 63;
  int wid  = threadIdx.x >> 6;
  #pragma unroll
  for (int k = 0; k < CNT; k++){
    float v = acc[k];
    #pragma unroll
    for (int o = 32; o > 0; o >>= 1) v += __shfl_down(v, o, 64);
    if (lane == 0) red[wid*CNT + k] = v;
  }
  __syncthreads();
  int t = threadIdx.x;
  if (t < CNT){
    double s = 0.0;
    #pragma unroll
    for (int w = 0; w < WAVES; w++) s += (double)red[w*CNT + t];
    atomicAdd(&out[t], s);
  }
}

// float polar grid (ref computes masks in f64 then casts to f32)
__device__ __forceinline__ void polar_f(int iy, int ix, float& lr, float& ang){
  float yn = (float)(iy - 512) * (1.f/512.f);
  float xn = (float)(ix - 512) * (1.f/512.f);
  ang = atan2f(yn, xn);
  float rad = (iy == 512 && ix == 512) ? (1.f/512.f) : sqrtf(xn*xn + yn*yn);
  lr = log2f(rad);
}
__device__ __forceinline__ float f_hi(float lr, float shift){
  float v = fminf(fmaxf(lr - shift, -1.f), 0.f);
  return cosf((PI_F*0.5f) * v);
}
__device__ __forceinline__ float f_lo(float lr, float shift){
  float h = f_hi(lr, shift);
  float q = fminf(fmaxf(1.f - h*h, 0.f), 1.f);
  return sqrtf(q);
}
__device__ __forceinline__ float band_am(float ang, int b){
  float a0 = ang - (PI_F*0.25f)*(float)b + PI_F;
  float a = fmodf(a0, 2.f*PI_F);
  if (a < 0.f) a += 2.f*PI_F;
  a -= PI_F;
  float mk = 0.f;
  if (fabsf(a) < PI_F*0.5f){ float c = cosf(a); mk = 1.78885438199983f*c*c*c; }
  return mk;
}

// radix-4 butterfly on v[4]; fwd: omega=-i
__device__ __forceinline__ void bfly4(float2* v, bool fwd){
  float2 A = f2add(v[0], v[2]), B = f2sub(v[0], v[2]);
  float2 C = f2add(v[1], v[3]), D = f2sub(v[1], v[3]);
  float2 dj = fwd ? make_float2(D.y, -D.x) : make_float2(-D.y, D.x);
  v[0] = f2add(A, C);
  v[1] = f2add(B, dj);
  v[2] = f2sub(A, C);
  v[3] = f2sub(B, dj);
}

// shared radix-4 (radix-2 first if odd log2) Stockham body over sm[N]
template<int N, int T>
__device__ __forceinline__ void fft_rows_body(float2* sm, int t, float dir){
  const bool fwd = (dir < 0.f);
  int Ns = 1;
  if constexpr ((N & 0xAAAAAAAAu) != 0){
    constexpr int NB2 = N/2;
    constexpr int P2 = (NB2 + T - 1)/T;
    float2 a[P2], b[P2];
    #pragma unroll
    for (int p = 0; p < P2; p++){
      int q = t + p*T;
      if (q < NB2){ a[p] = sm[q]; b[p] = sm[q + N/2]; }
    }
    __syncthreads();
    #pragma unroll
    for (int p = 0; p < P2; p++){
      int q = t + p*T;
      if (q < NB2){
        sm[2*q]   = f2add(a[p], b[p]);
        sm[2*q+1] = f2sub(a[p], b[p]);
      }
    }
    __syncthreads();
    Ns = 2;
  }
  constexpr int NB4 = N/4;
  for (; Ns < N; Ns <<= 2){
    float2 v[4];
    int q = t, k = 0;
    if (q < NB4){
      k = q & (Ns - 1);
      #pragma unroll
      for (int r = 0; r < 4; r++) v[r] = sm[q + r*NB4];
      if (k){
        float ang = dir * (PI_F*0.5f) * (float)k / (float)Ns;
        float s1, c1; __sincosf(ang, &s1, &c1);
        float c2 = c1*c1 - s1*s1, s2 = 2.f*c1*s1;
        float c3 = c1*c2 - s1*s2, s3 = c1*s2 + s1*c2;
        v[1] = cxmul(v[1], c1, s1);
        v[2] = cxmul(v[2], c2, s2);
        v[3] = cxmul(v[3], c3, s3);
      }
      bfly4(v, fwd);
    }
    __syncthreads();
    if (q < NB4){
      int dd = ((q - k) << 2) + k;
      sm[dd]        = v[0];
      sm[dd + Ns]   = v[1];
      sm[dd + 2*Ns] = v[2];
      sm[dd + 3*Ns] = v[3];
    }
    __syncthreads();
  }
}

// cols FFT body over sm[N*CB]
template<int N, int CB, int T>
__device__ __forceinline__ void fft_cols_body(float2* sm, int t, float dir){
  constexpr int LCB = (CB==2)?1:(CB==4)?2:(CB==8)?3:4;
  const bool fwd = (dir < 0.f);
  int Ns = 1;
  if constexpr ((N & 0xAAAAAAAAu) != 0){
    constexpr int NB2 = (N/2)*CB;
    constexpr int P2 = (NB2 + T - 1)/T;
    float2 a[P2], b[P2];
    #pragma unroll
    for (int p = 0; p < P2; p++){
      int q = t + p*T;
      if (q < NB2){
        int c = q & (CB-1), tt = q >> LCB;
        a[p] = sm[tt*CB + c];
        b[p] = sm[(tt + N/2)*CB + c];
      }
    }
    __syncthreads();
    #pragma unroll
    for (int p = 0; p < P2; p++){
      int q = t + p*T;
      if (q < NB2){
        int c = q & (CB-1), tt = q >> LCB;
        sm[(2*tt)*CB + c]   = f2add(a[p], b[p]);
        sm[(2*tt+1)*CB + c] = f2sub(a[p], b[p]);
      }
    }
    __syncthreads();
    Ns = 2;
  }
  constexpr int NB4 = (N/4)*CB;
  constexpr int PB = (NB4 + T - 1)/T;
  for (; Ns < N; Ns <<= 2){
    float2 v[PB][4];
    int kk[PB];
    #pragma unroll
    for (int p = 0; p < PB; p++){
      int q = t + p*T;
      if (q < NB4){
        int c = q & (CB-1), tt = q >> LCB;
        int k = tt & (Ns - 1);
        kk[p] = k;
        #pragma unroll
        for (int r = 0; r < 4; r++) v[p][r] = sm[(tt + r*(N/4))*CB + c];
        if (k){
          float ang = dir * (PI_F*0.5f) * (float)k / (float)Ns;
          float s1, c1; __sincosf(ang, &s1, &c1);
          float c2 = c1*c1 - s1*s1, s2 = 2.f*c1*s1;
          float c3 = c1*c2 - s1*s2, s3 = c1*s2 + s1*c2;
          v[p][1] = cxmul(v[p][1], c1, s1);
          v[p][2] = cxmul(v[p][2], c2, s2);
          v[p][3] = cxmul(v[p][3], c3, s3);
        }
        bfly4(v[p], fwd);
      }
    }
    __syncthreads();
    #pragma unroll
    for (int p = 0; p < PB; p++){
      int q = t + p*T;
      if (q < NB4){
        int c = q & (CB-1), tt = q >> LCB;
        int k = kk[p];
        int dd = ((tt - k) << 2) + k;
        sm[(dd)*CB + c]        = v[p][0];
        sm[(dd + Ns)*CB + c]   = v[p][1];
        sm[(dd + 2*Ns)*CB + c] = v[p][2];
        sm[(dd + 3*Ns)*CB + c] = v[p][3];
      }
    }
    __syncthreads();
  }
}

// ---------------------------------------------------------------------------
// simple FFT rows (f32, single image): R2C / NONE / PAD
// ---------------------------------------------------------------------------
template<int N>
__global__ __launch_bounds__((N/4 < 64) ? 64 : N/4)
void ps_fft_rows(float2* __restrict__ dst, const void* __restrict__ vsrc,
                 int srcH1, float dir, int xin, int xout, int lop)
{
  constexpr int T = (N/4 < 64) ? 64 : N/4;
  __shared__ float2 sm[N];
  const int t = threadIdx.x;
  const int l = blockIdx.x;
  float2* dline = dst + (size_t)l*N;
  if (lop == LOP_PAD){
    const int q = N/4;
    const int sl = l - q;
    if (sl < 0 || sl >= srcH1){
      for (int j = t; j < N; j += T) dline[j] = make_float2(0.f, 0.f);
      return;
    }
    const float2* s = (const float2*)vsrc + (size_t)sl*srcH1;
    for (int j = t; j < N; j += T){
      int p = j ^ xin;
      sm[j] = (p >= q && p < q + srcH1) ? s[p - q] : make_float2(0.f, 0.f);
    }
  } else if (lop == LOP_R2C){
    const float* s = (const float*)vsrc + (size_t)l*N;
    for (int j = t; j < N; j += T) sm[j] = make_float2(s[j ^ xin], 0.f);
  } else {
    const float2* s = (const float2*)vsrc + (size_t)l*N;
    for (int j = t; j < N; j += T) sm[j] = s[j ^ xin];
  }
  __syncthreads();
  fft_rows_body<N, T>(sm, t, dir);
  for (int j = t; j < N; j += T) dline[j ^ xout] = sm[j];
}

// ---------------------------------------------------------------------------
// merged pyramid rows (inverse): nA plain + 4 band-masked + up to 4 padded ups.
// ---------------------------------------------------------------------------
template<int N>
__global__ __launch_bounds__((N/4 < 64) ? 64 : N/4)
void ps_fft_rows_m(__half2* __restrict__ h4, __half2* __restrict__ bandD,
                   const float2* __restrict__ lodS, const float2* __restrict__ lodS1,
                   int nA, int inAHalf, int n, int srcH1,
                   int moffB, float shiftB, int moffC, float shiftC, float scale)
{
  constexpr int T = (N/4 < 64) ? 64 : N/4;
  constexpr int XIN = N/2;
  __shared__ float2 sm[N];
  const int t = threadIdx.x;
  const int l = blockIdx.x & (N-1);
  const int img = blockIdx.x / N;
  __half2* dline;
  if (img < nA)          dline = h4 + (size_t)img*n + (size_t)l*N;
  else if (img < nA + 4) dline = bandD + (size_t)(img - nA)*n + (size_t)l*N;
  else                   dline = h4 + (size_t)(img - 4)*n + (size_t)l*N;

  if (img < nA){
    if (inAHalf){
      const __half2* s = h4 + (size_t)img*n + (size_t)l*N;
      for (int j = t; j < N; j += T) sm[j] = h2f(s[j ^ XIN]);
    } else {
      const float2* s = lodS + (size_t)l*N;
      for (int j = t; j < N; j += T) sm[j] = s[j ^ XIN];
    }
  } else if (img < nA + 4){
    const int b = img - nA;
    const float2* s = lodS + (size_t)l*N;
    for (int j = t; j < N; j += T){
      int x = j ^ XIN;
      float lr, ang; polar_f(moffB + l, moffB + x, lr, ang);
      float mf = f_hi(lr, shiftB) * band_am(ang, b);
      float2 v = s[x];
      sm[j] = make_float2(-mf*v.y, mf*v.x);
    }
  } else {
    const int b = img - nA - 4;
    const int q = N/4;
    const int sl = l - q;
    if (sl < 0 || sl >= srcH1){
      __half2 z = f2h(make_float2(0.f, 0.f));
      for (int j = t; j < N; j += T) dline[j] = z;
      return;
    }
    const float2* s = lodS1 + (size_t)sl*srcH1;
    for (int j = t; j < N; j += T){
      int p = j ^ XIN;
      float2 r = make_float2(0.f, 0.f);
      if (p >= q && p < q + srcH1){
        int x = p - q;
        float lr, ang; polar_f(moffC + sl, moffC + x, lr, ang);
        float mf = f_hi(lr, shiftC) * band_am(ang, b);
        float2 v = s[x];
        r = make_float2(-mf*v.y, mf*v.x);
      }
      sm[j] = r;
    }
  }
  __syncthreads();
  fft_rows_body<N, T>(sm, t, +1.f);
  for (int j = t; j < N; j += T){
    float2 v = sm[j];
    dline[j] = f2h(make_float2(v.x*scale, v.y*scale));
  }
}

// ---------------------------------------------------------------------------
// simple FFT cols (f32, single image): SOP_HL / SOP_REAL(+stats)
// ---------------------------------------------------------------------------
template<int N, int CB>
__global__ __launch_bounds__(512)
void ps_fft_cols(float2* __restrict__ dst, const float2* __restrict__ src,
                 __half2* __restrict__ hdst, int hstride,
                 float dir, int xin, int xout, float scale,
                 int sop, float* __restrict__ rdst, double* __restrict__ mout)
{
  constexpr int T = 512;
  constexpr int LCB = (CB==2)?1:(CB==4)?2:(CB==8)?3:4;
  constexpr int NE = N*CB;
  __shared__ float2 sm[NE];
  const int t = threadIdx.x;
  const int c0 = blockIdx.x * CB;
  const float2* sbase = src + c0;

  for (int e = t; e < NE; e += T){
    int j = e >> LCB, c = e & (CB - 1);
    sm[e] = sbase[(size_t)(j ^ xin)*N + c];
  }
  __syncthreads();
  fft_cols_body<N, CB, T>(sm, t, dir);

  if (sop == SOP_HL){
    for (int e = t; e < NE; e += T){
      int j = e >> LCB, c = e & (CB - 1);
      int row = j ^ xout, col = c0 + c;
      float lr, ang; polar_f(row, col, lr, ang);
      float lo = f_lo(lr, 0.f), hi = f_hi(lr, 0.f);
      float2 v = sm[j*CB + c];
      float2 lv = make_float2(v.x*lo, v.y*lo);
      size_t o = (size_t)row*N + col;
      dst[o] = lv;
      hdst[o] = f2h(make_float2(v.x*hi, v.y*hi));
      hdst[(size_t)hstride + o] = f2h(lv);
    }
    return;
  }
  // SOP_REAL
  for (int e = t; e < NE; e += T){
    int j = e >> LCB, c = e & (CB - 1);
    rdst[(size_t)(j ^ xout)*N + c0 + c] = sm[j*CB + c].x * scale;
  }
  if (mout){
    float acc[5] = {0.f,0.f,0.f,0.f,0.f};
    for (int e = t; e < NE; e += T){
      float r = sm[e].x * scale, r2 = r*r;
      acc[0] += r; acc[1] += r2; acc[2] += r2*r; acc[3] += r2*r2; acc[4] += fabsf(r);
    }
    block_reduce_add_sc<5, 8>(acc, mout, (float*)sm);
  }
}

// ---------------------------------------------------------------------------
// merged pyramid cols (inverse, half2 in/out in-place; group A -> real+stats)
// ---------------------------------------------------------------------------
template<int N, int CB>
__global__ __launch_bounds__(512)
void ps_fft_cols_m(__half2* __restrict__ h4, __half2* __restrict__ bandD,
                   int nA, int n,
                   float* __restrict__ rdst, int rimg, int rmask,
                   double* __restrict__ mout, int mstride)
{
  constexpr int T = 512;
  constexpr int LCB = (CB==2)?1:(CB==4)?2:(CB==8)?3:4;
  constexpr int NBK = N / CB;
  constexpr int NE = N*CB;
  constexpr int XIN = N/2;
  __shared__ float2 sm[NE];
  const int t = threadIdx.x;
  const int img = blockIdx.x / NBK;
  const int c0 = (blockIdx.x % NBK) * CB;
  __half2* hbase;
  if (img < nA)          hbase = h4 + (size_t)img*n + c0;
  else if (img < nA + 4) hbase = bandD + (size_t)(img - nA)*n + c0;
  else                   hbase = h4 + (size_t)(img - 4)*n + c0;

  for (int e = t; e < NE; e += T){
    int j = e >> LCB, c = e & (CB - 1);
    sm[e] = h2f(hbase[(size_t)(j ^ XIN)*N + c]);
  }
  __syncthreads();
  fft_cols_body<N, CB, T>(sm, t, +1.f);

  if (img < nA){
    if ((rmask >> img) & 1){
      for (int e = t; e < NE; e += T){
        int j = e >> LCB, c = e & (CB - 1);
        rdst[(size_t)img*(size_t)rimg + (size_t)j*N + c0 + c] = sm[j*CB + c].x;
      }
    }
    float acc[5] = {0.f,0.f,0.f,0.f,0.f};
    for (int e = t; e < NE; e += T){
      float r = sm[e].x, r2 = r*r;
      acc[0] += r; acc[1] += r2; acc[2] += r2*r; acc[3] += r2*r2; acc[4] += fabsf(r);
    }
    block_reduce_add_sc<5, 8>(acc, mout + (size_t)img*mstride, (float*)sm);
  } else {
    float mul = (img < nA + 4) ? 1.f : 4.f;     // ups carries the expand2 x4
    for (int e = t; e < NE; e += T){
      int j = e >> LCB, c = e & (CB - 1);
      float2 v = sm[j*CB + c];
      hbase[(size_t)j*N + c] = f2h(make_float2(v.x*mul, v.y*mul));
    }
  }
}

// ---------------------------------------------------------------------------
// spatial circular autocorrelation (proven round-8 form; bands half2)
// ---------------------------------------------------------------------------
#define MAX_AC_TASKS 9
struct AcTaskTab {
  const void* src[MAX_AC_TASKS];
  int isMag[MAX_AC_TASKS];
  int H[MAX_AC_TASKS];
  int npi[MAX_AC_TASKS];
  int nb[MAX_AC_TASKS];
  int stOff[MAX_AC_TASKS];
  int stStride[MAX_AC_TASKS];
  int blkStart[MAX_AC_TASKS+1];
  int nTasks;
};

__global__ __launch_bounds__(256, 1)
void ps_spat_ac_multi(AcTaskTab tt, double* __restrict__ ST)
{
  __shared__ float tile[40*40];
  const int gb = blockIdx.x;
  int tk = 0;
  while (tk + 1 < tt.nTasks && gb >= tt.blkStart[tk+1]) tk++;
  const int lb  = gb - tt.blkStart[tk];
  const int nb  = tt.nb[tk];
  const int img = lb / nb;
  const int b0  = lb - img*nb;
  const int H = tt.H[tk];
  const int n_per_img = tt.npi[tk];
  const int isMag = tt.isMag[tk];
  const void* vsrc = tt.src[tk];
  const int t = threadIdx.x;
  const int tilesX = H >> 5;
  const int tiles = tilesX * tilesX;
  float acc[41];
  #pragma unroll
  for (int k = 0; k < 41; k++) acc[k] = 0.f;

  for (int tl = b0; tl < tiles; tl += nb){
    int by = tl / tilesX, bx = tl - by*tilesX;
    int y0 = by << 5, x0 = bx << 5;
    __syncthreads();
    for (int e = t; e < 40*40; e += 256){
      int ly = e / 40, lx = e - ly*40;
      int gy = (y0 + ly - 4) & (H - 1);
      int gx = (x0 + lx - 4) & (H - 1);
      float v;
      if (isMag){
        float2 c = h2f(((const __half2*)vsrc)[(size_t)img*n_per_img + (size_t)gy*H + gx]);
        v = sqrtf(c.x*c.x + c.y*c.y);
      } else {
        v = ((const float*)vsrc)[(size_t)img*n_per_img + (size_t)gy*H + gx];
      }
      tile[e] = v;
    }
    __syncthreads();
    for (int p = t; p < 32*32; p += 256){
      int py = p >> 5, px = p & 31;
      const float* row0 = tile + (py+4)*40 + (px+4);
      float c = row0[0];
      #pragma unroll
      for (int dx = 0; dx <= 4; dx++)
        acc[dx] += c * row0[dx];
      #pragma unroll
      for (int dy = 1; dy <= 4; dy++){
        const float* rw = row0 + dy*40;
        #pragma unroll
        for (int dx = -4; dx <= 4; dx++)
          acc[5 + (dy-1)*9 + (dx+4)] += c * rw[dx];
      }
    }
  }
  block_reduce_add<41, 4>(acc, ST + tt.stOff[tk] + (size_t)img*tt.stStride[tk]);
}

// ---------------------------------------------------------------------------
// elementwise
// ---------------------------------------------------------------------------
__global__ __launch_bounds__(256)
void ps_crop_lo(float2* dst, const float2* src, int Hs, int offNew, float shift){
  int Hd = Hs/2;
  int i = blockIdx.x*blockDim.x + threadIdx.x;
  if (i >= Hd*Hd) return;
  int y = i / Hd, x = i - y*Hd;
  float lr, ang; polar_f(offNew + y, offNew + x, lr, ang);
  float mk = f_lo(lr, shift);
  float2 v = src[(y + Hs/4)*Hs + (x + Hs/4)];
  dst[i] = make_float2(v.x*mk, v.y*mk);
}

// ---------------------------------------------------------------------------
// reductions
// ---------------------------------------------------------------------------
__global__ void ps_init_mm(unsigned* mm){ mm[0] = 0xFFFFFFFFu; mm[1] = 0u; }

__global__ __launch_bounds__(256, 1)
void ps_im_stats(const float4* __restrict__ x4, int n4, double* out, unsigned* mm){
  float acc[4] = {0.f,0.f,0.f,0.f};
  float mn = INFINITY, mx = -INFINITY;
  for (int i = blockIdx.x*blockDim.x + threadIdx.x; i < n4; i += gridDim.x*blockDim.x){
    float4 v = x4[i];
    float a0 = v.x, a1 = v.y, a2 = v.z, a3 = v.w;
    acc[0] += a0 + a1 + a2 + a3;
    acc[1] += a0*a0 + a1*a1 + a2*a2 + a3*a3;
    acc[2] += a0*a0*a0 + a1*a1*a1 + a2*a2*a2 + a3*a3*a3;
    acc[3] += a0*a0*a0*a0 + a1*a1*a1*a1 + a2*a2*a2*a2 + a3*a3*a3*a3;
    mn = fminf(mn, fminf(fminf(a0,a1), fminf(a2,a3)));
    mx = fmaxf(mx, fmaxf(fmaxf(a0,a1), fmaxf(a2,a3)));
  }
  block_reduce_add<4, 4>(acc, out);
  #pragma unroll
  for (int o = 32; o > 0; o >>= 1){
    mn = fminf(mn, __shfl_down(mn, o, 64));
    mx = fmaxf(mx, __shfl_down(mx, o, 64));
  }
  if ((threadIdx.x & 63) == 0){
    atomicMin(&mm[0], encf(mn));
    atomicMax(&mm[1], encf(mx));
  }
}

struct ScaleATab { const __half2* b[4]; int n[4]; };
__global__ __launch_bounds__(256, 1)
void ps_scaleA_multi(ScaleATab tt, double* __restrict__ ST){
  int s = blockIdx.y;
  int n = tt.n[s];
  if ((size_t)blockIdx.x*blockDim.x >= (size_t)n) return;
  const __half2* bb = tt.b[s];
  double* outp = ST + 64 + s*32;
  float acc[28];
  #pragma unroll
  for (int k = 0; k < 28; k++) acc[k] = 0.f;
  for (int i = blockIdx.x*blockDim.x + threadIdx.x; i < n; i += gridDim.x*blockDim.x){
    float2 v0 = h2f(bb[i]), v1 = h2f(bb[(size_t)n + i]),
           v2 = h2f(bb[2*(size_t)n + i]), v3 = h2f(bb[3*(size_t)n + i]);
    float ab[4] = { sqrtf(v0.x*v0.x+v0.y*v0.y), sqrtf(v1.x*v1.x+v1.y*v1.y),
                    sqrtf(v2.x*v2.x+v2.y*v2.y), sqrtf(v3.x*v3.x+v3.y*v3.y) };
    float re[4] = { v0.x, v1.x, v2.x, v3.x };
    #pragma unroll
    for (int a = 0; a < 4; a++){
      #pragma unroll
      for (int c = a; c < 4; c++){
        acc[P4(a,c)]      += ab[a]*ab[c];
        acc[10 + P4(a,c)] += re[a]*re[c];
      }
      acc[20 + a] += ab[a];
      acc[24 + a] += re[a];
    }
  }
  block_reduce_add<28, 4>(acc, outp);
}
__global__ __launch_bounds__(256, 1)
void ps_scaleB(const __half2* __restrict__ u0, const __half2* __restrict__ u1,
               const __half2* __restrict__ u2, const __half2* __restrict__ u3,
               const __half2* __restrict__ s0, const __half2* __restrict__ s1,
               const __half2* __restrict__ s2, const __half2* __restrict__ s3,
               int n, double* out){
  float acc[72];
  #pragma unroll
  for (int k = 0; k < 72; k++) acc[k] = 0.f;
  for (int i = blockIdx.x*blockDim.x + threadIdx.x; i < n; i += gridDim.x*blockDim.x){
    float2 u[4] = { h2f(u0[i]), h2f(u1[i]), h2f(u2[i]), h2f(u3[i]) };
    float2 bb[4] = { h2f(s0[i]), h2f(s1[i]), h2f(s2[i]), h2f(s3[i]) };
    float au[4], dre[4], dim[4], M[4], R[4];
    #pragma unroll
    for (int c = 0; c < 4; c++){
      float xx = u[c].x, yy = u[c].y;
      float mag = sqrtf(xx*xx + yy*yy);
      float den = mag + 1e-12f;
      au[c] = mag;
      dre[c] = (xx*xx - yy*yy)/den;
      dim[c] = (2.f*xx*yy)/den;
      M[c] = sqrtf(bb[c].x*bb[c].x + bb[c].y*bb[c].y);
      R[c] = bb[c].x;
    }
    #pragma unroll
    for (int c = 0; c < 4; c++){
      acc[c]      += au[c];
      acc[4 + c]  += au[c]*au[c];
      acc[24 + c] += dre[c];
      acc[28 + c] += dim[c];
      acc[32 + c] += dre[c]*dre[c];
      acc[36 + c] += dim[c]*dim[c];
    }
    #pragma unroll
    for (int a = 0; a < 4; a++)
      #pragma unroll
      for (int c = 0; c < 4; c++){
        acc[8 + a*4 + c]  += M[a]*au[c];
        acc[40 + a*4 + c] += R[a]*dre[c];
        acc[56 + a*4 + c] += R[a]*dim[c];
      }
  }
  block_reduce_add<72, 4>(acc, out);
}
__global__ __launch_bounds__(256, 1)
void ps_scaleC(const __half2* __restrict__ s0, const __half2* __restrict__ s1,
               const __half2* __restrict__ s2, const __half2* __restrict__ s3,
               const float* __restrict__ lp, int n, double* out){
  float acc[36];
  #pragma unroll
  for (int k = 0; k < 36; k++) acc[k] = 0.f;
  for (int i = blockIdx.x*blockDim.x + threadIdx.x; i < n; i += gridDim.x*blockDim.x){
    int y = i >> 7, x = i & 127;
    float L[5];
    L[0] = lp[i];
    L[1] = lp[(y << 7) | ((x + 126) & 127)];
    L[2] = lp[(y << 7) | ((x + 2) & 127)];
    L[3] = lp[(((y + 126) & 127) << 7) | x];
    L[4] = lp[(((y + 2) & 127) << 7) | x];
    float R[4] = { h2f(s0[i]).x, h2f(s1[i]).x, h2f(s2[i]).x, h2f(s3[i]).x };
    acc[0] += L[0];
    #pragma unroll
    for (int a = 0; a < 5; a++)
      #pragma unroll
      for (int c = a; c < 5; c++)
        acc[1 + P5(a,c)] += L[a]*L[c];
    #pragma unroll
    for (int a = 0; a < 4; a++)
      #pragma unroll
      for (int j = 0; j < 5; j++)
        acc[16 + a*5 + j] += R[a]*L[j];
  }
  block_reduce_add<36, 4>(acc, out);
}

// ---------------------------------------------------------------------------
// finalize — one thread per output element (layout unchanged)
// ---------------------------------------------------------------------------
__device__ __forceinline__ double d_ns(int s){ double h = (double)(1024 >> s); return h*h; }
__device__ __forceinline__ void d_moments(const double* Mo, double n,
                                          double& sk, double& ku, double& var){
  double m = Mo[0]/n, e2 = Mo[1]/n, e3 = Mo[2]/n, e4 = Mo[3]/n;
  var = e2 - m*m;
  double c3 = e3 - 3.0*m*e2 + 2.0*m*m*m;
  double c4 = e4 - 4.0*m*e3 + 6.0*m*m*e2 - 3.0*m*m*m*m;
  sk = c3/pow(var,1.5); ku = c4/(var*var);
}
__device__ __forceinline__ int ac_o(int w){
  int dy = w/9 - 4, dx = w - (w/9)*9 - 4;
  int ady = dy, adx = dx;
  if (dy < 0 || (dy == 0 && dx < 0)){ ady = -dy; adx = -dx; }
  return (ady == 0) ? adx : (5 + (ady-1)*9 + (adx+4));
}

__global__ __launch_bounds__(256)
void ps_finalize(const double* __restrict__ ST, const unsigned* __restrict__ MM,
                 float* __restrict__ out, int out_size){
  int idx = blockIdx.x*blockDim.x + threadIdx.x;
  if (idx >= out_size) return;
  const double n0 = 1048576.0;
  double val = 0.0;

  if (idx <= 5){
    if (idx == 4){ out[4] = decf(MM[0]); return; }
    if (idx == 5){ out[5] = decf(MM[1]); return; }
    double sk, ku, v; d_moments(ST, n0, sk, ku, v);
    val = (idx == 0) ? ST[0]/n0 : (idx == 1) ? v : (idx == 2) ? sk : ku;
  } else if (idx == 6){
    val = ST[8]/n0;
  } else if (idx <= 22){
    int i = idx - 7; int s = i >> 2, b = i & 3;
    val = ST[64 + s*32 + 20 + b] / d_ns(s);
  } else if (idx == 23){
    val = ST[10 + 4*6 + 4] / 4096.0;
  } else if (idx <= 1319){                      // band-mag ACs
    int i = idx - 24; int w = i >> 4; int j = i & 15;
    int s = j >> 2, b = j & 3;
    double n = d_ns(s);
    const double* R = ST + 752 + j*48;
    double mu = ST[64 + s*32 + 20 + b]/n, mu2 = mu*mu;
    int o = ac_o(w);
    val = (R[o]/n - mu2) / (R[0]/n - mu2 + 1e-12);
  } else if (idx <= 1329){                      // skew_r / kurt_r
    int i = idx - 1320; bool kq = (i >= 5); int r = kq ? i - 5 : i;
    double n = (r == 4) ? 4096.0 : d_ns(r);
    double sk, ku, v; d_moments(ST + 10 + r*6, n, sk, ku, v);
    val = kq ? ku : sk;
  } else if (idx <= 1734){                      // recon ACs
    int i = idx - 1330; int w = i / 5; int r = i - w*5;
    double n = (r == 4) ? 4096.0 : d_ns(r);
    const double* R = ST + 512 + r*48;
    double mu = ST[10 + r*6]/n, mu2 = mu*mu;
    int o = ac_o(w);
    val = (R[o]/n - mu2) / (R[0]/n - mu2 + 1e-12);
  } else if (idx <= 1739){                      // std_r
    int r = idx - 1735;
    double n = (r == 4) ? 4096.0 : d_ns(r);
    double sk, ku, v; d_moments(ST + 10 + r*6, n, sk, ku, v);
    val = sqrt(v);
  } else if (idx <= 1819){                      // com
    int i = idx - 1740; int s = i % 5; int q = i / 5; int a = q >> 2, b = q & 3;
    if (s < 4){
      double n = d_ns(s); const double* A = ST + 64 + s*32;
      double ma = A[20+a]/n, mb = A[20+b]/n;
      double caa = A[P4(a,a)]/n - ma*ma, cbb = A[P4(b,b)]/n - mb*mb;
      int lo = a < b ? a : b, hi = a < b ? b : a;
      double cab = A[P4(lo,hi)]/n - ma*mb;
      val = cab / (sqrt(caa)*sqrt(cbb) + 1e-12);
    }
  } else if (idx <= 1883){                      // csm
    int i = idx - 1820; int s = i & 3; int q = i >> 2; int a = q >> 2, c = q & 3;
    if (s < 3){
      double n = d_ns(s); const double* A = ST + 64 + s*32; const double* B = ST + 192 + s*80;
      double mM = A[20+a]/n; double sdM = sqrt(A[P4(a,a)]/n - mM*mM);
      double mU = B[c]/n;    double sdU = sqrt(B[4+c]/n - mU*mU);
      val = (B[8 + a*4 + c]/n - mM*mU) / (sdM*sdU + 1e-12);
    }
  } else if (idx <= 2203){                      // cor
    int i = idx - 1884; int s = i % 5; int q = i / 5; int a = q >> 3, b = q & 7;
    if (s < 4){
      if (a < 4 && b < 4){
        double n = d_ns(s); const double* A = ST + 64 + s*32;
        double ma = A[24+a]/n, mb = A[24+b]/n;
        double caa = A[10+P4(a,a)]/n - ma*ma, cbb = A[10+P4(b,b)]/n - mb*mb;
        int lo = a < b ? a : b, hi = a < b ? b : a;
        double cab = A[10+P4(lo,hi)]/n - ma*mb;
        val = cab / (sqrt(caa)*sqrt(cbb) + 1e-12);
      }
    } else {
      if (a < 5 && b < 5){
        const double* C = ST + 432; const double n3 = 16384.0;
        double lb = C[0]/n3;
        double caa = C[1+P5(a,a)]/n3 - lb*lb, cbb = C[1+P5(b,b)]/n3 - lb*lb;
        int lo = a < b ? a : b, hi = a < b ? b : a;
        double cab = C[1+P5(lo,hi)]/n3 - lb*lb;
        val = cab / (sqrt(caa)*sqrt(cbb) + 1e-12);
      }
    }
  } else if (idx <= 2459){                      // csr
    int i = idx - 2204; int s = i & 3; int q = i >> 2; int a = q >> 3, c = q & 7;
    if (a < 4){
      double n = d_ns(s); const double* A = ST + 64 + s*32;
      double mR = A[24+a]/n; double sdR = sqrt(A[10+P4(a,a)]/n - mR*mR);
      if (s < 3 && c < 8){
        const double* B = ST + 192 + s*80;
        if (c < 4){
          double md = B[24+c]/n; double sd = sqrt(B[32+c]/n - md*md);
          val = (B[40 + a*4 + c]/n - mR*md) / (sdR*sd + 1e-12);
        } else {
          int cc = c - 4;
          double md = B[28+cc]/n; double sd = sqrt(B[36+cc]/n - md*md);
          val = (B[56 + a*4 + cc]/n - mR*md) / (sdR*sd + 1e-12);
        }
      } else if (s == 3 && c < 5){
        const double* C = ST + 432; const double n3 = 16384.0;
        double lb = C[0]/n3;
        double sdL = sqrt(C[1+P5(c,c)]/n3 - lb*lb);
        val = (C[16 + a*5 + c]/n3 - mR*lb) / (sdR*sdL + 1e-12);
      }
    }
  } else {
    val = ST[5]/n0 - (ST[4]/n0)*(ST[4]/n0);
  }
  out[idx] = (float)val;
}

// ---------------------------------------------------------------------------
// host orchestration
// ---------------------------------------------------------------------------
static void rows_s(int H, float2* dst, const void* src, int srcH1,
                   float dir, int xin, int xout, int lop, hipStream_t st){
  dim3 g(H);
  switch (H){
    case 64:   ps_fft_rows<64>  <<<g, 64,  0, st>>>(dst, src, srcH1, dir, xin, xout, lop); break;
    case 128:  ps_fft_rows<128> <<<g, 64,  0, st>>>(dst, src, srcH1, dir, xin, xout, lop); break;
    case 256:  ps_fft_rows<256> <<<g, 64,  0, st>>>(dst, src, srcH1, dir, xin, xout, lop); break;
    case 512:  ps_fft_rows<512> <<<g, 128, 0, st>>>(dst, src, srcH1, dir, xin, xout, lop); break;
    case 1024: ps_fft_rows<1024><<<g, 256, 0, st>>>(dst, src, srcH1, dir, xin, xout, lop); break;
    default: break;
  }
}
static void cols_s(int H, float2* dst, const float2* src, __half2* hdst, int hstride,
                   float dir, int xin, int xout, float scale,
                   int sop, float* rdst, double* mout, hipStream_t st){
  switch (H){
    case 64:   ps_fft_cols<64,16>  <<<dim3(64/16),  512, 0, st>>>(dst, src, hdst, hstride, dir, xin, xout, scale, sop, rdst, mout); break;
    case 128:  ps_fft_cols<128,16> <<<dim3(128/16), 512, 0, st>>>(dst, src, hdst, hstride, dir, xin, xout, scale, sop, rdst, mout); break;
    case 256:  ps_fft_cols<256,16> <<<dim3(256/16), 512, 0, st>>>(dst, src, hdst, hstride, dir, xin, xout, scale, sop, rdst, mout); break;
    case 512:  ps_fft_cols<512,16> <<<dim3(512/16), 512, 0, st>>>(dst, src, hdst, hstride, dir, xin, xout, scale, sop, rdst, mout); break;
    case 1024: ps_fft_cols<1024,8> <<<dim3(1024/8), 512, 0, st>>>(dst, src, hdst, hstride, dir, xin, xout, scale, sop, rdst, mout); break;
    default: break;
  }
}
static void rows_m(int H, __half2* h4, __half2* bandD, const float2* lodS, const float2* lodS1,
                   int nA, int inAHalf, int nimg, int n, int srcH1,
                   int moffB, float shiftB, int moffC, float shiftC, float scale, hipStream_t st){
  dim3 g(nimg * H);
  switch (H){
    case 128:  ps_fft_rows_m<128> <<<g, 64,  0, st>>>(h4, bandD, lodS, lodS1, nA, inAHalf, n, srcH1, moffB, shiftB, moffC, shiftC, scale); break;
    case 256:  ps_fft_rows_m<256> <<<g, 64,  0, st>>>(h4, bandD, lodS, lodS1, nA, inAHalf, n, srcH1, moffB, shiftB, moffC, shiftC, scale); break;
    case 512:  ps_fft_rows_m<512> <<<g, 128, 0, st>>>(h4, bandD, lodS, lodS1, nA, inAHalf, n, srcH1, moffB, shiftB, moffC, shiftC, scale); break;
    case 1024: ps_fft_rows_m<1024><<<g, 256, 0, st>>>(h4, bandD, lodS, lodS1, nA, inAHalf, n, srcH1, moffB, shiftB, moffC, shiftC, scale); break;
    default: break;
  }
}
static void cols_m(int H, __half2* h4, __half2* bandD, int nA, int nimg, int n,
                   float* rdst, int rimg, int rmask, double* mout, int mstride, hipStream_t st){
  switch (H){
    case 128:  ps_fft_cols_m<128,16> <<<dim3(nimg*(128/16)), 512, 0, st>>>(h4, bandD, nA, n, rdst, rimg, rmask, mout, mstride); break;
    case 256:  ps_fft_cols_m<256,16> <<<dim3(nimg*(256/16)), 512, 0, st>>>(h4, bandD, nA, n, rdst, rimg, rmask, mout, mstride); break;
    case 512:  ps_fft_cols_m<512,16> <<<dim3(nimg*(512/16)), 512, 0, st>>>(h4, bandD, nA, n, rdst, rimg, rmask, mout, mstride); break;
    case 1024: ps_fft_cols_m<1024,8> <<<dim3(nimg*(1024/8)), 512, 0, st>>>(h4, bandD, nA, n, rdst, rimg, rmask, mout, mstride); break;
    default: break;
  }
}

static inline dim3 gr(int n){ return dim3((n + 255)/256); }
static inline int  rblocks(int n){ int b = (n + 255)/256; return b > 512 ? 512 : b; }

#define FWD (-1.0f)
#define INV (+1.0f)

extern "C" void kernel_launch(void* const* d_in, const int* in_sizes, int n_in,
                              void* d_out, int out_size, void* d_ws, size_t ws_size,
                              hipStream_t stream){
  (void)in_sizes; (void)n_in;
  const float* im = (const float*)d_in[0];
  float* out = (float*)d_out;

  const int Hs[5]   = {1024, 512, 256, 128, 64};
  const int offs[5] = {0, 256, 384, 448, 480};

  // ---- carve workspace ----
  char* base = (char*)d_ws;
  size_t off = 0;
  auto carve = [&](size_t bytes)->void*{
    void* r = base + off;
    off = (off + bytes + 255) & ~(size_t)255;
    return r;
  };
  const int n0 = 1024*1024;
  float2* lod[5];
  for (int s = 0; s < 5; s++) lod[s] = (float2*)carve((size_t)Hs[s]*Hs[s]*sizeof(float2));
  __half2* band[4];
  for (int s = 0; s < 4; s++) band[s] = (__half2*)carve((size_t)4*Hs[s]*Hs[s]*sizeof(__half2));
  float* reals0 = (float*)carve((size_t)2*n0*sizeof(float));
  float* recon[5];
  recon[0] = reals0 + n0;
  for (int s = 1; s < 5; s++) recon[s] = (float*)carve((size_t)Hs[s]*Hs[s]*sizeof(float));
  float* lp = (float*)carve(128*128*sizeof(float));
  float2* scrF = (float2*)carve((size_t)n0*sizeof(float2));
  __half2* h4 = (__half2*)carve((size_t)6*n0*sizeof(__half2));
  double* ST = (double*)carve(2048*sizeof(double));
  unsigned* MM = (unsigned*)carve(64*sizeof(unsigned));
  if (off > ws_size) return;

  // ---- init ----
  hipMemsetAsync(ST, 0, 2048*sizeof(double), stream);
  ps_init_mm<<<1, 1, 0, stream>>>(MM);
  ps_im_stats<<<256, 256, 0, stream>>>((const float4*)im, n0/4, ST + 0, MM);

  // ---- imdft (shifted); cols fuses radial masks ----
  rows_s(1024, scrF, im, 0, FWD, 0, 512, LOP_R2C, stream);
  cols_s(1024, lod[0], scrF, h4, n0, FWD, 0, 512, 1.0f, SOP_HL, nullptr, nullptr, stream);

  // ---- pyramid scales: crop, then merged rows+cols pair ----
  for (int s = 0; s < 4; s++){
    int H = Hs[s], n = H*H;
    float invn = 1.0f/((float)H*(float)H);
    ps_crop_lo<<<gr((H/2)*(H/2)), 256, 0, stream>>>(lod[s+1], lod[s], H, offs[s+1], -(float)(s+1));
    int nA = (s == 0) ? 2 : 1;
    int nimg = nA + 4 + ((s < 3) ? 4 : 0);
    rows_m(H, h4, band[s], lod[s], lod[s+1], nA, (s == 0) ? 1 : 0, nimg, n, Hs[s+1],
           offs[s], -(float)(s+1), offs[s+1], -(float)(s+2), invn, stream);
    float* rT = (s == 0) ? reals0 : recon[s];
    int rimg = (s == 0) ? n0 : 0;
    int rmask = (s == 0) ? 2 : 1;
    double* mT = (s == 0) ? (ST + 4) : (ST + 10 + s*6);
    int mstr = (s == 0) ? 6 : 0;
    cols_m(H, h4, band[s], nA, nimg, n, rT, rimg, rmask, mT, mstr, stream);
    if (s < 3){
      __half2* u = h4 + (size_t)nA*n;
      ps_scaleB<<<rblocks(n), 256, 0, stream>>>(u, u+n, u+2*(size_t)n, u+3*(size_t)n,
                                                band[s], band[s]+n, band[s]+2*(size_t)n, band[s]+3*(size_t)n,
                                                n, ST + 192 + s*80);
    }
  }
  // lowpass recon (f32 path)
  rows_s(64, scrF, lod[4], 0, INV, 32, 0, LOP_NONE, stream);
  cols_s(64, nullptr, scrF, nullptr, 0, INV, 32, 0, 1.0f/4096.f, SOP_REAL, recon[4], ST + 34, stream);
  // lowpass expand2 (f32 path)
  rows_s(128, scrF, lod[4], 64, INV, 64, 0, LOP_PAD, stream);
  cols_s(128, nullptr, scrF, nullptr, 0, INV, 64, 0, 1.0f/4096.f, SOP_REAL, lp, nullptr, stream);
  ps_scaleC<<<rblocks(16384), 256, 0, stream>>>(band[3], band[3]+16384, band[3]+2*16384, band[3]+3*16384,
                                                lp, 16384, ST + 432);

  // ---- all 21 autocorrelations in one launch (big tasks first, nb<=128) ----
  {
    AcTaskTab tt{};
    int nt = 0, blk = 0;
    auto addTask = [&](const void* src, int isMag, int H, int nimgs, int stOff){
      int tiles = (H>>5)*(H>>5);
      int nb = tiles < 128 ? tiles : 128;
      tt.src[nt] = src; tt.isMag[nt] = isMag; tt.H[nt] = H; tt.npi[nt] = H*H;
      tt.nb[nt] = nb; tt.stOff[nt] = stOff; tt.stStride[nt] = 48;
      tt.blkStart[nt] = blk; blk += nb*nimgs; nt++;
    };
    addTask(band[0], 1, 1024, 4, 752 + 0*4*48);
    addTask(recon[0], 0, 1024, 1, 512 + 0*48);
    addTask(band[1], 1, 512, 4, 752 + 1*4*48);
    addTask(recon[1], 0, 512, 1, 512 + 1*48);
    addTask(band[2], 1, 256, 4, 752 + 2*4*48);
    addTask(recon[2], 0, 256, 1, 512 + 2*48);
    addTask(band[3], 1, 128, 4, 752 + 3*4*48);
    addTask(recon[3], 0, 128, 1, 512 + 3*48);
    addTask(recon[4], 0, 64, 1, 512 + 4*48);
    tt.blkStart[nt] = blk; tt.nTasks = nt;
    ps_spat_ac_multi<<<dim3(blk), 256, 0, stream>>>(tt, ST);
  }

  // ---- per-scale band Grams (one launch) ----
  {
    ScaleATab ta{};
    for (int s = 0; s < 4; s++){ ta.b[s] = band[s]; ta.n[s] = Hs[s]*Hs[s]; }
    ps_scaleA_multi<<<dim3(512, 4), 256, 0, stream>>>(ta, ST);
  }

  // ---- finalize ----
  ps_finalize<<<gr(out_size), 256, 0, stream>>>(ST, MM, out, out_size);
}